// Round 2
// baseline (91613.672 us; speedup 1.0000x reference)
//
#include <hip/hip_runtime.h>
#include <stdint.h>

// F=1024, H=512, S=512, B=32, T=128
// Persistent cooperative kernels; custom monotonic grid barrier.
// ws layout (floats after 1024-int ctrl block): enc_proj[512*32*512],
// henc[2dir][2pp][32][512], cfin[2dir][32][512], hbuf[2][32][1024],
// dproj[32*512], pval[256*32], pidx[256*32]  => ~34.3 MB total.

#define NWG 256

__device__ __forceinline__ float sigm(float x) { return 1.0f / (1.0f + __expf(-x)); }
__device__ __forceinline__ float tanhx(float x) {
  float e = __expf(2.0f * x);
  return 1.0f - 2.0f / (e + 1.0f);
}

__device__ __forceinline__ void grid_barrier(int* ctr, int target) {
  __syncthreads();
  if (threadIdx.x == 0) {
    __threadfence();
    __hip_atomic_fetch_add(ctr, 1, __ATOMIC_RELAXED, __HIP_MEMORY_SCOPE_AGENT);
    while (__hip_atomic_load(ctr, __ATOMIC_RELAXED, __HIP_MEMORY_SCOPE_AGENT) < target) {
      __builtin_amdgcn_s_sleep(1);
    }
    __threadfence();
  }
  __syncthreads();
}

// ---------------------------------------------------------------------------
// Encoder (cooperative, 256 WGs x 256 thr). WG<128: fwd, WG>=128: bwd.
// WG owns 4 h-cols. One grid barrier per step. enc_proj accumulated in a
// deterministic first-store / second-add schedule (see role rule below).
// ---------------------------------------------------------------------------
__global__ __launch_bounds__(256) void encoder_kernel(
    const float* __restrict__ feats,
    const float* __restrict__ Wih_f, const float* __restrict__ Whh_f,
    const float* __restrict__ bih_f, const float* __restrict__ bhh_f,
    const float* __restrict__ Wih_b, const float* __restrict__ Whh_b,
    const float* __restrict__ bih_b, const float* __restrict__ bhh_b,
    const float* __restrict__ W_enc, const float* __restrict__ b_enc,
    float* __restrict__ enc_proj, float* __restrict__ henc,
    float* __restrict__ cfin, int* __restrict__ ctr)
{
  __shared__ float hch[32 * 132];     // staged h-prev chunk [32][128] (+pad)
  __shared__ float wenc[4 * 516];     // W_enc rows (4 out cols) x 512 (dir half)
  __shared__ float gpart[32][17];
  __shared__ float projp[2][128];
  __shared__ float bias_s[16];
  __shared__ float benc_s[4];

  const int w = blockIdx.x;
  const int dir = (w >= 128) ? 1 : 0;
  const int wl = w & 127;
  const int col0 = wl * 4;
  const int t = threadIdx.x;
  const int kh = t >> 7;       // 0/1: gate-pair (and proj k-half)
  const int tt = t & 127;
  const int b = tt >> 2;       // batch 0..31
  const int ci = tt & 3;       // col-in-group
  const int col = col0 + ci;   // 0..511

  const float* Wih = dir ? Wih_b : Wih_f;
  const float* Whh = dir ? Whh_b : Whh_f;
  const float* bih = dir ? bih_b : bih_f;
  const float* bhh = dir ? bhh_b : bhh_f;

  // preload W_enc slice for this WG's 4 proj output cols (dir's K-half)
  for (int i = t; i < 4 * 128; i += 256) {
    int jl = i >> 7, q = i & 127;
    *(float4*)(wenc + jl * 516 + q * 4) =
        *(const float4*)(W_enc + (size_t)(col0 + jl) * 1024 + dir * 512 + q * 4);
  }
  if (t < 16) {
    int g = t >> 2, cj = t & 3;
    bias_s[t] = bih[g * 512 + col0 + cj] + bhh[g * 512 + col0 + cj];
  }
  if (t < 4) benc_s[t] = b_enc[col0 + t];
  float c_reg = 0.0f;
  __syncthreads();

  const float* wx0 = Wih + (size_t)((kh * 2 + 0) * 512 + col) * 1024;
  const float* wx1 = Wih + (size_t)((kh * 2 + 1) * 512 + col) * 1024;
  const float* wh0 = Whh + (size_t)((kh * 2 + 0) * 512 + col) * 512;
  const float* wh1 = Whh + (size_t)((kh * 2 + 1) * 512 + col) * 512;

  for (int it = 0; it < 512; ++it) {
    const int s = dir ? (511 - it) : it;
    float accA = 0.0f, accB = 0.0f, projacc = 0.0f;

    if (it > 0) {
      const float* hsrc = henc + dir * 32768 + ((it - 1) & 1) * 16384;
      for (int ch = 0; ch < 4; ++ch) {
        for (int i = t; i < 1024; i += 256) {
          int bb = i >> 5, q = i & 31;
          *(float4*)(hch + bb * 132 + q * 4) =
              *(const float4*)(hsrc + bb * 512 + ch * 128 + q * 4);
        }
        __syncthreads();
        // recurrence part: 2 gate rows x 128 k
        {
          const float* hrow = hch + b * 132;
          const float* p0 = wh0 + ch * 128;
          const float* p1 = wh1 + ch * 128;
#pragma unroll 4
          for (int q = 0; q < 32; ++q) {
            float4 h4 = *(const float4*)(hrow + q * 4);
            float4 a4 = *(const float4*)(p0 + q * 4);
            float4 b4 = *(const float4*)(p1 + q * 4);
            accA += h4.x * a4.x + h4.y * a4.y + h4.z * a4.z + h4.w * a4.w;
            accB += h4.x * b4.x + h4.y * b4.y + h4.z * b4.z + h4.w * b4.w;
          }
        }
        // pipelined enc_proj part for h produced last step (same staged data)
        {
          const float* hp = hch + b * 132 + kh * 64;
          const float* wp = wenc + ci * 516 + ch * 128 + kh * 64;
#pragma unroll 4
          for (int kk = 0; kk < 16; ++kk) {
            float4 h4 = *(const float4*)(hp + kk * 4);
            float4 w4 = *(const float4*)(wp + kk * 4);
            projacc += h4.x * w4.x + h4.y * w4.y + h4.z * w4.z + h4.w * w4.w;
          }
        }
        __syncthreads();
      }
    }

    // x-part: full K=1024 for this thread's two gate rows
    {
      const float* frow = feats + ((size_t)s * 32 + b) * 1024;
#pragma unroll 4
      for (int q = 0; q < 256; ++q) {
        float4 f4 = *(const float4*)(frow + q * 4);
        float4 a4 = *(const float4*)(wx0 + q * 4);
        float4 b4 = *(const float4*)(wx1 + q * 4);
        accA += f4.x * a4.x + f4.y * a4.y + f4.z * a4.z + f4.w * a4.w;
        accB += f4.x * b4.x + f4.y * b4.y + f4.z * b4.z + f4.w * b4.w;
      }
    }
    gpart[b][(kh * 2 + 0) * 4 + ci] = accA;
    gpart[b][(kh * 2 + 1) * 4 + ci] = accB;
    projp[kh][tt] = projacc;
    __syncthreads();
    if (kh == 0) {
      float gi = gpart[b][ci + 0] + bias_s[ci + 0];
      float gf = gpart[b][ci + 4] + bias_s[ci + 4];
      float gg = gpart[b][ci + 8] + bias_s[ci + 8];
      float go = gpart[b][ci + 12] + bias_s[ci + 12];
      float cn = sigm(gf) * c_reg + sigm(gi) * tanhx(gg);
      c_reg = cn;
      henc[dir * 32768 + (it & 1) * 16384 + b * 512 + col] = sigm(go) * tanhx(cn);
    } else if (it > 0) {
      // store/accumulate enc_proj for position produced at step it-1.
      // Role rule: producer-step e=it-1 <= 255  => this dir arrived first.
      const int sp = dir ? (512 - it) : (it - 1);
      const float p = projp[0][tt] + projp[1][tt];
      const size_t off = ((size_t)sp * 32 + b) * 512 + col;
      if (it - 1 <= 255) enc_proj[off] = p + benc_s[ci];
      else               enc_proj[off] = enc_proj[off] + p;
    }
    grid_barrier(ctr, (it + 1) * NWG);
  }

  // final proj for h produced at step 511 (always the second arriver)
  {
    const float* hsrc = henc + dir * 32768 + 16384;  // pp = 511&1 = 1
    float projacc = 0.0f;
    for (int ch = 0; ch < 4; ++ch) {
      for (int i = t; i < 1024; i += 256) {
        int bb = i >> 5, q = i & 31;
        *(float4*)(hch + bb * 132 + q * 4) =
            *(const float4*)(hsrc + bb * 512 + ch * 128 + q * 4);
      }
      __syncthreads();
      const float* hp = hch + b * 132 + kh * 64;
      const float* wp = wenc + ci * 516 + ch * 128 + kh * 64;
#pragma unroll 4
      for (int kk = 0; kk < 16; ++kk) {
        float4 h4 = *(const float4*)(hp + kk * 4);
        float4 w4 = *(const float4*)(wp + kk * 4);
        projacc += h4.x * w4.x + h4.y * w4.y + h4.z * w4.z + h4.w * w4.w;
      }
      __syncthreads();
    }
    projp[kh][tt] = projacc;
    __syncthreads();
    if (kh == 1) {
      const int sp = dir ? 0 : 511;
      const size_t off = ((size_t)sp * 32 + b) * 512 + col;
      enc_proj[off] = enc_proj[off] + (projp[0][tt] + projp[1][tt]);
    }
    if (kh == 0) cfin[dir * 16384 + b * 512 + col] = c_reg;
  }
}

// ---------------------------------------------------------------------------
// Decoder (cooperative, 256 WGs x 256 thr), 128 steps, 4 barriers/step.
// WG w owns decoder h-cols [4w,4w+4). Weights stream from L2.
// ---------------------------------------------------------------------------
__global__ __launch_bounds__(256) void decoder_kernel(
    const float* __restrict__ feats,
    const float* __restrict__ Wih_d, const float* __restrict__ Whh_d,
    const float* __restrict__ bih_d, const float* __restrict__ bhh_d,
    const float* __restrict__ W_dec, const float* __restrict__ b_dec,
    const float* __restrict__ W_v, const float* __restrict__ b_v,
    const float* __restrict__ enc_proj, const float* __restrict__ henc,
    const float* __restrict__ cfin,
    float* __restrict__ hbuf, float* __restrict__ dproj,
    float* __restrict__ pval, int* __restrict__ pidx,
    int* __restrict__ idxbuf, int* __restrict__ ctr,
    float* __restrict__ out)
{
  __shared__ float gpart[2][32][17];
  __shared__ float c_lds[32][4];
  __shared__ float bias_s[16];
  __shared__ float svals[64];
  __shared__ float redv[4];
  __shared__ int redi[4];

  const int w = blockIdx.x;
  const int t = threadIdx.x;
  const int kh = t >> 7;    // 0: Whh-part, 1: Wih-part
  const int tt = t & 127;
  const int b = tt >> 2;
  const int ci = tt & 3;
  const int col0 = w * 4;
  const int col = col0 + ci;  // 0..1023

  if (t < 16) {
    int g = t >> 2, cj = t & 3;
    bias_s[t] = bih_d[g * 1024 + col0 + cj] + bhh_d[g * 1024 + col0 + cj];
  }
  // h0/c0 with the torch .view() batch-mixing reshape
  if (kh == 0) {
    int flat = b * 1024 + col;
    int d = flat >> 14, sb = (flat >> 9) & 31, sh = flat & 511;
    float h0, c0;
    if (d == 0) {
      h0 = henc[16384 + sb * 512 + sh];            // hf final (dir0, pp1)
      c0 = cfin[sb * 512 + sh];
    } else {
      h0 = henc[32768 + 16384 + sb * 512 + sh];    // hb final (dir1, pp1)
      c0 = cfin[16384 + sb * 512 + sh];
    }
    hbuf[b * 1024 + col] = h0;
    c_lds[b][ci] = c0;
  }
  int bars = 1;
  grid_barrier(ctr, bars * NWG);

  const float* wh0 = Whh_d + (size_t)(0 * 1024 + col) * 1024;
  const float* wh1 = Whh_d + (size_t)(1 * 1024 + col) * 1024;
  const float* wh2 = Whh_d + (size_t)(2 * 1024 + col) * 1024;
  const float* wh3 = Whh_d + (size_t)(3 * 1024 + col) * 1024;
  const float* wi0 = Wih_d + (size_t)(0 * 1024 + col) * 1024;
  const float* wi1 = Wih_d + (size_t)(1 * 1024 + col) * 1024;
  const float* wi2 = Wih_d + (size_t)(2 * 1024 + col) * 1024;
  const float* wi3 = Wih_d + (size_t)(3 * 1024 + col) * 1024;

  for (int ts = 0; ts < 128; ++ts) {
    const float* hprev = hbuf + (ts & 1) * 32768;
    float* hnext = hbuf + ((ts + 1) & 1) * 32768;

    // ---- phase A: gates GEMM + cell ----
    float a0 = 0.f, a1 = 0.f, a2 = 0.f, a3 = 0.f;
    {
      const float* xrow;
      const float *u0, *u1, *u2, *u3;
      if (kh == 0) {
        xrow = hprev + b * 1024;
        u0 = wh0; u1 = wh1; u2 = wh2; u3 = wh3;
      } else {
        int ib = idxbuf[b];
        xrow = feats + ((size_t)ib * 32 + b) * 1024;
        u0 = wi0; u1 = wi1; u2 = wi2; u3 = wi3;
      }
#pragma unroll 2
      for (int q = 0; q < 256; ++q) {
        float4 x4 = *(const float4*)(xrow + q * 4);
        float4 v0 = *(const float4*)(u0 + q * 4);
        float4 v1 = *(const float4*)(u1 + q * 4);
        float4 v2 = *(const float4*)(u2 + q * 4);
        float4 v3 = *(const float4*)(u3 + q * 4);
        a0 += x4.x * v0.x + x4.y * v0.y + x4.z * v0.z + x4.w * v0.w;
        a1 += x4.x * v1.x + x4.y * v1.y + x4.z * v1.z + x4.w * v1.w;
        a2 += x4.x * v2.x + x4.y * v2.y + x4.z * v2.z + x4.w * v2.w;
        a3 += x4.x * v3.x + x4.y * v3.y + x4.z * v3.z + x4.w * v3.w;
      }
    }
    gpart[kh][b][ci + 0] = a0;
    gpart[kh][b][ci + 4] = a1;
    gpart[kh][b][ci + 8] = a2;
    gpart[kh][b][ci + 12] = a3;
    __syncthreads();
    if (kh == 0) {
      float gi = gpart[0][b][ci + 0] + gpart[1][b][ci + 0] + bias_s[ci + 0];
      float gf = gpart[0][b][ci + 4] + gpart[1][b][ci + 4] + bias_s[ci + 4];
      float gg = gpart[0][b][ci + 8] + gpart[1][b][ci + 8] + bias_s[ci + 8];
      float go = gpart[0][b][ci + 12] + gpart[1][b][ci + 12] + bias_s[ci + 12];
      float cn = sigm(gf) * c_lds[b][ci] + sigm(gi) * tanhx(gg);
      c_lds[b][ci] = cn;
      hnext[b * 1024 + col] = sigm(go) * tanhx(cn);
    }
    ++bars; grid_barrier(ctr, bars * NWG);

    // ---- phase B: dproj = h @ W_dec^T + b_dec (WGs 0..63) ----
    if (w < 64) {
      int bb = t >> 3, cl = t & 7;
      int cc = w * 8 + cl;
      const float* hrow = hnext + bb * 1024;
      const float* wrow = W_dec + (size_t)cc * 1024;
      float acc = 0.f;
#pragma unroll 4
      for (int q = 0; q < 256; ++q) {
        float4 h4 = *(const float4*)(hrow + q * 4);
        float4 w4 = *(const float4*)(wrow + q * 4);
        acc += h4.x * w4.x + h4.y * w4.y + h4.z * w4.z + h4.w * w4.w;
      }
      dproj[bb * 512 + cc] = acc + b_dec[cc];
    }
    ++bars; grid_barrier(ctr, bars * NWG);

    // ---- phase C: scores + per-WG argmax partials (WG covers s=2w,2w+1) ----
    {
      int sc = t >> 2, ks = t & 3;
      int sl = sc >> 5, bb = sc & 31;
      int s = w * 2 + sl;
      const float* ep = enc_proj + ((size_t)s * 32 + bb) * 512 + ks * 128;
      const float* dp = dproj + bb * 512 + ks * 128;
      const float* wv = W_v + ks * 128;
      float sum = 0.f;
#pragma unroll 4
      for (int q = 0; q < 32; ++q) {
        float4 e4 = *(const float4*)(ep + q * 4);
        float4 d4 = *(const float4*)(dp + q * 4);
        float4 v4 = *(const float4*)(wv + q * 4);
        sum += tanhx(e4.x + d4.x) * v4.x;
        sum += tanhx(e4.y + d4.y) * v4.y;
        sum += tanhx(e4.z + d4.z) * v4.z;
        sum += tanhx(e4.w + d4.w) * v4.w;
      }
      sum += __shfl_xor(sum, 1);
      sum += __shfl_xor(sum, 2);
      if (ks == 0) {
        float sv = sum + b_v[0];
        out[((size_t)ts * 32 + bb) * 512 + s] = sv;
        svals[sl * 32 + bb] = sv;
      }
    }
    __syncthreads();
    if (t < 32) {
      float v0 = svals[t], v1 = svals[32 + t];
      float bv = v0; int bs = w * 2;
      if (v1 > v0) { bv = v1; bs = w * 2 + 1; }  // tie -> smaller s
      pval[w * 32 + t] = bv;
      pidx[w * 32 + t] = bs;
    }
    ++bars; grid_barrier(ctr, bars * NWG);

    // ---- phase D: final argmax per batch (WG w<32 handles b=w) ----
    if (w < 32) {
      float v = pval[t * 32 + w];
      int si = pidx[t * 32 + w];
#pragma unroll
      for (int m = 1; m < 64; m <<= 1) {
        float ov = __shfl_xor(v, m);
        int os = __shfl_xor(si, m);
        if (ov > v || (ov == v && os < si)) { v = ov; si = os; }
      }
      int lane = t & 63, wid = t >> 6;
      if (lane == 0) { redv[wid] = v; redi[wid] = si; }
      __syncthreads();
      if (t == 0) {
        for (int i = 1; i < 4; ++i) {
          if (redv[i] > v || (redv[i] == v && redi[i] < si)) { v = redv[i]; si = redi[i]; }
        }
        idxbuf[w] = si;
      }
    }
    ++bars; grid_barrier(ctr, bars * NWG);
  }
}

// ---------------------------------------------------------------------------
extern "C" void kernel_launch(void* const* d_in, const int* in_sizes, int n_in,
                              void* d_out, int out_size, void* d_ws, size_t ws_size,
                              hipStream_t stream) {
  (void)in_sizes; (void)n_in; (void)out_size; (void)ws_size;
  const float* feats = (const float*)d_in[0];
  const float* Wih_f = (const float*)d_in[1];
  const float* Whh_f = (const float*)d_in[2];
  const float* bih_f = (const float*)d_in[3];
  const float* bhh_f = (const float*)d_in[4];
  const float* Wih_b = (const float*)d_in[5];
  const float* Whh_b = (const float*)d_in[6];
  const float* bih_b = (const float*)d_in[7];
  const float* bhh_b = (const float*)d_in[8];
  const float* Wih_d = (const float*)d_in[9];
  const float* Whh_d = (const float*)d_in[10];
  const float* bih_d = (const float*)d_in[11];
  const float* bhh_d = (const float*)d_in[12];
  const float* W_enc = (const float*)d_in[13];
  const float* b_enc = (const float*)d_in[14];
  const float* W_dec = (const float*)d_in[15];
  const float* b_dec = (const float*)d_in[16];
  const float* W_v   = (const float*)d_in[17];
  const float* b_v   = (const float*)d_in[18];
  float* out = (float*)d_out;

  int* ctrl = (int*)d_ws;
  int* ctr_enc = ctrl;           // +0
  int* ctr_dec = ctrl + 64;      // +64
  int* idxbuf  = ctrl + 128;     // 32 ints
  float* base = (float*)d_ws + 1024;
  float* enc_proj = base;                    // 8,388,608
  float* henc     = enc_proj + 8388608;      //    65,536
  float* cfin     = henc + 65536;            //    32,768
  float* hbuf     = cfin + 32768;            //    65,536
  float* dproj    = hbuf + 65536;            //    16,384
  float* pval     = dproj + 16384;           //     8,192
  int*   pidx     = (int*)(pval + 8192);     //     8,192 ints
  // total ~34.3 MB

  hipMemsetAsync(d_ws, 0, 4096, stream);

  {
    void* args[] = {(void*)&feats,
                    (void*)&Wih_f, (void*)&Whh_f, (void*)&bih_f, (void*)&bhh_f,
                    (void*)&Wih_b, (void*)&Whh_b, (void*)&bih_b, (void*)&bhh_b,
                    (void*)&W_enc, (void*)&b_enc,
                    (void*)&enc_proj, (void*)&henc, (void*)&cfin, (void*)&ctr_enc};
    hipLaunchCooperativeKernel((const void*)encoder_kernel, dim3(NWG), dim3(256),
                               args, 0, stream);
  }
  {
    void* args[] = {(void*)&feats,
                    (void*)&Wih_d, (void*)&Whh_d, (void*)&bih_d, (void*)&bhh_d,
                    (void*)&W_dec, (void*)&b_dec, (void*)&W_v, (void*)&b_v,
                    (void*)&enc_proj, (void*)&henc, (void*)&cfin,
                    (void*)&hbuf, (void*)&dproj, (void*)&pval, (void*)&pidx,
                    (void*)&idxbuf, (void*)&ctr_dec, (void*)&out};
    hipLaunchCooperativeKernel((const void*)decoder_kernel, dim3(NWG), dim3(256),
                               args, 0, stream);
  }
}

// Round 4
// 86990.894 us; speedup vs baseline: 1.0531x; 1.0531x over previous
//
#include <hip/hip_runtime.h>
#include <stdint.h>

// F=1024, H=512, S=512, B=32, T=128
// Round-2 verified compute bodies; ONLY change: flat grid barrier -> two-level
// tree barrier (32 groups x 8 WGs, padded cachelines, monotonic epochs).

#define NWG 256

__device__ __forceinline__ float sigm(float x) { return 1.0f / (1.0f + __expf(-x)); }
__device__ __forceinline__ float tanhx(float x) {
  float e = __expf(2.0f * x);
  return 1.0f - 2.0f / (e + 1.0f);
}

// ---------------------------------------------------------------------------
// Two-level tree barrier. bar layout (ints): gcnt[g] @ g*64 (g=0..31),
// root cnt @ 2048, gflag[g] @ 2112 + g*64. All zeroed at launch.
// Epochs are 1-indexed and monotonic.
// ---------------------------------------------------------------------------
__device__ __forceinline__ void tree_barrier(int* bar, int w, int epoch) {
  __syncthreads();
  if (threadIdx.x == 0) {
    const int g = w >> 3;
    int* gc = bar + g * 64;
    int* rc = bar + 2048;
    int* gf = bar + 2112 + g * 64;
    __threadfence();  // release: publish our global stores
    int old = __hip_atomic_fetch_add(gc, 1, __ATOMIC_RELAXED, __HIP_MEMORY_SCOPE_AGENT);
    if (old == epoch * 8 - 1) {  // 8th arrival of this epoch -> group leader
      __hip_atomic_fetch_add(rc, 1, __ATOMIC_RELAXED, __HIP_MEMORY_SCOPE_AGENT);
      while (__hip_atomic_load(rc, __ATOMIC_RELAXED, __HIP_MEMORY_SCOPE_AGENT) < epoch * 32) {
        __builtin_amdgcn_s_sleep(2);
      }
      __hip_atomic_store(gf, epoch, __ATOMIC_RELAXED, __HIP_MEMORY_SCOPE_AGENT);
    } else {
      while (__hip_atomic_load(gf, __ATOMIC_RELAXED, __HIP_MEMORY_SCOPE_AGENT) < epoch) {
        __builtin_amdgcn_s_sleep(2);
      }
    }
    __threadfence();  // acquire: invalidate stale cached lines
  }
  __syncthreads();
}

// ---------------------------------------------------------------------------
// Encoder (cooperative, 256 WGs x 256 thr). WG<128: fwd, WG>=128: bwd.
// WG owns 4 h-cols. One global tree barrier per step (end of iteration).
// enc_proj accumulated with deterministic first-store/second-add schedule:
// producer-step e<=255 => that direction arrived first (proof: store happens
// before epoch e+2 <= 257; the other dir's add happens after epoch 512-sp
// >= 257; separated by >=1 barrier).
// ---------------------------------------------------------------------------
__global__ __launch_bounds__(256) void encoder_kernel(
    const float* __restrict__ feats,
    const float* __restrict__ Wih_f, const float* __restrict__ Whh_f,
    const float* __restrict__ bih_f, const float* __restrict__ bhh_f,
    const float* __restrict__ Wih_b, const float* __restrict__ Whh_b,
    const float* __restrict__ bih_b, const float* __restrict__ bhh_b,
    const float* __restrict__ W_enc, const float* __restrict__ b_enc,
    float* __restrict__ enc_proj, float* __restrict__ henc,
    float* __restrict__ cfin, int* __restrict__ bar)
{
  __shared__ float hch[32 * 132];     // staged h-prev chunk [32][128] (+pad)
  __shared__ float wenc[4 * 516];     // W_enc rows (4 out cols) x 512 (dir half)
  __shared__ float gpart[32][17];
  __shared__ float projp[2][128];
  __shared__ float bias_s[16];
  __shared__ float benc_s[4];

  const int w = blockIdx.x;
  const int dir = (w >= 128) ? 1 : 0;
  const int wl = w & 127;
  const int col0 = wl * 4;
  const int t = threadIdx.x;
  const int kh = t >> 7;       // 0/1: gate-pair (and proj k-half)
  const int tt = t & 127;
  const int b = tt >> 2;       // batch 0..31
  const int ci = tt & 3;       // col-in-group
  const int col = col0 + ci;   // 0..511

  const float* Wih = dir ? Wih_b : Wih_f;
  const float* Whh = dir ? Whh_b : Whh_f;
  const float* bih = dir ? bih_b : bih_f;
  const float* bhh = dir ? bhh_b : bhh_f;

  // preload W_enc slice for this WG's 4 proj output cols (dir's K-half)
  for (int i = t; i < 4 * 128; i += 256) {
    int jl = i >> 7, q = i & 127;
    *(float4*)(wenc + jl * 516 + q * 4) =
        *(const float4*)(W_enc + (size_t)(col0 + jl) * 1024 + dir * 512 + q * 4);
  }
  if (t < 16) {
    int g = t >> 2, cj = t & 3;
    bias_s[t] = bih[g * 512 + col0 + cj] + bhh[g * 512 + col0 + cj];
  }
  if (t < 4) benc_s[t] = b_enc[col0 + t];
  float c_reg = 0.0f;
  __syncthreads();

  const float* wx0 = Wih + (size_t)((kh * 2 + 0) * 512 + col) * 1024;
  const float* wx1 = Wih + (size_t)((kh * 2 + 1) * 512 + col) * 1024;
  const float* wh0 = Whh + (size_t)((kh * 2 + 0) * 512 + col) * 512;
  const float* wh1 = Whh + (size_t)((kh * 2 + 1) * 512 + col) * 512;

  for (int it = 0; it < 512; ++it) {
    const int s = dir ? (511 - it) : it;
    float accA = 0.0f, accB = 0.0f, projacc = 0.0f;

    if (it > 0) {
      const float* hsrc = henc + dir * 32768 + ((it - 1) & 1) * 16384;
      for (int ch = 0; ch < 4; ++ch) {
        for (int i = t; i < 1024; i += 256) {
          int bb = i >> 5, q = i & 31;
          *(float4*)(hch + bb * 132 + q * 4) =
              *(const float4*)(hsrc + bb * 512 + ch * 128 + q * 4);
        }
        __syncthreads();
        // recurrence part: 2 gate rows x 128 k
        {
          const float* hrow = hch + b * 132;
          const float* p0 = wh0 + ch * 128;
          const float* p1 = wh1 + ch * 128;
#pragma unroll 4
          for (int q = 0; q < 32; ++q) {
            float4 h4 = *(const float4*)(hrow + q * 4);
            float4 a4 = *(const float4*)(p0 + q * 4);
            float4 b4 = *(const float4*)(p1 + q * 4);
            accA += h4.x * a4.x + h4.y * a4.y + h4.z * a4.z + h4.w * a4.w;
            accB += h4.x * b4.x + h4.y * b4.y + h4.z * b4.z + h4.w * b4.w;
          }
        }
        // pipelined enc_proj part for h produced last step (same staged data)
        {
          const float* hp = hch + b * 132 + kh * 64;
          const float* wp = wenc + ci * 516 + ch * 128 + kh * 64;
#pragma unroll 4
          for (int kk = 0; kk < 16; ++kk) {
            float4 h4 = *(const float4*)(hp + kk * 4);
            float4 w4 = *(const float4*)(wp + kk * 4);
            projacc += h4.x * w4.x + h4.y * w4.y + h4.z * w4.z + h4.w * w4.w;
          }
        }
        __syncthreads();
      }
    }

    // x-part: full K=1024 for this thread's two gate rows
    {
      const float* frow = feats + ((size_t)s * 32 + b) * 1024;
#pragma unroll 4
      for (int q = 0; q < 256; ++q) {
        float4 f4 = *(const float4*)(frow + q * 4);
        float4 a4 = *(const float4*)(wx0 + q * 4);
        float4 b4 = *(const float4*)(wx1 + q * 4);
        accA += f4.x * a4.x + f4.y * a4.y + f4.z * a4.z + f4.w * a4.w;
        accB += f4.x * b4.x + f4.y * b4.y + f4.z * b4.z + f4.w * b4.w;
      }
    }
    gpart[b][(kh * 2 + 0) * 4 + ci] = accA;
    gpart[b][(kh * 2 + 1) * 4 + ci] = accB;
    projp[kh][tt] = projacc;
    __syncthreads();
    if (kh == 0) {
      float gi = gpart[b][ci + 0] + bias_s[ci + 0];
      float gf = gpart[b][ci + 4] + bias_s[ci + 4];
      float gg = gpart[b][ci + 8] + bias_s[ci + 8];
      float go = gpart[b][ci + 12] + bias_s[ci + 12];
      float cn = sigm(gf) * c_reg + sigm(gi) * tanhx(gg);
      c_reg = cn;
      henc[dir * 32768 + (it & 1) * 16384 + b * 512 + col] = sigm(go) * tanhx(cn);
    } else if (it > 0) {
      // store/accumulate enc_proj for position produced at step it-1.
      const int sp = dir ? (512 - it) : (it - 1);
      const float p = projp[0][tt] + projp[1][tt];
      const size_t off = ((size_t)sp * 32 + b) * 512 + col;
      if (it - 1 <= 255) enc_proj[off] = p + benc_s[ci];
      else               enc_proj[off] = enc_proj[off] + p;
    }
    tree_barrier(bar, w, it + 1);
  }

  // final proj for h produced at step 511 (always the second arriver;
  // protected by the epoch-512 barrier above)
  {
    const float* hsrc = henc + dir * 32768 + 16384;  // pp = 511&1 = 1
    float projacc = 0.0f;
    for (int ch = 0; ch < 4; ++ch) {
      for (int i = t; i < 1024; i += 256) {
        int bb = i >> 5, q = i & 31;
        *(float4*)(hch + bb * 132 + q * 4) =
            *(const float4*)(hsrc + bb * 512 + ch * 128 + q * 4);
      }
      __syncthreads();
      const float* hp = hch + b * 132 + kh * 64;
      const float* wp = wenc + ci * 516 + ch * 128 + kh * 64;
#pragma unroll 4
      for (int kk = 0; kk < 16; ++kk) {
        float4 h4 = *(const float4*)(hp + kk * 4);
        float4 w4 = *(const float4*)(wp + kk * 4);
        projacc += h4.x * w4.x + h4.y * w4.y + h4.z * w4.z + h4.w * w4.w;
      }
      __syncthreads();
    }
    projp[kh][tt] = projacc;
    __syncthreads();
    if (kh == 1) {
      const int sp = dir ? 0 : 511;
      const size_t off = ((size_t)sp * 32 + b) * 512 + col;
      enc_proj[off] = enc_proj[off] + (projp[0][tt] + projp[1][tt]);
    }
    if (kh == 0) cfin[dir * 16384 + b * 512 + col] = c_reg;
  }
}

// ---------------------------------------------------------------------------
// Decoder (cooperative, 256 WGs x 256 thr), 128 steps, 4 tree barriers/step.
// WG w owns decoder h-cols [4w,4w+4). Weights stream from L2.
// ---------------------------------------------------------------------------
__global__ __launch_bounds__(256) void decoder_kernel(
    const float* __restrict__ feats,
    const float* __restrict__ Wih_d, const float* __restrict__ Whh_d,
    const float* __restrict__ bih_d, const float* __restrict__ bhh_d,
    const float* __restrict__ W_dec, const float* __restrict__ b_dec,
    const float* __restrict__ W_v, const float* __restrict__ b_v,
    const float* __restrict__ enc_proj, const float* __restrict__ henc,
    const float* __restrict__ cfin,
    float* __restrict__ hbuf, float* __restrict__ dproj,
    float* __restrict__ pval, int* __restrict__ pidx,
    int* __restrict__ idxbuf, int* __restrict__ bar,
    float* __restrict__ out)
{
  __shared__ float gpart[2][32][17];
  __shared__ float c_lds[32][4];
  __shared__ float bias_s[16];
  __shared__ float svals[64];
  __shared__ float redv[4];
  __shared__ int redi[4];

  const int w = blockIdx.x;
  const int t = threadIdx.x;
  const int kh = t >> 7;    // 0: Whh-part, 1: Wih-part
  const int tt = t & 127;
  const int b = tt >> 2;
  const int ci = tt & 3;
  const int col0 = w * 4;
  const int col = col0 + ci;  // 0..1023

  if (t < 16) {
    int g = t >> 2, cj = t & 3;
    bias_s[t] = bih_d[g * 1024 + col0 + cj] + bhh_d[g * 1024 + col0 + cj];
  }
  // h0/c0 with the torch .view() batch-mixing reshape
  if (kh == 0) {
    int flat = b * 1024 + col;
    int d = flat >> 14, sb = (flat >> 9) & 31, sh = flat & 511;
    float h0, c0;
    if (d == 0) {
      h0 = henc[16384 + sb * 512 + sh];            // hf final (dir0, pp1)
      c0 = cfin[sb * 512 + sh];
    } else {
      h0 = henc[32768 + 16384 + sb * 512 + sh];    // hb final (dir1, pp1)
      c0 = cfin[16384 + sb * 512 + sh];
    }
    hbuf[b * 1024 + col] = h0;
    c_lds[b][ci] = c0;
  }
  int bars = 1;
  tree_barrier(bar, w, bars);

  const float* wh0 = Whh_d + (size_t)(0 * 1024 + col) * 1024;
  const float* wh1 = Whh_d + (size_t)(1 * 1024 + col) * 1024;
  const float* wh2 = Whh_d + (size_t)(2 * 1024 + col) * 1024;
  const float* wh3 = Whh_d + (size_t)(3 * 1024 + col) * 1024;
  const float* wi0 = Wih_d + (size_t)(0 * 1024 + col) * 1024;
  const float* wi1 = Wih_d + (size_t)(1 * 1024 + col) * 1024;
  const float* wi2 = Wih_d + (size_t)(2 * 1024 + col) * 1024;
  const float* wi3 = Wih_d + (size_t)(3 * 1024 + col) * 1024;

  for (int ts = 0; ts < 128; ++ts) {
    const float* hprev = hbuf + (ts & 1) * 32768;
    float* hnext = hbuf + ((ts + 1) & 1) * 32768;

    // ---- phase A: gates GEMM + cell ----
    float a0 = 0.f, a1 = 0.f, a2 = 0.f, a3 = 0.f;
    {
      const float* xrow;
      const float *u0, *u1, *u2, *u3;
      if (kh == 0) {
        xrow = hprev + b * 1024;
        u0 = wh0; u1 = wh1; u2 = wh2; u3 = wh3;
      } else {
        int ib = idxbuf[b];
        xrow = feats + ((size_t)ib * 32 + b) * 1024;
        u0 = wi0; u1 = wi1; u2 = wi2; u3 = wi3;
      }
#pragma unroll 2
      for (int q = 0; q < 256; ++q) {
        float4 x4 = *(const float4*)(xrow + q * 4);
        float4 v0 = *(const float4*)(u0 + q * 4);
        float4 v1 = *(const float4*)(u1 + q * 4);
        float4 v2 = *(const float4*)(u2 + q * 4);
        float4 v3 = *(const float4*)(u3 + q * 4);
        a0 += x4.x * v0.x + x4.y * v0.y + x4.z * v0.z + x4.w * v0.w;
        a1 += x4.x * v1.x + x4.y * v1.y + x4.z * v1.z + x4.w * v1.w;
        a2 += x4.x * v2.x + x4.y * v2.y + x4.z * v2.z + x4.w * v2.w;
        a3 += x4.x * v3.x + x4.y * v3.y + x4.z * v3.z + x4.w * v3.w;
      }
    }
    gpart[kh][b][ci + 0] = a0;
    gpart[kh][b][ci + 4] = a1;
    gpart[kh][b][ci + 8] = a2;
    gpart[kh][b][ci + 12] = a3;
    __syncthreads();
    if (kh == 0) {
      float gi = gpart[0][b][ci + 0] + gpart[1][b][ci + 0] + bias_s[ci + 0];
      float gf = gpart[0][b][ci + 4] + gpart[1][b][ci + 4] + bias_s[ci + 4];
      float gg = gpart[0][b][ci + 8] + gpart[1][b][ci + 8] + bias_s[ci + 8];
      float go = gpart[0][b][ci + 12] + gpart[1][b][ci + 12] + bias_s[ci + 12];
      float cn = sigm(gf) * c_lds[b][ci] + sigm(gi) * tanhx(gg);
      c_lds[b][ci] = cn;
      hnext[b * 1024 + col] = sigm(go) * tanhx(cn);
    }
    ++bars; tree_barrier(bar, w, bars);

    // ---- phase B: dproj = h @ W_dec^T + b_dec (WGs 0..63) ----
    if (w < 64) {
      int bb = t >> 3, cl = t & 7;
      int cc = w * 8 + cl;
      const float* hrow = hnext + bb * 1024;
      const float* wrow = W_dec + (size_t)cc * 1024;
      float acc = 0.f;
#pragma unroll 4
      for (int q = 0; q < 256; ++q) {
        float4 h4 = *(const float4*)(hrow + q * 4);
        float4 w4 = *(const float4*)(wrow + q * 4);
        acc += h4.x * w4.x + h4.y * w4.y + h4.z * w4.z + h4.w * w4.w;
      }
      dproj[bb * 512 + cc] = acc + b_dec[cc];
    }
    ++bars; tree_barrier(bar, w, bars);

    // ---- phase C: scores + per-WG argmax partials (WG covers s=2w,2w+1) ----
    {
      int sc = t >> 2, ks = t & 3;
      int sl = sc >> 5, bb = sc & 31;
      int s = w * 2 + sl;
      const float* ep = enc_proj + ((size_t)s * 32 + bb) * 512 + ks * 128;
      const float* dp = dproj + bb * 512 + ks * 128;
      const float* wv = W_v + ks * 128;
      float sum = 0.f;
#pragma unroll 4
      for (int q = 0; q < 32; ++q) {
        float4 e4 = *(const float4*)(ep + q * 4);
        float4 d4 = *(const float4*)(dp + q * 4);
        float4 v4 = *(const float4*)(wv + q * 4);
        sum += tanhx(e4.x + d4.x) * v4.x;
        sum += tanhx(e4.y + d4.y) * v4.y;
        sum += tanhx(e4.z + d4.z) * v4.z;
        sum += tanhx(e4.w + d4.w) * v4.w;
      }
      sum += __shfl_xor(sum, 1);
      sum += __shfl_xor(sum, 2);
      if (ks == 0) {
        float sv = sum + b_v[0];
        out[((size_t)ts * 32 + bb) * 512 + s] = sv;
        svals[sl * 32 + bb] = sv;
      }
    }
    __syncthreads();
    if (t < 32) {
      float v0 = svals[t], v1 = svals[32 + t];
      float bv = v0; int bs = w * 2;
      if (v1 > v0) { bv = v1; bs = w * 2 + 1; }  // tie -> smaller s
      pval[w * 32 + t] = bv;
      pidx[w * 32 + t] = bs;
    }
    ++bars; tree_barrier(bar, w, bars);

    // ---- phase D: final argmax per batch (WG w<32 handles b=w) ----
    if (w < 32) {
      float v = pval[t * 32 + w];
      int si = pidx[t * 32 + w];
#pragma unroll
      for (int m = 1; m < 64; m <<= 1) {
        float ov = __shfl_xor(v, m);
        int os = __shfl_xor(si, m);
        if (ov > v || (ov == v && os < si)) { v = ov; si = os; }
      }
      int lane = t & 63, wid = t >> 6;
      if (lane == 0) { redv[wid] = v; redi[wid] = si; }
      __syncthreads();
      if (t == 0) {
        for (int i = 1; i < 4; ++i) {
          if (redv[i] > v || (redv[i] == v && redi[i] < si)) { v = redv[i]; si = redi[i]; }
        }
        idxbuf[w] = si;
      }
    }
    ++bars; tree_barrier(bar, w, bars);
  }
}

// ---------------------------------------------------------------------------
extern "C" void kernel_launch(void* const* d_in, const int* in_sizes, int n_in,
                              void* d_out, int out_size, void* d_ws, size_t ws_size,
                              hipStream_t stream) {
  (void)in_sizes; (void)n_in; (void)out_size; (void)ws_size;
  const float* feats = (const float*)d_in[0];
  const float* Wih_f = (const float*)d_in[1];
  const float* Whh_f = (const float*)d_in[2];
  const float* bih_f = (const float*)d_in[3];
  const float* bhh_f = (const float*)d_in[4];
  const float* Wih_b = (const float*)d_in[5];
  const float* Whh_b = (const float*)d_in[6];
  const float* bih_b = (const float*)d_in[7];
  const float* bhh_b = (const float*)d_in[8];
  const float* Wih_d = (const float*)d_in[9];
  const float* Whh_d = (const float*)d_in[10];
  const float* bih_d = (const float*)d_in[11];
  const float* bhh_d = (const float*)d_in[12];
  const float* W_enc = (const float*)d_in[13];
  const float* b_enc = (const float*)d_in[14];
  const float* W_dec = (const float*)d_in[15];
  const float* b_dec = (const float*)d_in[16];
  const float* W_v   = (const float*)d_in[17];
  const float* b_v   = (const float*)d_in[18];
  float* out = (float*)d_out;

  // ctrl ints: bar_enc @0 (4160 used), bar_dec @8192 (4160 used),
  // idxbuf @16352 (32). All zeroed below.
  int* ctrl = (int*)d_ws;
  int* bar_enc = ctrl;
  int* bar_dec = ctrl + 8192;
  int* idxbuf  = ctrl + 16352;
  float* base = (float*)d_ws + 16384;        // after 64 KiB ctrl block
  float* enc_proj = base;                    // 8,388,608
  float* henc     = enc_proj + 8388608;      //    65,536  [2dir][2pp][32][512]
  float* cfin     = henc + 65536;            //    32,768  [2dir][32][512]
  float* hbuf     = cfin + 32768;            //    65,536  [2][32][1024]
  float* dproj    = hbuf + 65536;            //    16,384
  float* pval     = dproj + 16384;           //     8,192
  int*   pidx     = (int*)(pval + 8192);     //     8,192 ints
  // total ~34.4 MB

  hipMemsetAsync(d_ws, 0, 65536, stream);

  {
    void* args[] = {(void*)&feats,
                    (void*)&Wih_f, (void*)&Whh_f, (void*)&bih_f, (void*)&bhh_f,
                    (void*)&Wih_b, (void*)&Whh_b, (void*)&bih_b, (void*)&bhh_b,
                    (void*)&W_enc, (void*)&b_enc,
                    (void*)&enc_proj, (void*)&henc, (void*)&cfin, (void*)&bar_enc};
    hipLaunchCooperativeKernel((const void*)encoder_kernel, dim3(NWG), dim3(256),
                               args, 0, stream);
  }
  {
    void* args[] = {(void*)&feats,
                    (void*)&Wih_d, (void*)&Whh_d, (void*)&bih_d, (void*)&bhh_d,
                    (void*)&W_dec, (void*)&b_dec, (void*)&W_v, (void*)&b_v,
                    (void*)&enc_proj, (void*)&henc, (void*)&cfin,
                    (void*)&hbuf, (void*)&dproj, (void*)&pval, (void*)&pidx,
                    (void*)&idxbuf, (void*)&bar_dec, (void*)&out};
    hipLaunchCooperativeKernel((const void*)decoder_kernel, dim3(NWG), dim3(256),
                               args, 0, stream);
  }
}

// Round 6
// 84967.401 us; speedup vs baseline: 1.0782x; 1.0238x over previous
//
#include <hip/hip_runtime.h>
#include <stdint.h>

// F=1024, H=512, S=512, B=32, T=128
// Round-4 verified compute; fences removed. Cross-WG shared data uses
// __hip_atomic_load/store(RELAXED, AGENT) (compiler-emitted coherent ops);
// read-only data (weights/feats) stays on plain cached loads.

#define NWG 256

__device__ __forceinline__ float sigm(float x) { return 1.0f / (1.0f + __expf(-x)); }
__device__ __forceinline__ float tanhx(float x) {
  float e = __expf(2.0f * x);
  return 1.0f - 2.0f / (e + 1.0f);
}

// coherent (agent-scope, L2-bypassing) scalar access helpers
__device__ __forceinline__ float ldc(const float* p) {
  return __hip_atomic_load(p, __ATOMIC_RELAXED, __HIP_MEMORY_SCOPE_AGENT);
}
__device__ __forceinline__ void stc(float* p, float v) {
  __hip_atomic_store(p, v, __ATOMIC_RELAXED, __HIP_MEMORY_SCOPE_AGENT);
}
__device__ __forceinline__ int ldci(const int* p) {
  return __hip_atomic_load(p, __ATOMIC_RELAXED, __HIP_MEMORY_SCOPE_AGENT);
}
__device__ __forceinline__ void stci(int* p, int v) {
  __hip_atomic_store(p, v, __ATOMIC_RELAXED, __HIP_MEMORY_SCOPE_AGENT);
}

// ---------------------------------------------------------------------------
// Two-level tree barrier, NO cache fences. Release: __syncthreads drains
// vmcnt(0) in every wave before the arrival atomic (all shared stores are
// agent-scope => already at the coherent point). Acquire: readers use
// agent-scope loads, which bypass any stale per-XCD L2.
// bar ints: gcnt[g]@g*64, root@2048, gflag[g]@2112+g*64; zeroed at launch.
// ---------------------------------------------------------------------------
__device__ __forceinline__ void tree_barrier(int* bar, int w, int epoch) {
  __syncthreads();
  if (threadIdx.x == 0) {
    const int g = w >> 3;
    int* gc = bar + g * 64;
    int* rc = bar + 2048;
    int* gf = bar + 2112 + g * 64;
    int old = __hip_atomic_fetch_add(gc, 1, __ATOMIC_RELAXED, __HIP_MEMORY_SCOPE_AGENT);
    if (old == epoch * 8 - 1) {  // group leader
      __hip_atomic_fetch_add(rc, 1, __ATOMIC_RELAXED, __HIP_MEMORY_SCOPE_AGENT);
      while (__hip_atomic_load(rc, __ATOMIC_RELAXED, __HIP_MEMORY_SCOPE_AGENT) < epoch * 32)
        __builtin_amdgcn_s_sleep(2);
      __hip_atomic_store(gf, epoch, __ATOMIC_RELAXED, __HIP_MEMORY_SCOPE_AGENT);
    } else {
      while (__hip_atomic_load(gf, __ATOMIC_RELAXED, __HIP_MEMORY_SCOPE_AGENT) < epoch)
        __builtin_amdgcn_s_sleep(2);
    }
  }
  __syncthreads();
}

// ---------------------------------------------------------------------------
// Encoder (cooperative, 256 WGs x 256 thr). WG<128: fwd, WG>=128: bwd.
// henc / enc_proj via coherent scalar ops; weights/feats plain (L2-warm).
// enc_proj first-store/second-add ordering rule (e<=255) as proven.
// ---------------------------------------------------------------------------
__global__ __launch_bounds__(256) void encoder_kernel(
    const float* __restrict__ feats,
    const float* __restrict__ Wih_f, const float* __restrict__ Whh_f,
    const float* __restrict__ bih_f, const float* __restrict__ bhh_f,
    const float* __restrict__ Wih_b, const float* __restrict__ Whh_b,
    const float* __restrict__ bih_b, const float* __restrict__ bhh_b,
    const float* __restrict__ W_enc, const float* __restrict__ b_enc,
    float* __restrict__ enc_proj, float* __restrict__ henc,
    float* __restrict__ cfin, int* __restrict__ bar)
{
  __shared__ float hch[32 * 132];
  __shared__ float wenc[4 * 516];
  __shared__ float gpart[32][17];
  __shared__ float projp[2][128];
  __shared__ float bias_s[16];
  __shared__ float benc_s[4];

  const int w = blockIdx.x;
  const int dir = (w >= 128) ? 1 : 0;
  const int wl = w & 127;
  const int col0 = wl * 4;
  const int t = threadIdx.x;
  const int kh = t >> 7;
  const int tt = t & 127;
  const int b = tt >> 2;
  const int ci = tt & 3;
  const int col = col0 + ci;

  const float* Wih = dir ? Wih_b : Wih_f;
  const float* Whh = dir ? Whh_b : Whh_f;
  const float* bih = dir ? bih_b : bih_f;
  const float* bhh = dir ? bhh_b : bhh_f;

  for (int i = t; i < 4 * 128; i += 256) {
    int jl = i >> 7, q = i & 127;
    *(float4*)(wenc + jl * 516 + q * 4) =
        *(const float4*)(W_enc + (size_t)(col0 + jl) * 1024 + dir * 512 + q * 4);
  }
  if (t < 16) {
    int g = t >> 2, cj = t & 3;
    bias_s[t] = bih[g * 512 + col0 + cj] + bhh[g * 512 + col0 + cj];
  }
  if (t < 4) benc_s[t] = b_enc[col0 + t];
  float c_reg = 0.0f;
  __syncthreads();

  const float* wx0 = Wih + (size_t)((kh * 2 + 0) * 512 + col) * 1024;
  const float* wx1 = Wih + (size_t)((kh * 2 + 1) * 512 + col) * 1024;
  const float* wh0 = Whh + (size_t)((kh * 2 + 0) * 512 + col) * 512;
  const float* wh1 = Whh + (size_t)((kh * 2 + 1) * 512 + col) * 512;

  for (int it = 0; it < 512; ++it) {
    const int s = dir ? (511 - it) : it;
    float accA = 0.0f, accB = 0.0f, projacc = 0.0f;

    if (it > 0) {
      const float* hsrc = henc + dir * 32768 + ((it - 1) & 1) * 16384;
      for (int ch = 0; ch < 4; ++ch) {
        // coherent staging of h chunk [32][128]
        for (int i = t; i < 1024; i += 256) {
          int bb = i >> 5, q = i & 31;
          const float* sp = hsrc + bb * 512 + ch * 128 + q * 4;
          float* dp = hch + bb * 132 + q * 4;
          dp[0] = ldc(sp + 0);
          dp[1] = ldc(sp + 1);
          dp[2] = ldc(sp + 2);
          dp[3] = ldc(sp + 3);
        }
        __syncthreads();
        {
          const float* hrow = hch + b * 132;
          const float* p0 = wh0 + ch * 128;
          const float* p1 = wh1 + ch * 128;
#pragma unroll 4
          for (int q = 0; q < 32; ++q) {
            float4 h4 = *(const float4*)(hrow + q * 4);
            float4 a4 = *(const float4*)(p0 + q * 4);
            float4 b4 = *(const float4*)(p1 + q * 4);
            accA += h4.x * a4.x + h4.y * a4.y + h4.z * a4.z + h4.w * a4.w;
            accB += h4.x * b4.x + h4.y * b4.y + h4.z * b4.z + h4.w * b4.w;
          }
        }
        {
          const float* hp = hch + b * 132 + kh * 64;
          const float* wp = wenc + ci * 516 + ch * 128 + kh * 64;
#pragma unroll 4
          for (int kk = 0; kk < 16; ++kk) {
            float4 h4 = *(const float4*)(hp + kk * 4);
            float4 w4 = *(const float4*)(wp + kk * 4);
            projacc += h4.x * w4.x + h4.y * w4.y + h4.z * w4.z + h4.w * w4.w;
          }
        }
        __syncthreads();
      }
    }

    // x-part: plain cached (read-only, L2-warm)
    {
      const float* frow = feats + ((size_t)s * 32 + b) * 1024;
#pragma unroll 4
      for (int q = 0; q < 256; ++q) {
        float4 f4 = *(const float4*)(frow + q * 4);
        float4 a4 = *(const float4*)(wx0 + q * 4);
        float4 b4 = *(const float4*)(wx1 + q * 4);
        accA += f4.x * a4.x + f4.y * a4.y + f4.z * a4.z + f4.w * a4.w;
        accB += f4.x * b4.x + f4.y * b4.y + f4.z * b4.z + f4.w * b4.w;
      }
    }
    gpart[b][(kh * 2 + 0) * 4 + ci] = accA;
    gpart[b][(kh * 2 + 1) * 4 + ci] = accB;
    projp[kh][tt] = projacc;
    __syncthreads();
    if (kh == 0) {
      float gi = gpart[b][ci + 0] + bias_s[ci + 0];
      float gf = gpart[b][ci + 4] + bias_s[ci + 4];
      float gg = gpart[b][ci + 8] + bias_s[ci + 8];
      float go = gpart[b][ci + 12] + bias_s[ci + 12];
      float cn = sigm(gf) * c_reg + sigm(gi) * tanhx(gg);
      c_reg = cn;
      stc(henc + dir * 32768 + (it & 1) * 16384 + b * 512 + col,
          sigm(go) * tanhx(cn));
    } else if (it > 0) {
      const int sp = dir ? (512 - it) : (it - 1);
      const float p = projp[0][tt] + projp[1][tt];
      float* addr = enc_proj + ((size_t)sp * 32 + b) * 512 + col;
      if (it - 1 <= 255) {
        stc(addr, p + benc_s[ci]);
      } else {
        stc(addr, ldc(addr) + p);
      }
    }
    tree_barrier(bar, w, it + 1);
  }

  // post-loop: proj for e=511 (always second arriver), and cfin
  {
    const float* hsrc = henc + dir * 32768 + 16384;  // pp = 511&1 = 1
    float projacc = 0.0f;
    for (int ch = 0; ch < 4; ++ch) {
      for (int i = t; i < 1024; i += 256) {
        int bb = i >> 5, q = i & 31;
        const float* sp = hsrc + bb * 512 + ch * 128 + q * 4;
        float* dp = hch + bb * 132 + q * 4;
        dp[0] = ldc(sp + 0);
        dp[1] = ldc(sp + 1);
        dp[2] = ldc(sp + 2);
        dp[3] = ldc(sp + 3);
      }
      __syncthreads();
      const float* hp = hch + b * 132 + kh * 64;
      const float* wp = wenc + ci * 516 + ch * 128 + kh * 64;
#pragma unroll 4
      for (int kk = 0; kk < 16; ++kk) {
        float4 h4 = *(const float4*)(hp + kk * 4);
        float4 w4 = *(const float4*)(wp + kk * 4);
        projacc += h4.x * w4.x + h4.y * w4.y + h4.z * w4.z + h4.w * w4.w;
      }
      __syncthreads();
    }
    projp[kh][tt] = projacc;
    __syncthreads();
    if (kh == 1) {
      const int sp = dir ? 0 : 511;
      float* addr = enc_proj + ((size_t)sp * 32 + b) * 512 + col;
      stc(addr, ldc(addr) + (projp[0][tt] + projp[1][tt]));
    }
    if (kh == 0) cfin[dir * 16384 + b * 512 + col] = c_reg;  // cross-kernel only
  }
}

// ---------------------------------------------------------------------------
// Decoder (cooperative, 256 WGs x 256 thr), 128 steps, 4 tree barriers/step.
// hbuf/dproj/pval/pidx/idxbuf coherent; weights/feats/enc_proj plain cached.
// ---------------------------------------------------------------------------
__global__ __launch_bounds__(256) void decoder_kernel(
    const float* __restrict__ feats,
    const float* __restrict__ Wih_d, const float* __restrict__ Whh_d,
    const float* __restrict__ bih_d, const float* __restrict__ bhh_d,
    const float* __restrict__ W_dec, const float* __restrict__ b_dec,
    const float* __restrict__ W_v, const float* __restrict__ b_v,
    const float* __restrict__ enc_proj, const float* __restrict__ henc,
    const float* __restrict__ cfin,
    float* __restrict__ hbuf, float* __restrict__ dproj,
    float* __restrict__ pval, int* __restrict__ pidx,
    int* __restrict__ idxbuf, int* __restrict__ bar,
    float* __restrict__ out)
{
  __shared__ float gpart[2][32][17];
  __shared__ float c_lds[32][4];
  __shared__ float bias_s[16];
  __shared__ float svals[64];
  __shared__ float redv[4];
  __shared__ int redi[4];

  const int w = blockIdx.x;
  const int t = threadIdx.x;
  const int kh = t >> 7;
  const int tt = t & 127;
  const int b = tt >> 2;
  const int ci = tt & 3;
  const int col0 = w * 4;
  const int col = col0 + ci;

  if (t < 16) {
    int g = t >> 2, cj = t & 3;
    bias_s[t] = bih_d[g * 1024 + col0 + cj] + bhh_d[g * 1024 + col0 + cj];
  }
  // h0/c0 (torch .view() reshape); henc/cfin cross-kernel (plain loads ok)
  if (kh == 0) {
    int flat = b * 1024 + col;
    int d = flat >> 14, sb = (flat >> 9) & 31, sh = flat & 511;
    float h0, c0;
    if (d == 0) {
      h0 = henc[16384 + sb * 512 + sh];
      c0 = cfin[sb * 512 + sh];
    } else {
      h0 = henc[32768 + 16384 + sb * 512 + sh];
      c0 = cfin[16384 + sb * 512 + sh];
    }
    stc(hbuf + b * 1024 + col, h0);
    c_lds[b][ci] = c0;
  }
  int bars = 1;
  tree_barrier(bar, w, bars);

  const float* wh0 = Whh_d + (size_t)(0 * 1024 + col) * 1024;
  const float* wh1 = Whh_d + (size_t)(1 * 1024 + col) * 1024;
  const float* wh2 = Whh_d + (size_t)(2 * 1024 + col) * 1024;
  const float* wh3 = Whh_d + (size_t)(3 * 1024 + col) * 1024;
  const float* wi0 = Wih_d + (size_t)(0 * 1024 + col) * 1024;
  const float* wi1 = Wih_d + (size_t)(1 * 1024 + col) * 1024;
  const float* wi2 = Wih_d + (size_t)(2 * 1024 + col) * 1024;
  const float* wi3 = Wih_d + (size_t)(3 * 1024 + col) * 1024;

  for (int ts = 0; ts < 128; ++ts) {
    const float* hprev = hbuf + (ts & 1) * 32768;
    float* hnext = hbuf + ((ts + 1) & 1) * 32768;

    // ---- phase A: gates GEMM + cell ----
    float a0 = 0.f, a1 = 0.f, a2 = 0.f, a3 = 0.f;
    if (kh == 0) {
      const float* hrow = hprev + b * 1024;
#pragma unroll 2
      for (int q = 0; q < 256; ++q) {
        float hx = ldc(hrow + q * 4 + 0);
        float hy = ldc(hrow + q * 4 + 1);
        float hz = ldc(hrow + q * 4 + 2);
        float hw = ldc(hrow + q * 4 + 3);
        float4 v0 = *(const float4*)(wh0 + q * 4);
        float4 v1 = *(const float4*)(wh1 + q * 4);
        float4 v2 = *(const float4*)(wh2 + q * 4);
        float4 v3 = *(const float4*)(wh3 + q * 4);
        a0 += hx * v0.x + hy * v0.y + hz * v0.z + hw * v0.w;
        a1 += hx * v1.x + hy * v1.y + hz * v1.z + hw * v1.w;
        a2 += hx * v2.x + hy * v2.y + hz * v2.z + hw * v2.w;
        a3 += hx * v3.x + hy * v3.y + hz * v3.z + hw * v3.w;
      }
    } else {
      int ib = ldci(idxbuf + b);
      const float* xrow = feats + ((size_t)ib * 32 + b) * 1024;
#pragma unroll 2
      for (int q = 0; q < 256; ++q) {
        float4 x4 = *(const float4*)(xrow + q * 4);
        float4 v0 = *(const float4*)(wi0 + q * 4);
        float4 v1 = *(const float4*)(wi1 + q * 4);
        float4 v2 = *(const float4*)(wi2 + q * 4);
        float4 v3 = *(const float4*)(wi3 + q * 4);
        a0 += x4.x * v0.x + x4.y * v0.y + x4.z * v0.z + x4.w * v0.w;
        a1 += x4.x * v1.x + x4.y * v1.y + x4.z * v1.z + x4.w * v1.w;
        a2 += x4.x * v2.x + x4.y * v2.y + x4.z * v2.z + x4.w * v2.w;
        a3 += x4.x * v3.x + x4.y * v3.y + x4.z * v3.z + x4.w * v3.w;
      }
    }
    gpart[kh][b][ci + 0] = a0;
    gpart[kh][b][ci + 4] = a1;
    gpart[kh][b][ci + 8] = a2;
    gpart[kh][b][ci + 12] = a3;
    __syncthreads();
    if (kh == 0) {
      float gi = gpart[0][b][ci + 0] + gpart[1][b][ci + 0] + bias_s[ci + 0];
      float gf = gpart[0][b][ci + 4] + gpart[1][b][ci + 4] + bias_s[ci + 4];
      float gg = gpart[0][b][ci + 8] + gpart[1][b][ci + 8] + bias_s[ci + 8];
      float go = gpart[0][b][ci + 12] + gpart[1][b][ci + 12] + bias_s[ci + 12];
      float cn = sigm(gf) * c_lds[b][ci] + sigm(gi) * tanhx(gg);
      c_lds[b][ci] = cn;
      stc(hnext + b * 1024 + col, sigm(go) * tanhx(cn));
    }
    ++bars; tree_barrier(bar, w, bars);

    // ---- phase B: dproj = h @ W_dec^T + b_dec (WGs 0..63) ----
    if (w < 64) {
      int bb = t >> 3, cl = t & 7;
      int cc = w * 8 + cl;
      const float* hrow = hnext + bb * 1024;
      const float* wrow = W_dec + (size_t)cc * 1024;
      float acc = 0.f;
#pragma unroll 4
      for (int q = 0; q < 256; ++q) {
        float hx = ldc(hrow + q * 4 + 0);
        float hy = ldc(hrow + q * 4 + 1);
        float hz = ldc(hrow + q * 4 + 2);
        float hw = ldc(hrow + q * 4 + 3);
        float4 w4 = *(const float4*)(wrow + q * 4);
        acc += hx * w4.x + hy * w4.y + hz * w4.z + hw * w4.w;
      }
      stc(dproj + bb * 512 + cc, acc + b_dec[cc]);
    }
    ++bars; tree_barrier(bar, w, bars);

    // ---- phase C: scores + per-WG argmax partials (WG covers s=2w,2w+1) ----
    {
      int sc = t >> 2, ks = t & 3;
      int sl = sc >> 5, bb = sc & 31;
      int s = w * 2 + sl;
      const float* ep = enc_proj + ((size_t)s * 32 + bb) * 512 + ks * 128;
      const float* dp = dproj + bb * 512 + ks * 128;
      const float* wvv = W_v + ks * 128;
      float sum = 0.f;
#pragma unroll 4
      for (int q = 0; q < 32; ++q) {
        float dx = ldc(dp + q * 4 + 0);
        float dy = ldc(dp + q * 4 + 1);
        float dz = ldc(dp + q * 4 + 2);
        float dw = ldc(dp + q * 4 + 3);
        float4 e4 = *(const float4*)(ep + q * 4);
        float4 v4 = *(const float4*)(wvv + q * 4);
        sum += tanhx(e4.x + dx) * v4.x;
        sum += tanhx(e4.y + dy) * v4.y;
        sum += tanhx(e4.z + dz) * v4.z;
        sum += tanhx(e4.w + dw) * v4.w;
      }
      sum += __shfl_xor(sum, 1);
      sum += __shfl_xor(sum, 2);
      if (ks == 0) {
        float sv = sum + b_v[0];
        out[((size_t)ts * 32 + bb) * 512 + s] = sv;  // host-read only: plain
        svals[sl * 32 + bb] = sv;
      }
    }
    __syncthreads();
    if (t < 32) {
      float v0 = svals[t], v1 = svals[32 + t];
      float bv = v0; int bs = w * 2;
      if (v1 > v0) { bv = v1; bs = w * 2 + 1; }  // tie -> smaller s
      stc(pval + w * 32 + t, bv);
      stci(pidx + w * 32 + t, bs);
    }
    ++bars; tree_barrier(bar, w, bars);

    // ---- phase D: final argmax per batch (WG w<32 handles b=w) ----
    if (w < 32) {
      float v = ldc(pval + t * 32 + w);
      int si = ldci(pidx + t * 32 + w);
#pragma unroll
      for (int m = 1; m < 64; m <<= 1) {
        float ov = __shfl_xor(v, m);
        int os = __shfl_xor(si, m);
        if (ov > v || (ov == v && os < si)) { v = ov; si = os; }
      }
      int lane = t & 63, wid = t >> 6;
      if (lane == 0) { redv[wid] = v; redi[wid] = si; }
      __syncthreads();
      if (t == 0) {
        for (int i = 1; i < 4; ++i) {
          if (redv[i] > v || (redv[i] == v && redi[i] < si)) { v = redv[i]; si = redi[i]; }
        }
        stci(idxbuf + w, si);
      }
    }
    ++bars; tree_barrier(bar, w, bars);
  }
}

// ---------------------------------------------------------------------------
extern "C" void kernel_launch(void* const* d_in, const int* in_sizes, int n_in,
                              void* d_out, int out_size, void* d_ws, size_t ws_size,
                              hipStream_t stream) {
  (void)in_sizes; (void)n_in; (void)out_size; (void)ws_size;
  const float* feats = (const float*)d_in[0];
  const float* Wih_f = (const float*)d_in[1];
  const float* Whh_f = (const float*)d_in[2];
  const float* bih_f = (const float*)d_in[3];
  const float* bhh_f = (const float*)d_in[4];
  const float* Wih_b = (const float*)d_in[5];
  const float* Whh_b = (const float*)d_in[6];
  const float* bih_b = (const float*)d_in[7];
  const float* bhh_b = (const float*)d_in[8];
  const float* Wih_d = (const float*)d_in[9];
  const float* Whh_d = (const float*)d_in[10];
  const float* bih_d = (const float*)d_in[11];
  const float* bhh_d = (const float*)d_in[12];
  const float* W_enc = (const float*)d_in[13];
  const float* b_enc = (const float*)d_in[14];
  const float* W_dec = (const float*)d_in[15];
  const float* b_dec = (const float*)d_in[16];
  const float* W_v   = (const float*)d_in[17];
  const float* b_v   = (const float*)d_in[18];
  float* out = (float*)d_out;

  int* ctrl = (int*)d_ws;
  int* bar_enc = ctrl;
  int* bar_dec = ctrl + 8192;
  int* idxbuf  = ctrl + 16352;
  float* base = (float*)d_ws + 16384;        // after 64 KiB ctrl block
  float* enc_proj = base;                    // 8,388,608
  float* henc     = enc_proj + 8388608;      //    65,536  [2dir][2pp][32][512]
  float* cfin     = henc + 65536;            //    32,768  [2dir][32][512]
  float* hbuf     = cfin + 32768;            //    65,536  [2][32][1024]
  float* dproj    = hbuf + 65536;            //    16,384
  float* pval     = dproj + 16384;           //     8,192
  int*   pidx     = (int*)(pval + 8192);     //     8,192 ints
  // total ~34.4 MB

  hipMemsetAsync(d_ws, 0, 65536, stream);

  {
    void* args[] = {(void*)&feats,
                    (void*)&Wih_f, (void*)&Whh_f, (void*)&bih_f, (void*)&bhh_f,
                    (void*)&Wih_b, (void*)&Whh_b, (void*)&bih_b, (void*)&bhh_b,
                    (void*)&W_enc, (void*)&b_enc,
                    (void*)&enc_proj, (void*)&henc, (void*)&cfin, (void*)&bar_enc};
    hipLaunchCooperativeKernel((const void*)encoder_kernel, dim3(NWG), dim3(256),
                               args, 0, stream);
  }
  {
    void* args[] = {(void*)&feats,
                    (void*)&Wih_d, (void*)&Whh_d, (void*)&bih_d, (void*)&bhh_d,
                    (void*)&W_dec, (void*)&b_dec, (void*)&W_v, (void*)&b_v,
                    (void*)&enc_proj, (void*)&henc, (void*)&cfin,
                    (void*)&hbuf, (void*)&dproj, (void*)&pval, (void*)&pidx,
                    (void*)&idxbuf, (void*)&bar_dec, (void*)&out};
    hipLaunchCooperativeKernel((const void*)decoder_kernel, dim3(NWG), dim3(256),
                               args, 0, stream);
  }
}

// Round 7
// 34781.229 us; speedup vs baseline: 2.6340x; 2.4429x over previous
//
#include <hip/hip_runtime.h>
#include <stdint.h>

// F=1024, H=512, S=512, B=32, T=128
// Round-6 verified structure. ONE concept changed: per-WG weight slices are
// preloaded ONCE into dynamic LDS (they are re-read every step and exceed
// per-XCD L2 => were re-streamed from L3/HBM each step). Plus mechanical:
// coherent staging via 8-byte agent atomic loads (restores float4 LDS writes).

#define NWG 256

__device__ __forceinline__ float sigm(float x) { return 1.0f / (1.0f + __expf(-x)); }
__device__ __forceinline__ float tanhx(float x) {
  float e = __expf(2.0f * x);
  return 1.0f - 2.0f / (e + 1.0f);
}

// coherent (agent-scope) access helpers
__device__ __forceinline__ float ldc(const float* p) {
  return __hip_atomic_load(p, __ATOMIC_RELAXED, __HIP_MEMORY_SCOPE_AGENT);
}
__device__ __forceinline__ float2 ldc2(const float* p) {  // 8B coherent load
  double d = __hip_atomic_load((const double*)p, __ATOMIC_RELAXED, __HIP_MEMORY_SCOPE_AGENT);
  return __builtin_bit_cast(float2, d);
}
__device__ __forceinline__ void stc(float* p, float v) {
  __hip_atomic_store(p, v, __ATOMIC_RELAXED, __HIP_MEMORY_SCOPE_AGENT);
}
__device__ __forceinline__ int ldci(const int* p) {
  return __hip_atomic_load(p, __ATOMIC_RELAXED, __HIP_MEMORY_SCOPE_AGENT);
}
__device__ __forceinline__ void stci(int* p, int v) {
  __hip_atomic_store(p, v, __ATOMIC_RELAXED, __HIP_MEMORY_SCOPE_AGENT);
}

// two-level tree barrier (unchanged from round 6)
__device__ __forceinline__ void tree_barrier(int* bar, int w, int epoch) {
  __syncthreads();
  if (threadIdx.x == 0) {
    const int g = w >> 3;
    int* gc = bar + g * 64;
    int* rc = bar + 2048;
    int* gf = bar + 2112 + g * 64;
    int old = __hip_atomic_fetch_add(gc, 1, __ATOMIC_RELAXED, __HIP_MEMORY_SCOPE_AGENT);
    if (old == epoch * 8 - 1) {
      __hip_atomic_fetch_add(rc, 1, __ATOMIC_RELAXED, __HIP_MEMORY_SCOPE_AGENT);
      while (__hip_atomic_load(rc, __ATOMIC_RELAXED, __HIP_MEMORY_SCOPE_AGENT) < epoch * 32)
        __builtin_amdgcn_s_sleep(2);
      __hip_atomic_store(gf, epoch, __ATOMIC_RELAXED, __HIP_MEMORY_SCOPE_AGENT);
    } else {
      while (__hip_atomic_load(gf, __ATOMIC_RELAXED, __HIP_MEMORY_SCOPE_AGENT) < epoch)
        __builtin_amdgcn_s_sleep(2);
    }
  }
  __syncthreads();
}

// ---------------------------------------------------------------------------
// Encoder. Dynamic LDS: wih_l[16][1028] (64+ KB), whh_l[16][516] (33 KB).
// Row r = g*4+cj holds global gate row (g*512 + col0 + cj). Strides 1028/516
// => row r starts at bank 4r%32: the wave's 8 distinct rows are conflict-free.
// ---------------------------------------------------------------------------
__global__ __launch_bounds__(256) void encoder_kernel(
    const float* __restrict__ feats,
    const float* __restrict__ Wih_f, const float* __restrict__ Whh_f,
    const float* __restrict__ bih_f, const float* __restrict__ bhh_f,
    const float* __restrict__ Wih_b, const float* __restrict__ Whh_b,
    const float* __restrict__ bih_b, const float* __restrict__ bhh_b,
    const float* __restrict__ W_enc, const float* __restrict__ b_enc,
    float* __restrict__ enc_proj, float* __restrict__ henc,
    float* __restrict__ cfin, int* __restrict__ bar)
{
  extern __shared__ __align__(16) float dyn[];
  float* wih_l = dyn;            // 16 * 1028
  float* whh_l = dyn + 16448;    // 16 * 516
  __shared__ float hch[32 * 132];
  __shared__ float wenc[4 * 516];
  __shared__ float gpart[32][17];
  __shared__ float projp[2][128];
  __shared__ float bias_s[16];
  __shared__ float benc_s[4];

  const int w = blockIdx.x;
  const int dir = (w >= 128) ? 1 : 0;
  const int wl = w & 127;
  const int col0 = wl * 4;
  const int t = threadIdx.x;
  const int kh = t >> 7;
  const int tt = t & 127;
  const int b = tt >> 2;
  const int ci = tt & 3;
  const int col = col0 + ci;

  const float* Wih = dir ? Wih_b : Wih_f;
  const float* Whh = dir ? Whh_b : Whh_f;
  const float* bih = dir ? bih_b : bih_f;
  const float* bhh = dir ? bhh_b : bhh_f;

  // one-time weight preloads into LDS
  for (int i = t; i < 16 * 256; i += 256) {        // Wih slice: 16 rows x 1024
    int r = i >> 8, q = i & 255;
    int g = r >> 2, cj = r & 3;
    *(float4*)(wih_l + r * 1028 + q * 4) =
        *(const float4*)(Wih + (size_t)(g * 512 + col0 + cj) * 1024 + q * 4);
  }
  for (int i = t; i < 16 * 128; i += 256) {        // Whh slice: 16 rows x 512
    int r = i >> 7, q = i & 127;
    int g = r >> 2, cj = r & 3;
    *(float4*)(whh_l + r * 516 + q * 4) =
        *(const float4*)(Whh + (size_t)(g * 512 + col0 + cj) * 512 + q * 4);
  }
  for (int i = t; i < 4 * 128; i += 256) {
    int jl = i >> 7, q = i & 127;
    *(float4*)(wenc + jl * 516 + q * 4) =
        *(const float4*)(W_enc + (size_t)(col0 + jl) * 1024 + dir * 512 + q * 4);
  }
  if (t < 16) {
    int g = t >> 2, cj = t & 3;
    bias_s[t] = bih[g * 512 + col0 + cj] + bhh[g * 512 + col0 + cj];
  }
  if (t < 4) benc_s[t] = b_enc[col0 + t];
  float c_reg = 0.0f;
  __syncthreads();

  // this thread's weight rows, now in LDS (r = g*4 + ci)
  const float* wx0 = wih_l + (size_t)((kh * 2 + 0) * 4 + ci) * 1028;
  const float* wx1 = wih_l + (size_t)((kh * 2 + 1) * 4 + ci) * 1028;
  const float* wh0 = whh_l + (size_t)((kh * 2 + 0) * 4 + ci) * 516;
  const float* wh1 = whh_l + (size_t)((kh * 2 + 1) * 4 + ci) * 516;

  for (int it = 0; it < 512; ++it) {
    const int s = dir ? (511 - it) : it;
    float accA = 0.0f, accB = 0.0f, projacc = 0.0f;

    if (it > 0) {
      const float* hsrc = henc + dir * 32768 + ((it - 1) & 1) * 16384;
      for (int ch = 0; ch < 4; ++ch) {
        // coherent staging of h chunk [32][128] (8B loads -> float4 writes)
        for (int i = t; i < 1024; i += 256) {
          int bb = i >> 5, q = i & 31;
          const float* sp = hsrc + bb * 512 + ch * 128 + q * 4;
          float2 f0 = ldc2(sp);
          float2 f1 = ldc2(sp + 2);
          *(float4*)(hch + bb * 132 + q * 4) = make_float4(f0.x, f0.y, f1.x, f1.y);
        }
        __syncthreads();
        {
          const float* hrow = hch + b * 132;
          const float* p0 = wh0 + ch * 128;
          const float* p1 = wh1 + ch * 128;
#pragma unroll 4
          for (int q = 0; q < 32; ++q) {
            float4 h4 = *(const float4*)(hrow + q * 4);
            float4 a4 = *(const float4*)(p0 + q * 4);
            float4 b4 = *(const float4*)(p1 + q * 4);
            accA += h4.x * a4.x + h4.y * a4.y + h4.z * a4.z + h4.w * a4.w;
            accB += h4.x * b4.x + h4.y * b4.y + h4.z * b4.z + h4.w * b4.w;
          }
        }
        {
          const float* hp = hch + b * 132 + kh * 64;
          const float* wp = wenc + ci * 516 + ch * 128 + kh * 64;
#pragma unroll 4
          for (int kk = 0; kk < 16; ++kk) {
            float4 h4 = *(const float4*)(hp + kk * 4);
            float4 w4 = *(const float4*)(wp + kk * 4);
            projacc += h4.x * w4.x + h4.y * w4.y + h4.z * w4.z + h4.w * w4.w;
          }
        }
        __syncthreads();
      }
    }

    // x-part: weights from LDS, feats plain cached
    {
      const float* frow = feats + ((size_t)s * 32 + b) * 1024;
#pragma unroll 4
      for (int q = 0; q < 256; ++q) {
        float4 f4 = *(const float4*)(frow + q * 4);
        float4 a4 = *(const float4*)(wx0 + q * 4);
        float4 b4 = *(const float4*)(wx1 + q * 4);
        accA += f4.x * a4.x + f4.y * a4.y + f4.z * a4.z + f4.w * a4.w;
        accB += f4.x * b4.x + f4.y * b4.y + f4.z * b4.z + f4.w * b4.w;
      }
    }
    gpart[b][(kh * 2 + 0) * 4 + ci] = accA;
    gpart[b][(kh * 2 + 1) * 4 + ci] = accB;
    projp[kh][tt] = projacc;
    __syncthreads();
    if (kh == 0) {
      float gi = gpart[b][ci + 0] + bias_s[ci + 0];
      float gf = gpart[b][ci + 4] + bias_s[ci + 4];
      float gg = gpart[b][ci + 8] + bias_s[ci + 8];
      float go = gpart[b][ci + 12] + bias_s[ci + 12];
      float cn = sigm(gf) * c_reg + sigm(gi) * tanhx(gg);
      c_reg = cn;
      stc(henc + dir * 32768 + (it & 1) * 16384 + b * 512 + col,
          sigm(go) * tanhx(cn));
    } else if (it > 0) {
      const int sp = dir ? (512 - it) : (it - 1);
      const float p = projp[0][tt] + projp[1][tt];
      float* addr = enc_proj + ((size_t)sp * 32 + b) * 512 + col;
      if (it - 1 <= 255) {
        stc(addr, p + benc_s[ci]);
      } else {
        stc(addr, ldc(addr) + p);
      }
    }
    tree_barrier(bar, w, it + 1);
  }

  // post-loop: proj for e=511 (always second arriver), and cfin
  {
    const float* hsrc = henc + dir * 32768 + 16384;
    float projacc = 0.0f;
    for (int ch = 0; ch < 4; ++ch) {
      for (int i = t; i < 1024; i += 256) {
        int bb = i >> 5, q = i & 31;
        const float* sp = hsrc + bb * 512 + ch * 128 + q * 4;
        float2 f0 = ldc2(sp);
        float2 f1 = ldc2(sp + 2);
        *(float4*)(hch + bb * 132 + q * 4) = make_float4(f0.x, f0.y, f1.x, f1.y);
      }
      __syncthreads();
      const float* hp = hch + b * 132 + kh * 64;
      const float* wp = wenc + ci * 516 + ch * 128 + kh * 64;
#pragma unroll 4
      for (int kk = 0; kk < 16; ++kk) {
        float4 h4 = *(const float4*)(hp + kk * 4);
        float4 w4 = *(const float4*)(wp + kk * 4);
        projacc += h4.x * w4.x + h4.y * w4.y + h4.z * w4.z + h4.w * w4.w;
      }
      __syncthreads();
    }
    projp[kh][tt] = projacc;
    __syncthreads();
    if (kh == 1) {
      const int sp = dir ? 0 : 511;
      float* addr = enc_proj + ((size_t)sp * 32 + b) * 512 + col;
      stc(addr, ldc(addr) + (projp[0][tt] + projp[1][tt]));
    }
    if (kh == 0) cfin[dir * 16384 + b * 512 + col] = c_reg;
  }
}

// ---------------------------------------------------------------------------
// Decoder. Dynamic LDS: whh_l[16][1028] + wih_l[16][1028] = 131.6 KB.
// Row r = g*4+cj holds global gate row (g*1024 + col0 + cj).
// ---------------------------------------------------------------------------
__global__ __launch_bounds__(256) void decoder_kernel(
    const float* __restrict__ feats,
    const float* __restrict__ Wih_d, const float* __restrict__ Whh_d,
    const float* __restrict__ bih_d, const float* __restrict__ bhh_d,
    const float* __restrict__ W_dec, const float* __restrict__ b_dec,
    const float* __restrict__ W_v, const float* __restrict__ b_v,
    const float* __restrict__ enc_proj, const float* __restrict__ henc,
    const float* __restrict__ cfin,
    float* __restrict__ hbuf, float* __restrict__ dproj,
    float* __restrict__ pval, int* __restrict__ pidx,
    int* __restrict__ idxbuf, int* __restrict__ bar,
    float* __restrict__ out)
{
  extern __shared__ __align__(16) float dyn[];
  float* whh_l = dyn;            // 16 * 1028
  float* wih_l = dyn + 16448;    // 16 * 1028
  __shared__ float gpart[2][32][17];
  __shared__ float c_lds[32][4];
  __shared__ float bias_s[16];
  __shared__ float svals[64];
  __shared__ float redv[4];
  __shared__ int redi[4];

  const int w = blockIdx.x;
  const int t = threadIdx.x;
  const int kh = t >> 7;
  const int tt = t & 127;
  const int b = tt >> 2;
  const int ci = tt & 3;
  const int col0 = w * 4;
  const int col = col0 + ci;

  // one-time weight preloads
  for (int i = t; i < 16 * 256; i += 256) {
    int r = i >> 8, q = i & 255;
    int g = r >> 2, cj = r & 3;
    *(float4*)(whh_l + r * 1028 + q * 4) =
        *(const float4*)(Whh_d + (size_t)(g * 1024 + col0 + cj) * 1024 + q * 4);
    *(float4*)(wih_l + r * 1028 + q * 4) =
        *(const float4*)(Wih_d + (size_t)(g * 1024 + col0 + cj) * 1024 + q * 4);
  }
  if (t < 16) {
    int g = t >> 2, cj = t & 3;
    bias_s[t] = bih_d[g * 1024 + col0 + cj] + bhh_d[g * 1024 + col0 + cj];
  }
  if (kh == 0) {
    int flat = b * 1024 + col;
    int d = flat >> 14, sb = (flat >> 9) & 31, sh = flat & 511;
    float h0, c0;
    if (d == 0) {
      h0 = henc[16384 + sb * 512 + sh];
      c0 = cfin[sb * 512 + sh];
    } else {
      h0 = henc[32768 + 16384 + sb * 512 + sh];
      c0 = cfin[16384 + sb * 512 + sh];
    }
    stc(hbuf + b * 1024 + col, h0);
    c_lds[b][ci] = c0;
  }
  int bars = 1;
  tree_barrier(bar, w, bars);

  const float* wh0 = whh_l + (size_t)(0 * 4 + ci) * 1028;
  const float* wh1 = whh_l + (size_t)(1 * 4 + ci) * 1028;
  const float* wh2 = whh_l + (size_t)(2 * 4 + ci) * 1028;
  const float* wh3 = whh_l + (size_t)(3 * 4 + ci) * 1028;
  const float* wi0 = wih_l + (size_t)(0 * 4 + ci) * 1028;
  const float* wi1 = wih_l + (size_t)(1 * 4 + ci) * 1028;
  const float* wi2 = wih_l + (size_t)(2 * 4 + ci) * 1028;
  const float* wi3 = wih_l + (size_t)(3 * 4 + ci) * 1028;

  for (int ts = 0; ts < 128; ++ts) {
    const float* hprev = hbuf + (ts & 1) * 32768;
    float* hnext = hbuf + ((ts + 1) & 1) * 32768;

    // ---- phase A: gates GEMM + cell ----
    float a0 = 0.f, a1 = 0.f, a2 = 0.f, a3 = 0.f;
    if (kh == 0) {
      const float* hrow = hprev + b * 1024;
#pragma unroll 2
      for (int q = 0; q < 256; ++q) {
        float2 h01 = ldc2(hrow + q * 4);
        float2 h23 = ldc2(hrow + q * 4 + 2);
        float4 v0 = *(const float4*)(wh0 + q * 4);
        float4 v1 = *(const float4*)(wh1 + q * 4);
        float4 v2 = *(const float4*)(wh2 + q * 4);
        float4 v3 = *(const float4*)(wh3 + q * 4);
        a0 += h01.x * v0.x + h01.y * v0.y + h23.x * v0.z + h23.y * v0.w;
        a1 += h01.x * v1.x + h01.y * v1.y + h23.x * v1.z + h23.y * v1.w;
        a2 += h01.x * v2.x + h01.y * v2.y + h23.x * v2.z + h23.y * v2.w;
        a3 += h01.x * v3.x + h01.y * v3.y + h23.x * v3.z + h23.y * v3.w;
      }
    } else {
      int ib = ldci(idxbuf + b);
      const float* xrow = feats + ((size_t)ib * 32 + b) * 1024;
#pragma unroll 2
      for (int q = 0; q < 256; ++q) {
        float4 x4 = *(const float4*)(xrow + q * 4);
        float4 v0 = *(const float4*)(wi0 + q * 4);
        float4 v1 = *(const float4*)(wi1 + q * 4);
        float4 v2 = *(const float4*)(wi2 + q * 4);
        float4 v3 = *(const float4*)(wi3 + q * 4);
        a0 += x4.x * v0.x + x4.y * v0.y + x4.z * v0.z + x4.w * v0.w;
        a1 += x4.x * v1.x + x4.y * v1.y + x4.z * v1.z + x4.w * v1.w;
        a2 += x4.x * v2.x + x4.y * v2.y + x4.z * v2.z + x4.w * v2.w;
        a3 += x4.x * v3.x + x4.y * v3.y + x4.z * v3.z + x4.w * v3.w;
      }
    }
    gpart[kh][b][ci + 0] = a0;
    gpart[kh][b][ci + 4] = a1;
    gpart[kh][b][ci + 8] = a2;
    gpart[kh][b][ci + 12] = a3;
    __syncthreads();
    if (kh == 0) {
      float gi = gpart[0][b][ci + 0] + gpart[1][b][ci + 0] + bias_s[ci + 0];
      float gf = gpart[0][b][ci + 4] + gpart[1][b][ci + 4] + bias_s[ci + 4];
      float gg = gpart[0][b][ci + 8] + gpart[1][b][ci + 8] + bias_s[ci + 8];
      float go = gpart[0][b][ci + 12] + gpart[1][b][ci + 12] + bias_s[ci + 12];
      float cn = sigm(gf) * c_lds[b][ci] + sigm(gi) * tanhx(gg);
      c_lds[b][ci] = cn;
      stc(hnext + b * 1024 + col, sigm(go) * tanhx(cn));
    }
    ++bars; tree_barrier(bar, w, bars);

    // ---- phase B: dproj = h @ W_dec^T + b_dec (WGs 0..63) ----
    if (w < 64) {
      int bb = t >> 3, cl = t & 7;
      int cc = w * 8 + cl;
      const float* hrow = hnext + bb * 1024;
      const float* wrow = W_dec + (size_t)cc * 1024;
      float acc = 0.f;
#pragma unroll 4
      for (int q = 0; q < 256; ++q) {
        float2 h01 = ldc2(hrow + q * 4);
        float2 h23 = ldc2(hrow + q * 4 + 2);
        float4 w4 = *(const float4*)(wrow + q * 4);
        acc += h01.x * w4.x + h01.y * w4.y + h23.x * w4.z + h23.y * w4.w;
      }
      stc(dproj + bb * 512 + cc, acc + b_dec[cc]);
    }
    ++bars; tree_barrier(bar, w, bars);

    // ---- phase C: scores + per-WG argmax partials (WG covers s=2w,2w+1) ----
    {
      int sc = t >> 2, ks = t & 3;
      int sl = sc >> 5, bb = sc & 31;
      int s = w * 2 + sl;
      const float* ep = enc_proj + ((size_t)s * 32 + bb) * 512 + ks * 128;
      const float* dp = dproj + bb * 512 + ks * 128;
      const float* wvv = W_v + ks * 128;
      float sum = 0.f;
#pragma unroll 4
      for (int q = 0; q < 32; ++q) {
        float2 d01 = ldc2(dp + q * 4);
        float2 d23 = ldc2(dp + q * 4 + 2);
        float4 e4 = *(const float4*)(ep + q * 4);
        float4 v4 = *(const float4*)(wvv + q * 4);
        sum += tanhx(e4.x + d01.x) * v4.x;
        sum += tanhx(e4.y + d01.y) * v4.y;
        sum += tanhx(e4.z + d23.x) * v4.z;
        sum += tanhx(e4.w + d23.y) * v4.w;
      }
      sum += __shfl_xor(sum, 1);
      sum += __shfl_xor(sum, 2);
      if (ks == 0) {
        float sv = sum + b_v[0];
        out[((size_t)ts * 32 + bb) * 512 + s] = sv;
        svals[sl * 32 + bb] = sv;
      }
    }
    __syncthreads();
    if (t < 32) {
      float v0 = svals[t], v1 = svals[32 + t];
      float bv = v0; int bs = w * 2;
      if (v1 > v0) { bv = v1; bs = w * 2 + 1; }
      stc(pval + w * 32 + t, bv);
      stci(pidx + w * 32 + t, bs);
    }
    ++bars; tree_barrier(bar, w, bars);

    // ---- phase D: final argmax per batch (WG w<32 handles b=w) ----
    if (w < 32) {
      float v = ldc(pval + t * 32 + w);
      int si = ldci(pidx + t * 32 + w);
#pragma unroll
      for (int m = 1; m < 64; m <<= 1) {
        float ov = __shfl_xor(v, m);
        int os = __shfl_xor(si, m);
        if (ov > v || (ov == v && os < si)) { v = ov; si = os; }
      }
      int lane = t & 63, wid = t >> 6;
      if (lane == 0) { redv[wid] = v; redi[wid] = si; }
      __syncthreads();
      if (t == 0) {
        for (int i = 1; i < 4; ++i) {
          if (redv[i] > v || (redv[i] == v && redi[i] < si)) { v = redv[i]; si = redi[i]; }
        }
        stci(idxbuf + w, si);
      }
    }
    ++bars; tree_barrier(bar, w, bars);
  }
}

// ---------------------------------------------------------------------------
extern "C" void kernel_launch(void* const* d_in, const int* in_sizes, int n_in,
                              void* d_out, int out_size, void* d_ws, size_t ws_size,
                              hipStream_t stream) {
  (void)in_sizes; (void)n_in; (void)out_size; (void)ws_size;
  const float* feats = (const float*)d_in[0];
  const float* Wih_f = (const float*)d_in[1];
  const float* Whh_f = (const float*)d_in[2];
  const float* bih_f = (const float*)d_in[3];
  const float* bhh_f = (const float*)d_in[4];
  const float* Wih_b = (const float*)d_in[5];
  const float* Whh_b = (const float*)d_in[6];
  const float* bih_b = (const float*)d_in[7];
  const float* bhh_b = (const float*)d_in[8];
  const float* Wih_d = (const float*)d_in[9];
  const float* Whh_d = (const float*)d_in[10];
  const float* bih_d = (const float*)d_in[11];
  const float* bhh_d = (const float*)d_in[12];
  const float* W_enc = (const float*)d_in[13];
  const float* b_enc = (const float*)d_in[14];
  const float* W_dec = (const float*)d_in[15];
  const float* b_dec = (const float*)d_in[16];
  const float* W_v   = (const float*)d_in[17];
  const float* b_v   = (const float*)d_in[18];
  float* out = (float*)d_out;

  int* ctrl = (int*)d_ws;
  int* bar_enc = ctrl;
  int* bar_dec = ctrl + 8192;
  int* idxbuf  = ctrl + 16352;
  float* base = (float*)d_ws + 16384;        // after 64 KiB ctrl block
  float* enc_proj = base;                    // 8,388,608
  float* henc     = enc_proj + 8388608;      //    65,536  [2dir][2pp][32][512]
  float* cfin     = henc + 65536;            //    32,768  [2dir][32][512]
  float* hbuf     = cfin + 32768;            //    65,536  [2][32][1024]
  float* dproj    = hbuf + 65536;            //    16,384
  float* pval     = dproj + 16384;           //     8,192
  int*   pidx     = (int*)(pval + 8192);     //     8,192 ints
  // total ~34.4 MB

  const int ENC_LDS = (16 * 1028 + 16 * 516) * 4;   //  98,816 B
  const int DEC_LDS = (2 * 16 * 1028) * 4;          // 131,584 B
  hipFuncSetAttribute((const void*)encoder_kernel,
                      hipFuncAttributeMaxDynamicSharedMemorySize, ENC_LDS);
  hipFuncSetAttribute((const void*)decoder_kernel,
                      hipFuncAttributeMaxDynamicSharedMemorySize, DEC_LDS);

  hipMemsetAsync(d_ws, 0, 65536, stream);

  {
    void* args[] = {(void*)&feats,
                    (void*)&Wih_f, (void*)&Whh_f, (void*)&bih_f, (void*)&bhh_f,
                    (void*)&Wih_b, (void*)&Whh_b, (void*)&bih_b, (void*)&bhh_b,
                    (void*)&W_enc, (void*)&b_enc,
                    (void*)&enc_proj, (void*)&henc, (void*)&cfin, (void*)&bar_enc};
    hipLaunchCooperativeKernel((const void*)encoder_kernel, dim3(NWG), dim3(256),
                               args, ENC_LDS, stream);
  }
  {
    void* args[] = {(void*)&feats,
                    (void*)&Wih_d, (void*)&Whh_d, (void*)&bih_d, (void*)&bhh_d,
                    (void*)&W_dec, (void*)&b_dec, (void*)&W_v, (void*)&b_v,
                    (void*)&enc_proj, (void*)&henc, (void*)&cfin,
                    (void*)&hbuf, (void*)&dproj, (void*)&pval, (void*)&pidx,
                    (void*)&idxbuf, (void*)&bar_dec, (void*)&out};
    hipLaunchCooperativeKernel((const void*)decoder_kernel, dim3(NWG), dim3(256),
                               args, DEC_LDS, stream);
  }
}

// Round 8
// 31987.433 us; speedup vs baseline: 2.8641x; 1.0873x over previous
//
#include <hip/hip_runtime.h>
#include <stdint.h>

// F=1024, H=512, S=512, B=32, T=128
// Round-7 verified math. Mechanical changes only (bit-identical sums):
//  - 512 threads/WG (8 waves/CU): encoder 1 gate row/thread, decoder 4-way
//    (Whh/Wih x gate-pair) split.
//  - decoder hprev/hnext and encoder feats staged via LDS [32][128] chunks.

#define NWG 256

__device__ __forceinline__ float sigm(float x) { return 1.0f / (1.0f + __expf(-x)); }
__device__ __forceinline__ float tanhx(float x) {
  float e = __expf(2.0f * x);
  return 1.0f - 2.0f / (e + 1.0f);
}

// coherent (agent-scope) access helpers
__device__ __forceinline__ float ldc(const float* p) {
  return __hip_atomic_load(p, __ATOMIC_RELAXED, __HIP_MEMORY_SCOPE_AGENT);
}
__device__ __forceinline__ float2 ldc2(const float* p) {
  double d = __hip_atomic_load((const double*)p, __ATOMIC_RELAXED, __HIP_MEMORY_SCOPE_AGENT);
  return __builtin_bit_cast(float2, d);
}
__device__ __forceinline__ void stc(float* p, float v) {
  __hip_atomic_store(p, v, __ATOMIC_RELAXED, __HIP_MEMORY_SCOPE_AGENT);
}
__device__ __forceinline__ int ldci(const int* p) {
  return __hip_atomic_load(p, __ATOMIC_RELAXED, __HIP_MEMORY_SCOPE_AGENT);
}
__device__ __forceinline__ void stci(int* p, int v) {
  __hip_atomic_store(p, v, __ATOMIC_RELAXED, __HIP_MEMORY_SCOPE_AGENT);
}

// two-level tree barrier (unchanged)
__device__ __forceinline__ void tree_barrier(int* bar, int w, int epoch) {
  __syncthreads();
  if (threadIdx.x == 0) {
    const int g = w >> 3;
    int* gc = bar + g * 64;
    int* rc = bar + 2048;
    int* gf = bar + 2112 + g * 64;
    int old = __hip_atomic_fetch_add(gc, 1, __ATOMIC_RELAXED, __HIP_MEMORY_SCOPE_AGENT);
    if (old == epoch * 8 - 1) {
      __hip_atomic_fetch_add(rc, 1, __ATOMIC_RELAXED, __HIP_MEMORY_SCOPE_AGENT);
      while (__hip_atomic_load(rc, __ATOMIC_RELAXED, __HIP_MEMORY_SCOPE_AGENT) < epoch * 32)
        __builtin_amdgcn_s_sleep(2);
      __hip_atomic_store(gf, epoch, __ATOMIC_RELAXED, __HIP_MEMORY_SCOPE_AGENT);
    } else {
      while (__hip_atomic_load(gf, __ATOMIC_RELAXED, __HIP_MEMORY_SCOPE_AGENT) < epoch)
        __builtin_amdgcn_s_sleep(2);
    }
  }
  __syncthreads();
}

// ---------------------------------------------------------------------------
// Encoder: 256 WGs x 512 thr. WG<128 fwd, >=128 bwd; WG owns 4 h-cols.
// Thread (g,b,ci): ONE gate row (g*512+col), full K ascending (bit-identical
// to round 7's 2-rows-per-thread order). Weights LDS-resident; feats staged.
// ---------------------------------------------------------------------------
__global__ __launch_bounds__(512) void encoder_kernel(
    const float* __restrict__ feats,
    const float* __restrict__ Wih_f, const float* __restrict__ Whh_f,
    const float* __restrict__ bih_f, const float* __restrict__ bhh_f,
    const float* __restrict__ Wih_b, const float* __restrict__ Whh_b,
    const float* __restrict__ bih_b, const float* __restrict__ bhh_b,
    const float* __restrict__ W_enc, const float* __restrict__ b_enc,
    float* __restrict__ enc_proj, float* __restrict__ henc,
    float* __restrict__ cfin, int* __restrict__ bar)
{
  extern __shared__ __align__(16) float dyn[];
  float* wih_l = dyn;            // 16 x 1028
  float* whh_l = dyn + 16448;    // 16 x 516
  __shared__ float hch[32 * 132];
  __shared__ float wenc[4 * 516];
  __shared__ float gpart[32][17];
  __shared__ float projp[2][128];
  __shared__ float bias_s[16];
  __shared__ float benc_s[4];

  const int w = blockIdx.x;
  const int dir = (w >= 128) ? 1 : 0;
  const int wl = w & 127;
  const int col0 = wl * 4;
  const int t = threadIdx.x;
  const int g = t >> 7;        // gate 0..3
  const int tt = t & 127;
  const int b = tt >> 2;
  const int ci = tt & 3;
  const int col = col0 + ci;

  const float* Wih = dir ? Wih_b : Wih_f;
  const float* Whh = dir ? Whh_b : Whh_f;
  const float* bih = dir ? bih_b : bih_f;
  const float* bhh = dir ? bhh_b : bhh_f;

  for (int i = t; i < 16 * 256; i += 512) {
    int r = i >> 8, q = i & 255;
    int gg = r >> 2, cj = r & 3;
    *(float4*)(wih_l + r * 1028 + q * 4) =
        *(const float4*)(Wih + (size_t)(gg * 512 + col0 + cj) * 1024 + q * 4);
  }
  for (int i = t; i < 16 * 128; i += 512) {
    int r = i >> 7, q = i & 127;
    int gg = r >> 2, cj = r & 3;
    *(float4*)(whh_l + r * 516 + q * 4) =
        *(const float4*)(Whh + (size_t)(gg * 512 + col0 + cj) * 512 + q * 4);
  }
  for (int i = t; i < 4 * 128; i += 512) {
    int jl = i >> 7, q = i & 127;
    *(float4*)(wenc + jl * 516 + q * 4) =
        *(const float4*)(W_enc + (size_t)(col0 + jl) * 1024 + dir * 512 + q * 4);
  }
  if (t < 16) {
    int gg = t >> 2, cj = t & 3;
    bias_s[t] = bih[gg * 512 + col0 + cj] + bhh[gg * 512 + col0 + cj];
  }
  if (t < 4) benc_s[t] = b_enc[col0 + t];
  float c_reg = 0.0f;
  __syncthreads();

  const float* wx = wih_l + (g * 4 + ci) * 1028;   // this thread's Wih row
  const float* wh = whh_l + (g * 4 + ci) * 516;    // this thread's Whh row
  const float* wpe = wenc + ci * 516;              // proj row (g<2 roles)

  for (int it = 0; it < 512; ++it) {
    const int s = dir ? (511 - it) : it;
    float acc = 0.0f, projacc = 0.0f;

    if (it > 0) {
      const float* hsrc = henc + dir * 32768 + ((it - 1) & 1) * 16384;
      for (int ch = 0; ch < 4; ++ch) {
        for (int i = t; i < 1024; i += 512) {
          int bb = i >> 5, q = i & 31;
          const float* sp = hsrc + bb * 512 + ch * 128 + q * 4;
          float2 f0 = ldc2(sp);
          float2 f1 = ldc2(sp + 2);
          *(float4*)(hch + bb * 132 + q * 4) = make_float4(f0.x, f0.y, f1.x, f1.y);
        }
        __syncthreads();
        {
          const float* hrow = hch + b * 132;
          const float* p0 = wh + ch * 128;
#pragma unroll 8
          for (int q = 0; q < 32; ++q) {
            float4 h4 = *(const float4*)(hrow + q * 4);
            float4 a4 = *(const float4*)(p0 + q * 4);
            acc += h4.x * a4.x + h4.y * a4.y + h4.z * a4.z + h4.w * a4.w;
          }
        }
        if (g < 2) {  // proj k-half role = g (exact round-7 kh split)
          const float* hp = hch + b * 132 + g * 64;
          const float* wp = wpe + ch * 128 + g * 64;
#pragma unroll 4
          for (int kk = 0; kk < 16; ++kk) {
            float4 h4 = *(const float4*)(hp + kk * 4);
            float4 w4 = *(const float4*)(wp + kk * 4);
            projacc += h4.x * w4.x + h4.y * w4.y + h4.z * w4.z + h4.w * w4.w;
          }
        }
        __syncthreads();
      }
    }

    // x-part: feats staged in 8 chunks of [32][128] (plain loads, read-only)
    {
      const float* fsrc = feats + ((size_t)s * 32) * 1024;
      for (int ch = 0; ch < 8; ++ch) {
        for (int i = t; i < 1024; i += 512) {
          int bb = i >> 5, q = i & 31;
          *(float4*)(hch + bb * 132 + q * 4) =
              *(const float4*)(fsrc + bb * 1024 + ch * 128 + q * 4);
        }
        __syncthreads();
        const float* hrow = hch + b * 132;
        const float* p0 = wx + ch * 128;
#pragma unroll 8
        for (int q = 0; q < 32; ++q) {
          float4 f4 = *(const float4*)(hrow + q * 4);
          float4 a4 = *(const float4*)(p0 + q * 4);
          acc += f4.x * a4.x + f4.y * a4.y + f4.z * a4.z + f4.w * a4.w;
        }
        __syncthreads();
      }
    }

    gpart[b][g * 4 + ci] = acc;
    if (g < 2) projp[g][tt] = projacc;
    __syncthreads();
    if (t < 128) {
      float gi = gpart[b][ci + 0] + bias_s[ci + 0];
      float gf = gpart[b][ci + 4] + bias_s[ci + 4];
      float gg = gpart[b][ci + 8] + bias_s[ci + 8];
      float go = gpart[b][ci + 12] + bias_s[ci + 12];
      float cn = sigm(gf) * c_reg + sigm(gi) * tanhx(gg);
      c_reg = cn;
      stc(henc + dir * 32768 + (it & 1) * 16384 + b * 512 + col,
          sigm(go) * tanhx(cn));
    } else if (g == 1 && it > 0) {
      const int sp = dir ? (512 - it) : (it - 1);
      const float p = projp[0][tt] + projp[1][tt];
      float* addr = enc_proj + ((size_t)sp * 32 + b) * 512 + col;
      if (it - 1 <= 255) {
        stc(addr, p + benc_s[ci]);
      } else {
        stc(addr, ldc(addr) + p);
      }
    }
    tree_barrier(bar, w, it + 1);
  }

  // post-loop: proj for e=511 (always second arriver), and cfin
  {
    const float* hsrc = henc + dir * 32768 + 16384;
    float projacc = 0.0f;
    for (int ch = 0; ch < 4; ++ch) {
      for (int i = t; i < 1024; i += 512) {
        int bb = i >> 5, q = i & 31;
        const float* sp = hsrc + bb * 512 + ch * 128 + q * 4;
        float2 f0 = ldc2(sp);
        float2 f1 = ldc2(sp + 2);
        *(float4*)(hch + bb * 132 + q * 4) = make_float4(f0.x, f0.y, f1.x, f1.y);
      }
      __syncthreads();
      if (g < 2) {
        const float* hp = hch + b * 132 + g * 64;
        const float* wp = wpe + ch * 128 + g * 64;
#pragma unroll 4
        for (int kk = 0; kk < 16; ++kk) {
          float4 h4 = *(const float4*)(hp + kk * 4);
          float4 w4 = *(const float4*)(wp + kk * 4);
          projacc += h4.x * w4.x + h4.y * w4.y + h4.z * w4.z + h4.w * w4.w;
        }
      }
      __syncthreads();
    }
    if (g < 2) projp[g][tt] = projacc;
    __syncthreads();
    if (g == 1) {
      const int sp = dir ? 0 : 511;
      float* addr = enc_proj + ((size_t)sp * 32 + b) * 512 + col;
      stc(addr, ldc(addr) + (projp[0][tt] + projp[1][tt]));
    }
    if (t < 128) cfin[dir * 16384 + b * 512 + col] = c_reg;
  }
}

// ---------------------------------------------------------------------------
// Decoder: 256 WGs x 512 thr. Group q4 = t>>7: {0,1}: Whh gate-pairs {01,23};
// {2,3}: Wih gate-pairs {01,23}. hprev/hnext staged via LDS chunks.
// ---------------------------------------------------------------------------
__global__ __launch_bounds__(512) void decoder_kernel(
    const float* __restrict__ feats,
    const float* __restrict__ Wih_d, const float* __restrict__ Whh_d,
    const float* __restrict__ bih_d, const float* __restrict__ bhh_d,
    const float* __restrict__ W_dec, const float* __restrict__ b_dec,
    const float* __restrict__ W_v, const float* __restrict__ b_v,
    const float* __restrict__ enc_proj, const float* __restrict__ henc,
    const float* __restrict__ cfin,
    float* __restrict__ hbuf, float* __restrict__ dproj,
    float* __restrict__ pval, int* __restrict__ pidx,
    int* __restrict__ idxbuf, int* __restrict__ bar,
    float* __restrict__ out)
{
  extern __shared__ __align__(16) float dyn[];
  float* whh_l = dyn;            // 16 x 1028
  float* wih_l = dyn + 16448;    // 16 x 1028
  __shared__ float hch[32 * 132];
  __shared__ float gpart[2][32][17];
  __shared__ float c_lds[32][4];
  __shared__ float bias_s[16];
  __shared__ float svals[64];
  __shared__ float redv[4];
  __shared__ int redi[4];

  const int w = blockIdx.x;
  const int t = threadIdx.x;
  const int q4 = t >> 7;       // 0..3
  const int tt = t & 127;
  const int b = tt >> 2;
  const int ci = tt & 3;
  const int col0 = w * 4;
  const int col = col0 + ci;

  for (int i = t; i < 16 * 256; i += 512) {
    int r = i >> 8, q = i & 255;
    int gg = r >> 2, cj = r & 3;
    *(float4*)(whh_l + r * 1028 + q * 4) =
        *(const float4*)(Whh_d + (size_t)(gg * 1024 + col0 + cj) * 1024 + q * 4);
    *(float4*)(wih_l + r * 1028 + q * 4) =
        *(const float4*)(Wih_d + (size_t)(gg * 1024 + col0 + cj) * 1024 + q * 4);
  }
  if (t < 16) {
    int gg = t >> 2, cj = t & 3;
    bias_s[t] = bih_d[gg * 1024 + col0 + cj] + bhh_d[gg * 1024 + col0 + cj];
  }
  if (t < 128) {
    int flat = b * 1024 + col;
    int d = flat >> 14, sb = (flat >> 9) & 31, sh = flat & 511;
    float h0, c0;
    if (d == 0) {
      h0 = henc[16384 + sb * 512 + sh];
      c0 = cfin[sb * 512 + sh];
    } else {
      h0 = henc[32768 + 16384 + sb * 512 + sh];
      c0 = cfin[16384 + sb * 512 + sh];
    }
    stc(hbuf + b * 1024 + col, h0);
    c_lds[b][ci] = c0;
  }
  int bars = 1;
  tree_barrier(bar, w, bars);

  const float* wbase = (q4 < 2) ? whh_l : wih_l;
  const int g0 = (q4 & 1) * 2;                      // gate pair base
  const float* wr0 = wbase + (size_t)((g0 + 0) * 4 + ci) * 1028;
  const float* wr1 = wbase + (size_t)((g0 + 1) * 4 + ci) * 1028;

  for (int ts = 0; ts < 128; ++ts) {
    const float* hprev = hbuf + (ts & 1) * 32768;
    float* hnext = hbuf + ((ts + 1) & 1) * 32768;

    // ---- phase A: gates GEMM (chunked) + cell ----
    float a0 = 0.f, a1 = 0.f;
    const float* xrow = nullptr;
    if (q4 >= 2) {
      int ib = ldci(idxbuf + b);
      xrow = feats + ((size_t)ib * 32 + b) * 1024;
    }
    for (int ch = 0; ch < 8; ++ch) {
      for (int i = t; i < 1024; i += 512) {
        int bb = i >> 5, qq = i & 31;
        const float* sp = hprev + bb * 1024 + ch * 128 + qq * 4;
        float2 f0 = ldc2(sp);
        float2 f1 = ldc2(sp + 2);
        *(float4*)(hch + bb * 132 + qq * 4) = make_float4(f0.x, f0.y, f1.x, f1.y);
      }
      __syncthreads();
      const float* src = (q4 < 2) ? (hch + b * 132) : (xrow + ch * 128);
      const float* p0 = wr0 + ch * 128;
      const float* p1 = wr1 + ch * 128;
#pragma unroll 8
      for (int qq = 0; qq < 32; ++qq) {
        float4 h4 = *(const float4*)(src + qq * 4);
        float4 u0 = *(const float4*)(p0 + qq * 4);
        float4 u1 = *(const float4*)(p1 + qq * 4);
        a0 += h4.x * u0.x + h4.y * u0.y + h4.z * u0.z + h4.w * u0.w;
        a1 += h4.x * u1.x + h4.y * u1.y + h4.z * u1.z + h4.w * u1.w;
      }
      __syncthreads();
    }
    gpart[q4 >> 1][b][ci + (g0 + 0) * 4] = a0;
    gpart[q4 >> 1][b][ci + (g0 + 1) * 4] = a1;
    __syncthreads();
    if (t < 128) {
      float gi = gpart[0][b][ci + 0] + gpart[1][b][ci + 0] + bias_s[ci + 0];
      float gf = gpart[0][b][ci + 4] + gpart[1][b][ci + 4] + bias_s[ci + 4];
      float gg = gpart[0][b][ci + 8] + gpart[1][b][ci + 8] + bias_s[ci + 8];
      float go = gpart[0][b][ci + 12] + gpart[1][b][ci + 12] + bias_s[ci + 12];
      float cn = sigm(gf) * c_lds[b][ci] + sigm(gi) * tanhx(gg);
      c_lds[b][ci] = cn;
      stc(hnext + b * 1024 + col, sigm(go) * tanhx(cn));
    }
    ++bars; tree_barrier(bar, w, bars);

    // ---- phase B: dproj (WGs 0..31, 16 cols each; hnext staged) ----
    if (w < 32) {
      const int bb2 = t >> 4, cl = t & 15;
      const int cc = w * 16 + cl;
      const float* wrow = W_dec + (size_t)cc * 1024;
      float acc = 0.f;
      for (int ch = 0; ch < 8; ++ch) {
        for (int i = t; i < 1024; i += 512) {
          int bb = i >> 5, qq = i & 31;
          const float* sp = hnext + bb * 1024 + ch * 128 + qq * 4;
          float2 f0 = ldc2(sp);
          float2 f1 = ldc2(sp + 2);
          *(float4*)(hch + bb * 132 + qq * 4) = make_float4(f0.x, f0.y, f1.x, f1.y);
        }
        __syncthreads();
        const float* hr = hch + bb2 * 132;
        const float* wp = wrow + ch * 128;
#pragma unroll 8
        for (int qq = 0; qq < 32; ++qq) {
          float4 h4 = *(const float4*)(hr + qq * 4);
          float4 w4 = *(const float4*)(wp + qq * 4);
          acc += h4.x * w4.x + h4.y * w4.y + h4.z * w4.z + h4.w * w4.w;
        }
        __syncthreads();
      }
      stc(dproj + bb2 * 512 + cc, acc + b_dec[cc]);
    }
    ++bars; tree_barrier(bar, w, bars);

    // ---- phase C: scores + per-WG argmax partials (t<256, exact r7 code) ----
    if (t < 256) {
      int sc = t >> 2, ks = t & 3;
      int sl = sc >> 5, bb = sc & 31;
      int s = w * 2 + sl;
      const float* ep = enc_proj + ((size_t)s * 32 + bb) * 512 + ks * 128;
      const float* dp = dproj + bb * 512 + ks * 128;
      const float* wvv = W_v + ks * 128;
      float sum = 0.f;
#pragma unroll 4
      for (int q = 0; q < 32; ++q) {
        float2 d01 = ldc2(dp + q * 4);
        float2 d23 = ldc2(dp + q * 4 + 2);
        float4 e4 = *(const float4*)(ep + q * 4);
        float4 v4 = *(const float4*)(wvv + q * 4);
        sum += tanhx(e4.x + d01.x) * v4.x;
        sum += tanhx(e4.y + d01.y) * v4.y;
        sum += tanhx(e4.z + d23.x) * v4.z;
        sum += tanhx(e4.w + d23.y) * v4.w;
      }
      sum += __shfl_xor(sum, 1);
      sum += __shfl_xor(sum, 2);
      if (ks == 0) {
        float sv = sum + b_v[0];
        out[((size_t)ts * 32 + bb) * 512 + s] = sv;
        svals[sl * 32 + bb] = sv;
      }
    }
    __syncthreads();
    if (t < 32) {
      float v0 = svals[t], v1 = svals[32 + t];
      float bv = v0; int bs = w * 2;
      if (v1 > v0) { bv = v1; bs = w * 2 + 1; }  // tie -> smaller s
      stc(pval + w * 32 + t, bv);
      stci(pidx + w * 32 + t, bs);
    }
    ++bars; tree_barrier(bar, w, bars);

    // ---- phase D: final argmax per batch (WG w<32 handles b=w) ----
    {
      float v = 0.f; int si = 0;
      if (w < 32 && t < 256) {
        v = ldc(pval + t * 32 + w);
        si = ldci(pidx + t * 32 + w);
#pragma unroll
        for (int m = 1; m < 64; m <<= 1) {
          float ov = __shfl_xor(v, m);
          int os = __shfl_xor(si, m);
          if (ov > v || (ov == v && os < si)) { v = ov; si = os; }
        }
        int lane = t & 63, wid = t >> 6;
        if (lane == 0) { redv[wid] = v; redi[wid] = si; }
      }
      __syncthreads();
      if (w < 32 && t == 0) {
        for (int i = 1; i < 4; ++i) {
          if (redv[i] > v || (redv[i] == v && redi[i] < si)) { v = redv[i]; si = redi[i]; }
        }
        stci(idxbuf + w, si);
      }
    }
    ++bars; tree_barrier(bar, w, bars);
  }
}

// ---------------------------------------------------------------------------
extern "C" void kernel_launch(void* const* d_in, const int* in_sizes, int n_in,
                              void* d_out, int out_size, void* d_ws, size_t ws_size,
                              hipStream_t stream) {
  (void)in_sizes; (void)n_in; (void)out_size; (void)ws_size;
  const float* feats = (const float*)d_in[0];
  const float* Wih_f = (const float*)d_in[1];
  const float* Whh_f = (const float*)d_in[2];
  const float* bih_f = (const float*)d_in[3];
  const float* bhh_f = (const float*)d_in[4];
  const float* Wih_b = (const float*)d_in[5];
  const float* Whh_b = (const float*)d_in[6];
  const float* bih_b = (const float*)d_in[7];
  const float* bhh_b = (const float*)d_in[8];
  const float* Wih_d = (const float*)d_in[9];
  const float* Whh_d = (const float*)d_in[10];
  const float* bih_d = (const float*)d_in[11];
  const float* bhh_d = (const float*)d_in[12];
  const float* W_enc = (const float*)d_in[13];
  const float* b_enc = (const float*)d_in[14];
  const float* W_dec = (const float*)d_in[15];
  const float* b_dec = (const float*)d_in[16];
  const float* W_v   = (const float*)d_in[17];
  const float* b_v   = (const float*)d_in[18];
  float* out = (float*)d_out;

  int* ctrl = (int*)d_ws;
  int* bar_enc = ctrl;
  int* bar_dec = ctrl + 8192;
  int* idxbuf  = ctrl + 16352;
  float* base = (float*)d_ws + 16384;        // after 64 KiB ctrl block
  float* enc_proj = base;                    // 8,388,608
  float* henc     = enc_proj + 8388608;      //    65,536  [2dir][2pp][32][512]
  float* cfin     = henc + 65536;            //    32,768  [2dir][32][512]
  float* hbuf     = cfin + 32768;            //    65,536  [2][32][1024]
  float* dproj    = hbuf + 65536;            //    16,384
  float* pval     = dproj + 16384;           //     8,192
  int*   pidx     = (int*)(pval + 8192);     //     8,192 ints
  // total ~34.4 MB

  const int ENC_LDS = (16 * 1028 + 16 * 516) * 4;   //  98,816 B
  const int DEC_LDS = (2 * 16 * 1028) * 4;          // 131,584 B
  hipFuncSetAttribute((const void*)encoder_kernel,
                      hipFuncAttributeMaxDynamicSharedMemorySize, ENC_LDS);
  hipFuncSetAttribute((const void*)decoder_kernel,
                      hipFuncAttributeMaxDynamicSharedMemorySize, DEC_LDS);

  hipMemsetAsync(d_ws, 0, 65536, stream);

  {
    void* args[] = {(void*)&feats,
                    (void*)&Wih_f, (void*)&Whh_f, (void*)&bih_f, (void*)&bhh_f,
                    (void*)&Wih_b, (void*)&Whh_b, (void*)&bih_b, (void*)&bhh_b,
                    (void*)&W_enc, (void*)&b_enc,
                    (void*)&enc_proj, (void*)&henc, (void*)&cfin, (void*)&bar_enc};
    hipLaunchCooperativeKernel((const void*)encoder_kernel, dim3(NWG), dim3(512),
                               args, ENC_LDS, stream);
  }
  {
    void* args[] = {(void*)&feats,
                    (void*)&Wih_d, (void*)&Whh_d, (void*)&bih_d, (void*)&bhh_d,
                    (void*)&W_dec, (void*)&b_dec, (void*)&W_v, (void*)&b_v,
                    (void*)&enc_proj, (void*)&henc, (void*)&cfin,
                    (void*)&hbuf, (void*)&dproj, (void*)&pval, (void*)&pidx,
                    (void*)&idxbuf, (void*)&bar_dec, (void*)&out};
    hipLaunchCooperativeKernel((const void*)decoder_kernel, dim3(NWG), dim3(512),
                               args, DEC_LDS, stream);
  }
}

// Round 11
// 21203.975 us; speedup vs baseline: 4.3206x; 1.5086x over previous
//
#include <hip/hip_runtime.h>
#include <stdint.h>

// F=1024, H=512, S=512, B=32, T=128
// Round-9 resubmission, attempt 3. Rounds 9/10 died with "connection closed
// while sending FIRST message" to the same container => dead lease (code never
// ran either round). Audit found no deadlock; round 8 proved these launch
// configs. Changes vs round 8: decoder phase C batch-major (dproj staged once
// to LDS, 2 KB/WG), phase B distributed across all WGs, T14 reg-prefetch.

#define NWG 256

__device__ __forceinline__ float sigm(float x) { return 1.0f / (1.0f + __expf(-x)); }
__device__ __forceinline__ float tanhx(float x) {
  float e = __expf(2.0f * x);
  return 1.0f - 2.0f / (e + 1.0f);
}

__device__ __forceinline__ float ldc(const float* p) {
  return __hip_atomic_load(p, __ATOMIC_RELAXED, __HIP_MEMORY_SCOPE_AGENT);
}
__device__ __forceinline__ float2 ldc2(const float* p) {
  double d = __hip_atomic_load((const double*)p, __ATOMIC_RELAXED, __HIP_MEMORY_SCOPE_AGENT);
  return __builtin_bit_cast(float2, d);
}
__device__ __forceinline__ void stc(float* p, float v) {
  __hip_atomic_store(p, v, __ATOMIC_RELAXED, __HIP_MEMORY_SCOPE_AGENT);
}
__device__ __forceinline__ int ldci(const int* p) {
  return __hip_atomic_load(p, __ATOMIC_RELAXED, __HIP_MEMORY_SCOPE_AGENT);
}
__device__ __forceinline__ void stci(int* p, int v) {
  __hip_atomic_store(p, v, __ATOMIC_RELAXED, __HIP_MEMORY_SCOPE_AGENT);
}

__device__ __forceinline__ void tree_barrier(int* bar, int w, int epoch) {
  __syncthreads();
  if (threadIdx.x == 0) {
    const int g = w >> 3;
    int* gc = bar + g * 64;
    int* rc = bar + 2048;
    int* gf = bar + 2112 + g * 64;
    int old = __hip_atomic_fetch_add(gc, 1, __ATOMIC_RELAXED, __HIP_MEMORY_SCOPE_AGENT);
    if (old == epoch * 8 - 1) {
      __hip_atomic_fetch_add(rc, 1, __ATOMIC_RELAXED, __HIP_MEMORY_SCOPE_AGENT);
      while (__hip_atomic_load(rc, __ATOMIC_RELAXED, __HIP_MEMORY_SCOPE_AGENT) < epoch * 32)
        __builtin_amdgcn_s_sleep(2);
      __hip_atomic_store(gf, epoch, __ATOMIC_RELAXED, __HIP_MEMORY_SCOPE_AGENT);
    } else {
      while (__hip_atomic_load(gf, __ATOMIC_RELAXED, __HIP_MEMORY_SCOPE_AGENT) < epoch)
        __builtin_amdgcn_s_sleep(2);
    }
  }
  __syncthreads();
}

// ---------------------------------------------------------------------------
// Encoder: as round 8, with T14 reg-prefetch staging (bit-identical sums).
// ---------------------------------------------------------------------------
__global__ __launch_bounds__(512) void encoder_kernel(
    const float* __restrict__ feats,
    const float* __restrict__ Wih_f, const float* __restrict__ Whh_f,
    const float* __restrict__ bih_f, const float* __restrict__ bhh_f,
    const float* __restrict__ Wih_b, const float* __restrict__ Whh_b,
    const float* __restrict__ bih_b, const float* __restrict__ bhh_b,
    const float* __restrict__ W_enc, const float* __restrict__ b_enc,
    float* __restrict__ enc_proj, float* __restrict__ henc,
    float* __restrict__ cfin, int* __restrict__ bar)
{
  extern __shared__ __align__(16) float dyn[];
  float* wih_l = dyn;            // 16 x 1028
  float* whh_l = dyn + 16448;    // 16 x 516
  __shared__ float hch[32 * 132];
  __shared__ float wenc[4 * 516];
  __shared__ float gpart[32][17];
  __shared__ float projp[2][128];
  __shared__ float bias_s[16];
  __shared__ float benc_s[4];

  const int w = blockIdx.x;
  const int dir = (w >= 128) ? 1 : 0;
  const int wl = w & 127;
  const int col0 = wl * 4;
  const int t = threadIdx.x;
  const int g = t >> 7;
  const int tt = t & 127;
  const int b = tt >> 2;
  const int ci = tt & 3;
  const int col = col0 + ci;
  const int i0 = t, i1 = t + 512;
  const int bb0 = i0 >> 5, q0 = i0 & 31;
  const int bb1 = i1 >> 5, q1 = i1 & 31;

  const float* Wih = dir ? Wih_b : Wih_f;
  const float* Whh = dir ? Whh_b : Whh_f;
  const float* bih = dir ? bih_b : bih_f;
  const float* bhh = dir ? bhh_b : bhh_f;

  for (int i = t; i < 16 * 256; i += 512) {
    int r = i >> 8, q = i & 255;
    int gg = r >> 2, cj = r & 3;
    *(float4*)(wih_l + r * 1028 + q * 4) =
        *(const float4*)(Wih + (size_t)(gg * 512 + col0 + cj) * 1024 + q * 4);
  }
  for (int i = t; i < 16 * 128; i += 512) {
    int r = i >> 7, q = i & 127;
    int gg = r >> 2, cj = r & 3;
    *(float4*)(whh_l + r * 516 + q * 4) =
        *(const float4*)(Whh + (size_t)(gg * 512 + col0 + cj) * 512 + q * 4);
  }
  for (int i = t; i < 4 * 128; i += 512) {
    int jl = i >> 7, q = i & 127;
    *(float4*)(wenc + jl * 516 + q * 4) =
        *(const float4*)(W_enc + (size_t)(col0 + jl) * 1024 + dir * 512 + q * 4);
  }
  if (t < 16) {
    int gg = t >> 2, cj = t & 3;
    bias_s[t] = bih[gg * 512 + col0 + cj] + bhh[gg * 512 + col0 + cj];
  }
  if (t < 4) benc_s[t] = b_enc[col0 + t];
  float c_reg = 0.0f;
  __syncthreads();

  const float* wx = wih_l + (g * 4 + ci) * 1028;
  const float* wh = whh_l + (g * 4 + ci) * 516;
  const float* wpe = wenc + ci * 516;

  for (int it = 0; it < 512; ++it) {
    const int s = dir ? (511 - it) : it;
    float acc = 0.0f, projacc = 0.0f;

    if (it > 0) {
      const float* hsrc = henc + dir * 32768 + ((it - 1) & 1) * 16384;
      float2 rA0, rA1, rB0, rB1;
      rA0 = ldc2(hsrc + bb0 * 512 + q0 * 4);
      rA1 = ldc2(hsrc + bb0 * 512 + q0 * 4 + 2);
      rB0 = ldc2(hsrc + bb1 * 512 + q1 * 4);
      rB1 = ldc2(hsrc + bb1 * 512 + q1 * 4 + 2);
      for (int ch = 0; ch < 4; ++ch) {
        *(float4*)(hch + bb0 * 132 + q0 * 4) = make_float4(rA0.x, rA0.y, rA1.x, rA1.y);
        *(float4*)(hch + bb1 * 132 + q1 * 4) = make_float4(rB0.x, rB0.y, rB1.x, rB1.y);
        __syncthreads();
        if (ch < 3) {
          rA0 = ldc2(hsrc + bb0 * 512 + (ch + 1) * 128 + q0 * 4);
          rA1 = ldc2(hsrc + bb0 * 512 + (ch + 1) * 128 + q0 * 4 + 2);
          rB0 = ldc2(hsrc + bb1 * 512 + (ch + 1) * 128 + q1 * 4);
          rB1 = ldc2(hsrc + bb1 * 512 + (ch + 1) * 128 + q1 * 4 + 2);
        }
        {
          const float* hrow = hch + b * 132;
          const float* p0 = wh + ch * 128;
#pragma unroll 8
          for (int q = 0; q < 32; ++q) {
            float4 h4 = *(const float4*)(hrow + q * 4);
            float4 a4 = *(const float4*)(p0 + q * 4);
            acc += h4.x * a4.x + h4.y * a4.y + h4.z * a4.z + h4.w * a4.w;
          }
        }
        if (g < 2) {
          const float* hp = hch + b * 132 + g * 64;
          const float* wp = wpe + ch * 128 + g * 64;
#pragma unroll 4
          for (int kk = 0; kk < 16; ++kk) {
            float4 h4 = *(const float4*)(hp + kk * 4);
            float4 w4 = *(const float4*)(wp + kk * 4);
            projacc += h4.x * w4.x + h4.y * w4.y + h4.z * w4.z + h4.w * w4.w;
          }
        }
        __syncthreads();
      }
    }

    // x-part: feats staged with T14 (plain loads)
    {
      const float* fsrc = feats + ((size_t)s * 32) * 1024;
      float4 fA = *(const float4*)(fsrc + bb0 * 1024 + q0 * 4);
      float4 fB = *(const float4*)(fsrc + bb1 * 1024 + q1 * 4);
      for (int ch = 0; ch < 8; ++ch) {
        *(float4*)(hch + bb0 * 132 + q0 * 4) = fA;
        *(float4*)(hch + bb1 * 132 + q1 * 4) = fB;
        __syncthreads();
        if (ch < 7) {
          fA = *(const float4*)(fsrc + bb0 * 1024 + (ch + 1) * 128 + q0 * 4);
          fB = *(const float4*)(fsrc + bb1 * 1024 + (ch + 1) * 128 + q1 * 4);
        }
        const float* hrow = hch + b * 132;
        const float* p0 = wx + ch * 128;
#pragma unroll 8
        for (int q = 0; q < 32; ++q) {
          float4 f4 = *(const float4*)(hrow + q * 4);
          float4 a4 = *(const float4*)(p0 + q * 4);
          acc += f4.x * a4.x + f4.y * a4.y + f4.z * a4.z + f4.w * a4.w;
        }
        __syncthreads();
      }
    }

    gpart[b][g * 4 + ci] = acc;
    if (g < 2) projp[g][tt] = projacc;
    __syncthreads();
    if (t < 128) {
      float gi = gpart[b][ci + 0] + bias_s[ci + 0];
      float gf = gpart[b][ci + 4] + bias_s[ci + 4];
      float gg = gpart[b][ci + 8] + bias_s[ci + 8];
      float go = gpart[b][ci + 12] + bias_s[ci + 12];
      float cn = sigm(gf) * c_reg + sigm(gi) * tanhx(gg);
      c_reg = cn;
      stc(henc + dir * 32768 + (it & 1) * 16384 + b * 512 + col,
          sigm(go) * tanhx(cn));
    } else if (g == 1 && it > 0) {
      const int sp = dir ? (512 - it) : (it - 1);
      const float p = projp[0][tt] + projp[1][tt];
      float* addr = enc_proj + ((size_t)sp * 32 + b) * 512 + col;
      if (it - 1 <= 255) {
        stc(addr, p + benc_s[ci]);
      } else {
        stc(addr, ldc(addr) + p);
      }
    }
    tree_barrier(bar, w, it + 1);
  }

  // post-loop: proj for e=511 (second arriver), and cfin
  {
    const float* hsrc = henc + dir * 32768 + 16384;
    float projacc = 0.0f;
    for (int ch = 0; ch < 4; ++ch) {
      for (int i = t; i < 1024; i += 512) {
        int bb = i >> 5, q = i & 31;
        const float* sp = hsrc + bb * 512 + ch * 128 + q * 4;
        float2 f0 = ldc2(sp);
        float2 f1 = ldc2(sp + 2);
        *(float4*)(hch + bb * 132 + q * 4) = make_float4(f0.x, f0.y, f1.x, f1.y);
      }
      __syncthreads();
      if (g < 2) {
        const float* hp = hch + b * 132 + g * 64;
        const float* wp = wpe + ch * 128 + g * 64;
#pragma unroll 4
        for (int kk = 0; kk < 16; ++kk) {
          float4 h4 = *(const float4*)(hp + kk * 4);
          float4 w4 = *(const float4*)(wp + kk * 4);
          projacc += h4.x * w4.x + h4.y * w4.y + h4.z * w4.z + h4.w * w4.w;
        }
      }
      __syncthreads();
    }
    if (g < 2) projp[g][tt] = projacc;
    __syncthreads();
    if (g == 1) {
      const int sp = dir ? 0 : 511;
      float* addr = enc_proj + ((size_t)sp * 32 + b) * 512 + col;
      stc(addr, ldc(addr) + (projp[0][tt] + projp[1][tt]));
    }
    if (t < 128) cfin[dir * 16384 + b * 512 + col] = c_reg;
  }
}

// ---------------------------------------------------------------------------
// Decoder: phase A as r8 (+T14), phase B distributed (all WGs, 2 cols),
// phase C batch-major (WG w -> bb=w>>3, s-block q=w&7; dproj staged to LDS),
// phase D 8-partial reduce.
// ---------------------------------------------------------------------------
__global__ __launch_bounds__(512) void decoder_kernel(
    const float* __restrict__ feats,
    const float* __restrict__ Wih_d, const float* __restrict__ Whh_d,
    const float* __restrict__ bih_d, const float* __restrict__ bhh_d,
    const float* __restrict__ W_dec, const float* __restrict__ b_dec,
    const float* __restrict__ W_v, const float* __restrict__ b_v,
    const float* __restrict__ enc_proj, const float* __restrict__ henc,
    const float* __restrict__ cfin,
    float* __restrict__ hbuf, float* __restrict__ dproj,
    float* __restrict__ pval, int* __restrict__ pidx,
    int* __restrict__ idxbuf, int* __restrict__ bar,
    float* __restrict__ out)
{
  extern __shared__ __align__(16) float dyn[];
  float* whh_l = dyn;            // 16 x 1028
  float* wih_l = dyn + 16448;    // 16 x 1028
  __shared__ float hch[32 * 132];   // phase A staging; aliased by pb/dpl below
  __shared__ float gpart[2][32][17];
  __shared__ float c_lds[32][4];
  __shared__ float bias_s[16];
  __shared__ float svals[64];
  float* pb  = hch;          // [32][33]+2 phase-B partials (alias, barrier-safe)
  float* dpl = hch + 1088;   // [8][68] dproj slice for phase C (alias)

  const int w = blockIdx.x;
  const int t = threadIdx.x;
  const int q4 = t >> 7;
  const int tt = t & 127;
  const int b = tt >> 2;
  const int ci = tt & 3;
  const int col0 = w * 4;
  const int col = col0 + ci;
  const int i0 = t, i1 = t + 512;
  const int bb0 = i0 >> 5, q0 = i0 & 31;
  const int bb1 = i1 >> 5, q1 = i1 & 31;
  const int bb_c = w >> 3;   // phase C batch
  const int qq_ = w & 7;     // phase C s-block

  for (int i = t; i < 16 * 256; i += 512) {
    int r = i >> 8, q = i & 255;
    int gg = r >> 2, cj = r & 3;
    *(float4*)(whh_l + r * 1028 + q * 4) =
        *(const float4*)(Whh_d + (size_t)(gg * 1024 + col0 + cj) * 1024 + q * 4);
    *(float4*)(wih_l + r * 1028 + q * 4) =
        *(const float4*)(Wih_d + (size_t)(gg * 1024 + col0 + cj) * 1024 + q * 4);
  }
  if (t < 16) {
    int gg = t >> 2, cj = t & 3;
    bias_s[t] = bih_d[gg * 1024 + col0 + cj] + bhh_d[gg * 1024 + col0 + cj];
  }
  if (t < 128) {
    int flat = b * 1024 + col;
    int d = flat >> 14, sb = (flat >> 9) & 31, sh = flat & 511;
    float h0, c0;
    if (d == 0) {
      h0 = henc[16384 + sb * 512 + sh];
      c0 = cfin[sb * 512 + sh];
    } else {
      h0 = henc[32768 + 16384 + sb * 512 + sh];
      c0 = cfin[16384 + sb * 512 + sh];
    }
    stc(hbuf + b * 1024 + col, h0);
    c_lds[b][ci] = c0;
  }
  int bars = 1;
  tree_barrier(bar, w, bars);

  const float* wbase = (q4 < 2) ? whh_l : wih_l;
  const int g0 = (q4 & 1) * 2;
  const float* wr0 = wbase + (size_t)((g0 + 0) * 4 + ci) * 1028;
  const float* wr1 = wbase + (size_t)((g0 + 1) * 4 + ci) * 1028;

  for (int ts = 0; ts < 128; ++ts) {
    const float* hprev = hbuf + (ts & 1) * 32768;
    float* hnext = hbuf + ((ts + 1) & 1) * 32768;

    // ---- phase A: gates GEMM (T14-staged hprev) + cell ----
    float a0 = 0.f, a1 = 0.f;
    const float* xrow = nullptr;
    if (q4 >= 2) {
      int ib = ldci(idxbuf + b);
      xrow = feats + ((size_t)ib * 32 + b) * 1024;
    }
    {
      float2 rA0 = ldc2(hprev + bb0 * 1024 + q0 * 4);
      float2 rA1 = ldc2(hprev + bb0 * 1024 + q0 * 4 + 2);
      float2 rB0 = ldc2(hprev + bb1 * 1024 + q1 * 4);
      float2 rB1 = ldc2(hprev + bb1 * 1024 + q1 * 4 + 2);
      for (int ch = 0; ch < 8; ++ch) {
        *(float4*)(hch + bb0 * 132 + q0 * 4) = make_float4(rA0.x, rA0.y, rA1.x, rA1.y);
        *(float4*)(hch + bb1 * 132 + q1 * 4) = make_float4(rB0.x, rB0.y, rB1.x, rB1.y);
        __syncthreads();
        if (ch < 7) {
          rA0 = ldc2(hprev + bb0 * 1024 + (ch + 1) * 128 + q0 * 4);
          rA1 = ldc2(hprev + bb0 * 1024 + (ch + 1) * 128 + q0 * 4 + 2);
          rB0 = ldc2(hprev + bb1 * 1024 + (ch + 1) * 128 + q1 * 4);
          rB1 = ldc2(hprev + bb1 * 1024 + (ch + 1) * 128 + q1 * 4 + 2);
        }
        const float* src = (q4 < 2) ? (hch + b * 132) : (xrow + ch * 128);
        const float* p0 = wr0 + ch * 128;
        const float* p1 = wr1 + ch * 128;
#pragma unroll 8
        for (int qq = 0; qq < 32; ++qq) {
          float4 h4 = *(const float4*)(src + qq * 4);
          float4 u0 = *(const float4*)(p0 + qq * 4);
          float4 u1 = *(const float4*)(p1 + qq * 4);
          a0 += h4.x * u0.x + h4.y * u0.y + h4.z * u0.z + h4.w * u0.w;
          a1 += h4.x * u1.x + h4.y * u1.y + h4.z * u1.z + h4.w * u1.w;
        }
        __syncthreads();
      }
    }
    gpart[q4 >> 1][b][ci + (g0 + 0) * 4] = a0;
    gpart[q4 >> 1][b][ci + (g0 + 1) * 4] = a1;
    __syncthreads();
    if (t < 128) {
      float gi = gpart[0][b][ci + 0] + gpart[1][b][ci + 0] + bias_s[ci + 0];
      float gf = gpart[0][b][ci + 4] + gpart[1][b][ci + 4] + bias_s[ci + 4];
      float gg = gpart[0][b][ci + 8] + gpart[1][b][ci + 8] + bias_s[ci + 8];
      float go = gpart[0][b][ci + 12] + gpart[1][b][ci + 12] + bias_s[ci + 12];
      float cn = sigm(gf) * c_lds[b][ci] + sigm(gi) * tanhx(gg);
      c_lds[b][ci] = cn;
      stc(hnext + b * 1024 + col, sigm(go) * tanhx(cn));
    }
    ++bars; tree_barrier(bar, w, bars);

    // ---- phase B: dproj, all WGs, cols {2w, 2w+1}; 32 bb x 16 k-slices ----
    {
      const int bb2 = t >> 4, ks2 = t & 15;
      const float* hr = hnext + bb2 * 1024 + ks2 * 64;
      const float* wd0 = W_dec + (size_t)(2 * w + 0) * 1024 + ks2 * 64;
      const float* wd1 = W_dec + (size_t)(2 * w + 1) * 1024 + ks2 * 64;
      float s0 = 0.f, s1 = 0.f;
#pragma unroll 4
      for (int j = 0; j < 16; ++j) {
        float2 h01 = ldc2(hr + j * 4);
        float2 h23 = ldc2(hr + j * 4 + 2);
        float4 w40 = *(const float4*)(wd0 + j * 4);
        float4 w41 = *(const float4*)(wd1 + j * 4);
        s0 += h01.x * w40.x + h01.y * w40.y + h23.x * w40.z + h23.y * w40.w;
        s1 += h01.x * w41.x + h01.y * w41.y + h23.x * w41.z + h23.y * w41.w;
      }
      pb[bb2 * 33 + ks2 * 2 + 0] = s0;
      pb[bb2 * 33 + ks2 * 2 + 1] = s1;
    }
    __syncthreads();
    if (t < 64) {
      const int cl = t & 1, bb2 = t >> 1;
      const int cc = 2 * w + cl;
      float acc = 0.f;
#pragma unroll
      for (int k2 = 0; k2 < 16; ++k2) acc += pb[bb2 * 33 + k2 * 2 + cl];
      stc(dproj + bb2 * 512 + cc, acc + b_dec[cc]);
    }
    ++bars; tree_barrier(bar, w, bars);

    // ---- phase C: scores, batch-major. WG: bb_c, s in [64*qq_, 64*qq_+64) ----
    if (t < 256) {  // stage dproj[bb_c][0:512] into dpl[8][68]
      float2 v = ldc2(dproj + bb_c * 512 + 2 * t);
      int k = 2 * t;
      dpl[(k >> 6) * 68 + (k & 63) + 0] = v.x;
      dpl[(k >> 6) * 68 + (k & 63) + 1] = v.y;
    }
    __syncthreads();
    {
      const int sl = t >> 3, ks = t & 7;
      const int s = qq_ * 64 + sl;
      const float* ep = enc_proj + ((size_t)s * 32 + bb_c) * 512 + ks * 64;
      const float* dpp = dpl + ks * 68;
      const float* wvp = W_v + ks * 64;
      float sum = 0.f;
#pragma unroll 4
      for (int j = 0; j < 16; ++j) {
        float4 e4 = *(const float4*)(ep + j * 4);
        float4 d4 = *(const float4*)(dpp + j * 4);
        float4 v4 = *(const float4*)(wvp + j * 4);
        sum += tanhx(e4.x + d4.x) * v4.x;
        sum += tanhx(e4.y + d4.y) * v4.y;
        sum += tanhx(e4.z + d4.z) * v4.z;
        sum += tanhx(e4.w + d4.w) * v4.w;
      }
      sum += __shfl_xor(sum, 1);
      sum += __shfl_xor(sum, 2);
      sum += __shfl_xor(sum, 4);
      if (ks == 0) {
        float sv = sum + b_v[0];
        out[((size_t)ts * 32 + bb_c) * 512 + s] = sv;
        svals[sl] = sv;
      }
    }
    __syncthreads();
    if (t < 64) {  // per-WG argmax over its 64 s values (tie -> smaller s)
      float v = svals[t];
      int si = qq_ * 64 + t;
#pragma unroll
      for (int m = 1; m < 64; m <<= 1) {
        float ov = __shfl_xor(v, m);
        int os = __shfl_xor(si, m);
        if (ov > v || (ov == v && os < si)) { v = ov; si = os; }
      }
      if (t == 0) {
        stc(pval + bb_c * 8 + qq_, v);
        stci(pidx + bb_c * 8 + qq_, si);
      }
    }
    ++bars; tree_barrier(bar, w, bars);

    // ---- phase D: final argmax per batch (WG w<32 handles b=w) ----
    if (w < 32 && t < 64) {
      float v = ldc(pval + w * 8 + (t & 7));
      int si = ldci(pidx + w * 8 + (t & 7));
#pragma unroll
      for (int m = 1; m < 8; m <<= 1) {
        float ov = __shfl_xor(v, m);
        int os = __shfl_xor(si, m);
        if (ov > v || (ov == v && os < si)) { v = ov; si = os; }
      }
      if (t == 0) stci(idxbuf + w, si);
    }
    ++bars; tree_barrier(bar, w, bars);
  }
}

// ---------------------------------------------------------------------------
extern "C" void kernel_launch(void* const* d_in, const int* in_sizes, int n_in,
                              void* d_out, int out_size, void* d_ws, size_t ws_size,
                              hipStream_t stream) {
  (void)in_sizes; (void)n_in; (void)out_size; (void)ws_size;
  const float* feats = (const float*)d_in[0];
  const float* Wih_f = (const float*)d_in[1];
  const float* Whh_f = (const float*)d_in[2];
  const float* bih_f = (const float*)d_in[3];
  const float* bhh_f = (const float*)d_in[4];
  const float* Wih_b = (const float*)d_in[5];
  const float* Whh_b = (const float*)d_in[6];
  const float* bih_b = (const float*)d_in[7];
  const float* bhh_b = (const float*)d_in[8];
  const float* Wih_d = (const float*)d_in[9];
  const float* Whh_d = (const float*)d_in[10];
  const float* bih_d = (const float*)d_in[11];
  const float* bhh_d = (const float*)d_in[12];
  const float* W_enc = (const float*)d_in[13];
  const float* b_enc = (const float*)d_in[14];
  const float* W_dec = (const float*)d_in[15];
  const float* b_dec = (const float*)d_in[16];
  const float* W_v   = (const float*)d_in[17];
  const float* b_v   = (const float*)d_in[18];
  float* out = (float*)d_out;

  int* ctrl = (int*)d_ws;
  int* bar_enc = ctrl;
  int* bar_dec = ctrl + 8192;
  int* idxbuf  = ctrl + 16352;
  float* base = (float*)d_ws + 16384;        // after 64 KiB ctrl block
  float* enc_proj = base;                    // 8,388,608
  float* henc     = enc_proj + 8388608;      //    65,536
  float* cfin     = henc + 65536;            //    32,768
  float* hbuf     = cfin + 32768;            //    65,536
  float* dproj    = hbuf + 65536;            //    16,384
  float* pval     = dproj + 16384;           //       256 used
  int*   pidx     = (int*)(pval + 8192);     //       256 used
  // total ~34.4 MB

  const int ENC_LDS = (16 * 1028 + 16 * 516) * 4;   //  98,816 B
  const int DEC_LDS = (2 * 16 * 1028) * 4;          // 131,584 B
  hipFuncSetAttribute((const void*)encoder_kernel,
                      hipFuncAttributeMaxDynamicSharedMemorySize, ENC_LDS);
  hipFuncSetAttribute((const void*)decoder_kernel,
                      hipFuncAttributeMaxDynamicSharedMemorySize, DEC_LDS);

  hipMemsetAsync(d_ws, 0, 65536, stream);

  {
    void* args[] = {(void*)&feats,
                    (void*)&Wih_f, (void*)&Whh_f, (void*)&bih_f, (void*)&bhh_f,
                    (void*)&Wih_b, (void*)&Whh_b, (void*)&bih_b, (void*)&bhh_b,
                    (void*)&W_enc, (void*)&b_enc,
                    (void*)&enc_proj, (void*)&henc, (void*)&cfin, (void*)&bar_enc};
    hipLaunchCooperativeKernel((const void*)encoder_kernel, dim3(NWG), dim3(512),
                               args, ENC_LDS, stream);
  }
  {
    void* args[] = {(void*)&feats,
                    (void*)&Wih_d, (void*)&Whh_d, (void*)&bih_d, (void*)&bhh_d,
                    (void*)&W_dec, (void*)&b_dec, (void*)&W_v, (void*)&b_v,
                    (void*)&enc_proj, (void*)&henc, (void*)&cfin,
                    (void*)&hbuf, (void*)&dproj, (void*)&pval, (void*)&pidx,
                    (void*)&idxbuf, (void*)&bar_dec, (void*)&out};
    hipLaunchCooperativeKernel((const void*)decoder_kernel, dim3(NWG), dim3(512),
                               args, DEC_LDS, stream);
  }
}

// Round 12
// 19382.291 us; speedup vs baseline: 4.7267x; 1.0940x over previous
//
#include <hip/hip_runtime.h>
#include <stdint.h>

// F=1024, H=512, S=512, B=32, T=128
// Round-11 base. Changes:
//  1) Encoder x-projection hoisted to parallel GEMMs (xg = feats @ Wih^T per
//     dir) when ws_size permits (guarded; fallback = round-11 in-loop path).
//  2) Decoder: phase D folded into phase A (3 barriers/step, ib computed
//     locally from pval/pidx partials).
//  3) Decoder phase B: hnext staged via coalesced LDS chunks + 8-way k-split.

#define NWG 256

__device__ __forceinline__ float sigm(float x) { return 1.0f / (1.0f + __expf(-x)); }
__device__ __forceinline__ float tanhx(float x) {
  float e = __expf(2.0f * x);
  return 1.0f - 2.0f / (e + 1.0f);
}

__device__ __forceinline__ float ldc(const float* p) {
  return __hip_atomic_load(p, __ATOMIC_RELAXED, __HIP_MEMORY_SCOPE_AGENT);
}
__device__ __forceinline__ float2 ldc2(const float* p) {
  double d = __hip_atomic_load((const double*)p, __ATOMIC_RELAXED, __HIP_MEMORY_SCOPE_AGENT);
  return __builtin_bit_cast(float2, d);
}
__device__ __forceinline__ void stc(float* p, float v) {
  __hip_atomic_store(p, v, __ATOMIC_RELAXED, __HIP_MEMORY_SCOPE_AGENT);
}
__device__ __forceinline__ int ldci(const int* p) {
  return __hip_atomic_load(p, __ATOMIC_RELAXED, __HIP_MEMORY_SCOPE_AGENT);
}
__device__ __forceinline__ void stci(int* p, int v) {
  __hip_atomic_store(p, v, __ATOMIC_RELAXED, __HIP_MEMORY_SCOPE_AGENT);
}

__device__ __forceinline__ void tree_barrier(int* bar, int w, int epoch) {
  __syncthreads();
  if (threadIdx.x == 0) {
    const int g = w >> 3;
    int* gc = bar + g * 64;
    int* rc = bar + 2048;
    int* gf = bar + 2112 + g * 64;
    int old = __hip_atomic_fetch_add(gc, 1, __ATOMIC_RELAXED, __HIP_MEMORY_SCOPE_AGENT);
    if (old == epoch * 8 - 1) {
      __hip_atomic_fetch_add(rc, 1, __ATOMIC_RELAXED, __HIP_MEMORY_SCOPE_AGENT);
      while (__hip_atomic_load(rc, __ATOMIC_RELAXED, __HIP_MEMORY_SCOPE_AGENT) < epoch * 32)
        __builtin_amdgcn_s_sleep(2);
      __hip_atomic_store(gf, epoch, __ATOMIC_RELAXED, __HIP_MEMORY_SCOPE_AGENT);
    } else {
      while (__hip_atomic_load(gf, __ATOMIC_RELAXED, __HIP_MEMORY_SCOPE_AGENT) < epoch)
        __builtin_amdgcn_s_sleep(2);
    }
  }
  __syncthreads();
}

// ---------------------------------------------------------------------------
// xproj GEMM: C[m][n] = sum_k A[m][k]*W[n][k]; A=[16384][1024] feats,
// W=[2048][1024] Wih, C=[16384][2048]. 64x64 tile, BK=16, 256 thr, 4x4/thread.
// ---------------------------------------------------------------------------
__global__ __launch_bounds__(256) void xproj_gemm(
    const float* __restrict__ A, const float* __restrict__ W,
    float* __restrict__ C)
{
  __shared__ float As[16][68];
  __shared__ float Ws[16][68];
  const int t = threadIdx.x;
  const int m0 = blockIdx.x * 64, n0 = blockIdx.y * 64;
  const int tx = t & 15, ty = t >> 4;
  const int lr = t >> 2, lk = (t & 3) * 4;
  float acc[4][4] = {{0.f}};

  for (int kb = 0; kb < 1024; kb += 16) {
    float4 a4 = *(const float4*)(A + (size_t)(m0 + lr) * 1024 + kb + lk);
    float4 w4 = *(const float4*)(W + (size_t)(n0 + lr) * 1024 + kb + lk);
    __syncthreads();
    As[lk + 0][lr] = a4.x; As[lk + 1][lr] = a4.y;
    As[lk + 2][lr] = a4.z; As[lk + 3][lr] = a4.w;
    Ws[lk + 0][lr] = w4.x; Ws[lk + 1][lr] = w4.y;
    Ws[lk + 2][lr] = w4.z; Ws[lk + 3][lr] = w4.w;
    __syncthreads();
#pragma unroll
    for (int kk = 0; kk < 16; ++kk) {
      float4 av = *(const float4*)(&As[kk][ty * 4]);
      float4 wv = *(const float4*)(&Ws[kk][tx * 4]);
      acc[0][0] += av.x * wv.x; acc[0][1] += av.x * wv.y;
      acc[0][2] += av.x * wv.z; acc[0][3] += av.x * wv.w;
      acc[1][0] += av.y * wv.x; acc[1][1] += av.y * wv.y;
      acc[1][2] += av.y * wv.z; acc[1][3] += av.y * wv.w;
      acc[2][0] += av.z * wv.x; acc[2][1] += av.z * wv.y;
      acc[2][2] += av.z * wv.z; acc[2][3] += av.z * wv.w;
      acc[3][0] += av.w * wv.x; acc[3][1] += av.w * wv.y;
      acc[3][2] += av.w * wv.z; acc[3][3] += av.w * wv.w;
    }
  }
#pragma unroll
  for (int i = 0; i < 4; ++i) {
    float4 o;
    o.x = acc[i][0]; o.y = acc[i][1]; o.z = acc[i][2]; o.w = acc[i][3];
    *(float4*)(C + (size_t)(m0 + ty * 4 + i) * 2048 + n0 + tx * 4) = o;
  }
}

// ---------------------------------------------------------------------------
// Encoder: round-11 structure; x-part from precomputed xg (scalar read) when
// xg != nullptr, else round-11 in-loop staged x-part (fallback).
// ---------------------------------------------------------------------------
__global__ __launch_bounds__(512) void encoder_kernel(
    const float* __restrict__ feats,
    const float* __restrict__ Wih_f, const float* __restrict__ Whh_f,
    const float* __restrict__ bih_f, const float* __restrict__ bhh_f,
    const float* __restrict__ Wih_b, const float* __restrict__ Whh_b,
    const float* __restrict__ bih_b, const float* __restrict__ bhh_b,
    const float* __restrict__ W_enc, const float* __restrict__ b_enc,
    const float* __restrict__ xg_f, const float* __restrict__ xg_b,
    float* __restrict__ enc_proj, float* __restrict__ henc,
    float* __restrict__ cfin, int* __restrict__ bar)
{
  extern __shared__ __align__(16) float dyn[];
  float* wih_l = dyn;            // 16 x 1028 (fallback only)
  float* whh_l = dyn + 16448;    // 16 x 516
  __shared__ float hch[32 * 132];
  __shared__ float wenc[4 * 516];
  __shared__ float gpart[32][17];
  __shared__ float projp[2][128];
  __shared__ float bias_s[16];
  __shared__ float benc_s[4];

  const int w = blockIdx.x;
  const int dir = (w >= 128) ? 1 : 0;
  const int wl = w & 127;
  const int col0 = wl * 4;
  const int t = threadIdx.x;
  const int g = t >> 7;
  const int tt = t & 127;
  const int b = tt >> 2;
  const int ci = tt & 3;
  const int col = col0 + ci;
  const int i0 = t, i1 = t + 512;
  const int bb0 = i0 >> 5, q0 = i0 & 31;
  const int bb1 = i1 >> 5, q1 = i1 & 31;

  const float* Wih = dir ? Wih_b : Wih_f;
  const float* Whh = dir ? Whh_b : Whh_f;
  const float* bih = dir ? bih_b : bih_f;
  const float* bhh = dir ? bhh_b : bhh_f;
  const float* xg  = dir ? xg_b : xg_f;   // may be null (fallback)

  if (!xg) {
    for (int i = t; i < 16 * 256; i += 512) {
      int r = i >> 8, q = i & 255;
      int gg = r >> 2, cj = r & 3;
      *(float4*)(wih_l + r * 1028 + q * 4) =
          *(const float4*)(Wih + (size_t)(gg * 512 + col0 + cj) * 1024 + q * 4);
    }
  }
  for (int i = t; i < 16 * 128; i += 512) {
    int r = i >> 7, q = i & 127;
    int gg = r >> 2, cj = r & 3;
    *(float4*)(whh_l + r * 516 + q * 4) =
        *(const float4*)(Whh + (size_t)(gg * 512 + col0 + cj) * 512 + q * 4);
  }
  for (int i = t; i < 4 * 128; i += 512) {
    int jl = i >> 7, q = i & 127;
    *(float4*)(wenc + jl * 516 + q * 4) =
        *(const float4*)(W_enc + (size_t)(col0 + jl) * 1024 + dir * 512 + q * 4);
  }
  if (t < 16) {
    int gg = t >> 2, cj = t & 3;
    bias_s[t] = bih[gg * 512 + col0 + cj] + bhh[gg * 512 + col0 + cj];
  }
  if (t < 4) benc_s[t] = b_enc[col0 + t];
  float c_reg = 0.0f;
  __syncthreads();

  const float* wx = wih_l + (g * 4 + ci) * 1028;
  const float* wh = whh_l + (g * 4 + ci) * 516;
  const float* wpe = wenc + ci * 516;
  const size_t xg_row = (size_t)(g * 512 + col);

  for (int it = 0; it < 512; ++it) {
    const int s = dir ? (511 - it) : it;
    float acc = 0.0f, projacc = 0.0f;
    float xgv = 0.0f;
    if (xg) xgv = xg[(size_t)(s * 32 + b) * 2048 + xg_row];  // early issue

    if (it > 0) {
      const float* hsrc = henc + dir * 32768 + ((it - 1) & 1) * 16384;
      float2 rA0, rA1, rB0, rB1;
      rA0 = ldc2(hsrc + bb0 * 512 + q0 * 4);
      rA1 = ldc2(hsrc + bb0 * 512 + q0 * 4 + 2);
      rB0 = ldc2(hsrc + bb1 * 512 + q1 * 4);
      rB1 = ldc2(hsrc + bb1 * 512 + q1 * 4 + 2);
      for (int ch = 0; ch < 4; ++ch) {
        *(float4*)(hch + bb0 * 132 + q0 * 4) = make_float4(rA0.x, rA0.y, rA1.x, rA1.y);
        *(float4*)(hch + bb1 * 132 + q1 * 4) = make_float4(rB0.x, rB0.y, rB1.x, rB1.y);
        __syncthreads();
        if (ch < 3) {
          rA0 = ldc2(hsrc + bb0 * 512 + (ch + 1) * 128 + q0 * 4);
          rA1 = ldc2(hsrc + bb0 * 512 + (ch + 1) * 128 + q0 * 4 + 2);
          rB0 = ldc2(hsrc + bb1 * 512 + (ch + 1) * 128 + q1 * 4);
          rB1 = ldc2(hsrc + bb1 * 512 + (ch + 1) * 128 + q1 * 4 + 2);
        }
        {
          const float* hrow = hch + b * 132;
          const float* p0 = wh + ch * 128;
#pragma unroll 8
          for (int q = 0; q < 32; ++q) {
            float4 h4 = *(const float4*)(hrow + q * 4);
            float4 a4 = *(const float4*)(p0 + q * 4);
            acc += h4.x * a4.x + h4.y * a4.y + h4.z * a4.z + h4.w * a4.w;
          }
        }
        if (g < 2) {
          const float* hp = hch + b * 132 + g * 64;
          const float* wp = wpe + ch * 128 + g * 64;
#pragma unroll 4
          for (int kk = 0; kk < 16; ++kk) {
            float4 h4 = *(const float4*)(hp + kk * 4);
            float4 w4 = *(const float4*)(wp + kk * 4);
            projacc += h4.x * w4.x + h4.y * w4.y + h4.z * w4.z + h4.w * w4.w;
          }
        }
        __syncthreads();
      }
    }

    if (!xg) {  // fallback: in-loop x-part (round-11 path)
      const float* fsrc = feats + ((size_t)s * 32) * 1024;
      float4 fA = *(const float4*)(fsrc + bb0 * 1024 + q0 * 4);
      float4 fB = *(const float4*)(fsrc + bb1 * 1024 + q1 * 4);
      for (int ch = 0; ch < 8; ++ch) {
        *(float4*)(hch + bb0 * 132 + q0 * 4) = fA;
        *(float4*)(hch + bb1 * 132 + q1 * 4) = fB;
        __syncthreads();
        if (ch < 7) {
          fA = *(const float4*)(fsrc + bb0 * 1024 + (ch + 1) * 128 + q0 * 4);
          fB = *(const float4*)(fsrc + bb1 * 1024 + (ch + 1) * 128 + q1 * 4);
        }
        const float* hrow = hch + b * 132;
        const float* p0 = wx + ch * 128;
#pragma unroll 8
        for (int q = 0; q < 32; ++q) {
          float4 f4 = *(const float4*)(hrow + q * 4);
          float4 a4 = *(const float4*)(p0 + q * 4);
          acc += f4.x * a4.x + f4.y * a4.y + f4.z * a4.z + f4.w * a4.w;
        }
        __syncthreads();
      }
    }

    gpart[b][g * 4 + ci] = acc + xgv;
    if (g < 2) projp[g][tt] = projacc;
    __syncthreads();
    if (t < 128) {
      float gi = gpart[b][ci + 0] + bias_s[ci + 0];
      float gf = gpart[b][ci + 4] + bias_s[ci + 4];
      float gg = gpart[b][ci + 8] + bias_s[ci + 8];
      float go = gpart[b][ci + 12] + bias_s[ci + 12];
      float cn = sigm(gf) * c_reg + sigm(gi) * tanhx(gg);
      c_reg = cn;
      stc(henc + dir * 32768 + (it & 1) * 16384 + b * 512 + col,
          sigm(go) * tanhx(cn));
    } else if (g == 1 && it > 0) {
      const int sp = dir ? (512 - it) : (it - 1);
      const float p = projp[0][tt] + projp[1][tt];
      float* addr = enc_proj + ((size_t)sp * 32 + b) * 512 + col;
      if (it - 1 <= 255) {
        stc(addr, p + benc_s[ci]);
      } else {
        stc(addr, ldc(addr) + p);
      }
    }
    tree_barrier(bar, w, it + 1);
  }

  // post-loop: proj for e=511 (second arriver), and cfin
  {
    const float* hsrc = henc + dir * 32768 + 16384;
    float projacc = 0.0f;
    for (int ch = 0; ch < 4; ++ch) {
      for (int i = t; i < 1024; i += 512) {
        int bb = i >> 5, q = i & 31;
        const float* sp = hsrc + bb * 512 + ch * 128 + q * 4;
        float2 f0 = ldc2(sp);
        float2 f1 = ldc2(sp + 2);
        *(float4*)(hch + bb * 132 + q * 4) = make_float4(f0.x, f0.y, f1.x, f1.y);
      }
      __syncthreads();
      if (g < 2) {
        const float* hp = hch + b * 132 + g * 64;
        const float* wp = wpe + ch * 128 + g * 64;
#pragma unroll 4
        for (int kk = 0; kk < 16; ++kk) {
          float4 h4 = *(const float4*)(hp + kk * 4);
          float4 w4 = *(const float4*)(wp + kk * 4);
          projacc += h4.x * w4.x + h4.y * w4.y + h4.z * w4.z + h4.w * w4.w;
        }
      }
      __syncthreads();
    }
    if (g < 2) projp[g][tt] = projacc;
    __syncthreads();
    if (g == 1) {
      const int sp = dir ? 0 : 511;
      float* addr = enc_proj + ((size_t)sp * 32 + b) * 512 + col;
      stc(addr, ldc(addr) + (projp[0][tt] + projp[1][tt]));
    }
    if (t < 128) cfin[dir * 16384 + b * 512 + col] = c_reg;
  }
}

// ---------------------------------------------------------------------------
// Decoder: 3 barriers/step. Phase D folded into phase A (local ib reduce);
// phase B via LDS-staged hnext + 8-way k-split + shfl butterfly.
// ---------------------------------------------------------------------------
__global__ __launch_bounds__(512) void decoder_kernel(
    const float* __restrict__ feats,
    const float* __restrict__ Wih_d, const float* __restrict__ Whh_d,
    const float* __restrict__ bih_d, const float* __restrict__ bhh_d,
    const float* __restrict__ W_dec, const float* __restrict__ b_dec,
    const float* __restrict__ W_v, const float* __restrict__ b_v,
    const float* __restrict__ enc_proj, const float* __restrict__ henc,
    const float* __restrict__ cfin,
    float* __restrict__ hbuf, float* __restrict__ dproj,
    float* __restrict__ pval, int* __restrict__ pidx,
    int* __restrict__ bar, float* __restrict__ out)
{
  extern __shared__ __align__(16) float dyn[];
  float* whh_l = dyn;            // 16 x 1028
  float* wih_l = dyn + 16448;    // 16 x 1028
  __shared__ float hch[32 * 132];   // staging; aliased by dpl (barrier-safe)
  __shared__ float gpart[2][32][17];
  __shared__ float c_lds[32][4];
  __shared__ float bias_s[16];
  __shared__ float svals[64];
  __shared__ int ib_lds[32];
  float* dpl = hch + 1088;   // [8][68] dproj slice for phase C (alias)

  const int w = blockIdx.x;
  const int t = threadIdx.x;
  const int q4 = t >> 7;
  const int tt = t & 127;
  const int b = tt >> 2;
  const int ci = tt & 3;
  const int col0 = w * 4;
  const int col = col0 + ci;
  const int i0 = t, i1 = t + 512;
  const int bb0 = i0 >> 5, q0 = i0 & 31;
  const int bb1 = i1 >> 5, q1 = i1 & 31;
  const int bb_c = w >> 3;   // phase C batch
  const int qq_ = w & 7;     // phase C s-block
  const int ccB = t >> 8;            // phase B: col 2w+ccB
  const int bB = (t >> 3) & 31;      // phase B batch
  const int k8 = t & 7;              // phase B k-slice

  for (int i = t; i < 16 * 256; i += 512) {
    int r = i >> 8, q = i & 255;
    int gg = r >> 2, cj = r & 3;
    *(float4*)(whh_l + r * 1028 + q * 4) =
        *(const float4*)(Whh_d + (size_t)(gg * 1024 + col0 + cj) * 1024 + q * 4);
    *(float4*)(wih_l + r * 1028 + q * 4) =
        *(const float4*)(Wih_d + (size_t)(gg * 1024 + col0 + cj) * 1024 + q * 4);
  }
  if (t < 16) {
    int gg = t >> 2, cj = t & 3;
    bias_s[t] = bih_d[gg * 1024 + col0 + cj] + bhh_d[gg * 1024 + col0 + cj];
  }
  if (t < 128) {
    int flat = b * 1024 + col;
    int d = flat >> 14, sb = (flat >> 9) & 31, sh = flat & 511;
    float h0, c0;
    if (d == 0) {
      h0 = henc[16384 + sb * 512 + sh];
      c0 = cfin[sb * 512 + sh];
    } else {
      h0 = henc[32768 + 16384 + sb * 512 + sh];
      c0 = cfin[16384 + sb * 512 + sh];
    }
    stc(hbuf + b * 1024 + col, h0);
    c_lds[b][ci] = c0;
  }
  int bars = 1;
  tree_barrier(bar, w, bars);

  const float* wbase = (q4 < 2) ? whh_l : wih_l;
  const int g0 = (q4 & 1) * 2;
  const float* wr0 = wbase + (size_t)((g0 + 0) * 4 + ci) * 1028;
  const float* wr1 = wbase + (size_t)((g0 + 1) * 4 + ci) * 1028;

  for (int ts = 0; ts < 128; ++ts) {
    const float* hprev = hbuf + (ts & 1) * 32768;
    float* hnext = hbuf + ((ts + 1) & 1) * 32768;

    // ---- phase A: gates GEMM (T14-staged hprev) + cell; ib reduce folded ----
    float a0 = 0.f, a1 = 0.f;
    const float* xrow = nullptr;
    {
      float2 rA0 = ldc2(hprev + bb0 * 1024 + q0 * 4);
      float2 rA1 = ldc2(hprev + bb0 * 1024 + q0 * 4 + 2);
      float2 rB0 = ldc2(hprev + bb1 * 1024 + q1 * 4);
      float2 rB1 = ldc2(hprev + bb1 * 1024 + q1 * 4 + 2);
      // folded phase D: per-batch argmax from 8 partials (prev step's phase C)
      if (t < 32) {
        int ib = 0;
        if (ts > 0) {
          float v = ldc(pval + t * 8 + 0);
          int si = ldci(pidx + t * 8 + 0);
#pragma unroll
          for (int j = 1; j < 8; ++j) {
            float ov = ldc(pval + t * 8 + j);
            int os = ldci(pidx + t * 8 + j);
            if (ov > v || (ov == v && os < si)) { v = ov; si = os; }
          }
          ib = si;
        }
        ib_lds[t] = ib;
      }
      for (int ch = 0; ch < 8; ++ch) {
        *(float4*)(hch + bb0 * 132 + q0 * 4) = make_float4(rA0.x, rA0.y, rA1.x, rA1.y);
        *(float4*)(hch + bb1 * 132 + q1 * 4) = make_float4(rB0.x, rB0.y, rB1.x, rB1.y);
        __syncthreads();
        if (ch == 0 && q4 >= 2) {
          int ib = ib_lds[b];
          xrow = feats + ((size_t)ib * 32 + b) * 1024;
        }
        if (ch < 7) {
          rA0 = ldc2(hprev + bb0 * 1024 + (ch + 1) * 128 + q0 * 4);
          rA1 = ldc2(hprev + bb0 * 1024 + (ch + 1) * 128 + q0 * 4 + 2);
          rB0 = ldc2(hprev + bb1 * 1024 + (ch + 1) * 128 + q1 * 4);
          rB1 = ldc2(hprev + bb1 * 1024 + (ch + 1) * 128 + q1 * 4 + 2);
        }
        const float* src = (q4 < 2) ? (hch + b * 132) : (xrow + ch * 128);
        const float* p0 = wr0 + ch * 128;
        const float* p1 = wr1 + ch * 128;
#pragma unroll 8
        for (int qq = 0; qq < 32; ++qq) {
          float4 h4 = *(const float4*)(src + qq * 4);
          float4 u0 = *(const float4*)(p0 + qq * 4);
          float4 u1 = *(const float4*)(p1 + qq * 4);
          a0 += h4.x * u0.x + h4.y * u0.y + h4.z * u0.z + h4.w * u0.w;
          a1 += h4.x * u1.x + h4.y * u1.y + h4.z * u1.z + h4.w * u1.w;
        }
        __syncthreads();
      }
    }
    gpart[q4 >> 1][b][ci + (g0 + 0) * 4] = a0;
    gpart[q4 >> 1][b][ci + (g0 + 1) * 4] = a1;
    __syncthreads();
    if (t < 128) {
      float gi = gpart[0][b][ci + 0] + gpart[1][b][ci + 0] + bias_s[ci + 0];
      float gf = gpart[0][b][ci + 4] + gpart[1][b][ci + 4] + bias_s[ci + 4];
      float gg = gpart[0][b][ci + 8] + gpart[1][b][ci + 8] + bias_s[ci + 8];
      float go = gpart[0][b][ci + 12] + gpart[1][b][ci + 12] + bias_s[ci + 12];
      float cn = sigm(gf) * c_lds[b][ci] + sigm(gi) * tanhx(gg);
      c_lds[b][ci] = cn;
      stc(hnext + b * 1024 + col, sigm(go) * tanhx(cn));
    }
    ++bars; tree_barrier(bar, w, bars);

    // ---- phase B: dproj cols {2w,2w+1}; hnext LDS-staged, 8-way k-split ----
    {
      float dacc = 0.f;
      const float* wdrow = W_dec + (size_t)(2 * w + ccB) * 1024;
      float2 rA0 = ldc2(hnext + bb0 * 1024 + q0 * 4);
      float2 rA1 = ldc2(hnext + bb0 * 1024 + q0 * 4 + 2);
      float2 rB0 = ldc2(hnext + bb1 * 1024 + q1 * 4);
      float2 rB1 = ldc2(hnext + bb1 * 1024 + q1 * 4 + 2);
      for (int ch = 0; ch < 8; ++ch) {
        *(float4*)(hch + bb0 * 132 + q0 * 4) = make_float4(rA0.x, rA0.y, rA1.x, rA1.y);
        *(float4*)(hch + bb1 * 132 + q1 * 4) = make_float4(rB0.x, rB0.y, rB1.x, rB1.y);
        __syncthreads();
        if (ch < 7) {
          rA0 = ldc2(hnext + bb0 * 1024 + (ch + 1) * 128 + q0 * 4);
          rA1 = ldc2(hnext + bb0 * 1024 + (ch + 1) * 128 + q0 * 4 + 2);
          rB0 = ldc2(hnext + bb1 * 1024 + (ch + 1) * 128 + q1 * 4);
          rB1 = ldc2(hnext + bb1 * 1024 + (ch + 1) * 128 + q1 * 4 + 2);
        }
        const float* hl = hch + bB * 132 + k8 * 16;
        const float* wl = wdrow + ch * 128 + k8 * 16;
#pragma unroll
        for (int j = 0; j < 4; ++j) {
          float4 h4 = *(const float4*)(hl + j * 4);
          float4 w4 = *(const float4*)(wl + j * 4);
          dacc += h4.x * w4.x + h4.y * w4.y + h4.z * w4.z + h4.w * w4.w;
        }
        __syncthreads();
      }
      dacc += __shfl_xor(dacc, 1);
      dacc += __shfl_xor(dacc, 2);
      dacc += __shfl_xor(dacc, 4);
      if (k8 == 0) stc(dproj + bB * 512 + 2 * w + ccB, dacc + b_dec[2 * w + ccB]);
    }
    ++bars; tree_barrier(bar, w, bars);

    // ---- phase C: scores, batch-major (WG: bb_c, s-block qq_) ----
    if (t < 256) {
      float2 v = ldc2(dproj + bb_c * 512 + 2 * t);
      int k = 2 * t;
      dpl[(k >> 6) * 68 + (k & 63) + 0] = v.x;
      dpl[(k >> 6) * 68 + (k & 63) + 1] = v.y;
    }
    __syncthreads();
    {
      const int sl = t >> 3, ks = t & 7;
      const int s = qq_ * 64 + sl;
      const float* ep = enc_proj + ((size_t)s * 32 + bb_c) * 512 + ks * 64;
      const float* dpp = dpl + ks * 68;
      const float* wvp = W_v + ks * 64;
      float sum = 0.f;
#pragma unroll 4
      for (int j = 0; j < 16; ++j) {
        float4 e4 = *(const float4*)(ep + j * 4);
        float4 d4 = *(const float4*)(dpp + j * 4);
        float4 v4 = *(const float4*)(wvp + j * 4);
        sum += tanhx(e4.x + d4.x) * v4.x;
        sum += tanhx(e4.y + d4.y) * v4.y;
        sum += tanhx(e4.z + d4.z) * v4.z;
        sum += tanhx(e4.w + d4.w) * v4.w;
      }
      sum += __shfl_xor(sum, 1);
      sum += __shfl_xor(sum, 2);
      sum += __shfl_xor(sum, 4);
      if (ks == 0) {
        float sv = sum + b_v[0];
        out[((size_t)ts * 32 + bb_c) * 512 + s] = sv;
        svals[sl] = sv;
      }
    }
    __syncthreads();
    if (t < 64) {  // per-WG argmax over its 64 s values (tie -> smaller s)
      float v = svals[t];
      int si = qq_ * 64 + t;
#pragma unroll
      for (int m = 1; m < 64; m <<= 1) {
        float ov = __shfl_xor(v, m);
        int os = __shfl_xor(si, m);
        if (ov > v || (ov == v && os < si)) { v = ov; si = os; }
      }
      if (t == 0) {
        stc(pval + bb_c * 8 + qq_, v);
        stci(pidx + bb_c * 8 + qq_, si);
      }
    }
    ++bars; tree_barrier(bar, w, bars);
  }
}

// ---------------------------------------------------------------------------
extern "C" void kernel_launch(void* const* d_in, const int* in_sizes, int n_in,
                              void* d_out, int out_size, void* d_ws, size_t ws_size,
                              hipStream_t stream) {
  (void)in_sizes; (void)n_in; (void)out_size;
  const float* feats = (const float*)d_in[0];
  const float* Wih_f = (const float*)d_in[1];
  const float* Whh_f = (const float*)d_in[2];
  const float* bih_f = (const float*)d_in[3];
  const float* bhh_f = (const float*)d_in[4];
  const float* Wih_b = (const float*)d_in[5];
  const float* Whh_b = (const float*)d_in[6];
  const float* bih_b = (const float*)d_in[7];
  const float* bhh_b = (const float*)d_in[8];
  const float* Wih_d = (const float*)d_in[9];
  const float* Whh_d = (const float*)d_in[10];
  const float* bih_d = (const float*)d_in[11];
  const float* bhh_d = (const float*)d_in[12];
  const float* W_enc = (const float*)d_in[13];
  const float* b_enc = (const float*)d_in[14];
  const float* W_dec = (const float*)d_in[15];
  const float* b_dec = (const float*)d_in[16];
  const float* W_v   = (const float*)d_in[17];
  const float* b_v   = (const float*)d_in[18];
  float* out = (float*)d_out;

  int* ctrl = (int*)d_ws;
  int* bar_enc = ctrl;
  int* bar_dec = ctrl + 8192;
  float* base = (float*)d_ws + 16384;        // after 64 KiB ctrl block
  float* enc_proj = base;                    // 8,388,608
  float* henc     = enc_proj + 8388608;      //    65,536
  float* cfin     = henc + 65536;            //    32,768
  float* hbuf     = cfin + 32768;            //    65,536
  float* dproj    = hbuf + 65536;            //    16,384
  float* pval     = dproj + 16384;           //     8,192 (256 used)
  int*   pidx     = (int*)(pval + 8192);     //     8,192 (256 used)
  float* xg_base  = pval + 16384;            // 2 x 16384 x 2048
  // base usage ~34.4 MB; + xg 268.4 MB if enabled

  const size_t xg_elems = (size_t)16384 * 2048;
  const size_t need_xg_bytes =
      (size_t)(16384 + 8388608 + 65536 + 32768 + 65536 + 16384 + 16384) * 4 +
      2 * xg_elems * 4 + (1 << 20);
  const bool use_xg = ws_size >= need_xg_bytes;
  const float* xg_f = use_xg ? xg_base : nullptr;
  const float* xg_b = use_xg ? (xg_base + xg_elems) : nullptr;

  const int ENC_LDS = (16 * 1028 + 16 * 516) * 4;   //  98,816 B
  const int DEC_LDS = (2 * 16 * 1028) * 4;          // 131,584 B
  hipFuncSetAttribute((const void*)encoder_kernel,
                      hipFuncAttributeMaxDynamicSharedMemorySize, ENC_LDS);
  hipFuncSetAttribute((const void*)decoder_kernel,
                      hipFuncAttributeMaxDynamicSharedMemorySize, DEC_LDS);

  hipMemsetAsync(d_ws, 0, 65536, stream);

  if (use_xg) {
    dim3 gg(256, 32);
    xproj_gemm<<<gg, 256, 0, stream>>>(feats, Wih_f, (float*)xg_f);
    xproj_gemm<<<gg, 256, 0, stream>>>(feats, Wih_b, (float*)xg_b);
  }

  {
    void* args[] = {(void*)&feats,
                    (void*)&Wih_f, (void*)&Whh_f, (void*)&bih_f, (void*)&bhh_f,
                    (void*)&Wih_b, (void*)&Whh_b, (void*)&bih_b, (void*)&bhh_b,
                    (void*)&W_enc, (void*)&b_enc, (void*)&xg_f, (void*)&xg_b,
                    (void*)&enc_proj, (void*)&henc, (void*)&cfin, (void*)&bar_enc};
    hipLaunchCooperativeKernel((const void*)encoder_kernel, dim3(NWG), dim3(512),
                               args, ENC_LDS, stream);
  }
  {
    void* args[] = {(void*)&feats,
                    (void*)&Wih_d, (void*)&Whh_d, (void*)&bih_d, (void*)&bhh_d,
                    (void*)&W_dec, (void*)&b_dec, (void*)&W_v, (void*)&b_v,
                    (void*)&enc_proj, (void*)&henc, (void*)&cfin,
                    (void*)&hbuf, (void*)&dproj, (void*)&pval, (void*)&pidx,
                    (void*)&bar_dec, (void*)&out};
    hipLaunchCooperativeKernel((const void*)decoder_kernel, dim3(NWG), dim3(512),
                               args, DEC_LDS, stream);
  }
}

// Round 14
// 17660.469 us; speedup vs baseline: 5.1875x; 1.0975x over previous
//
#include <hip/hip_runtime.h>
#include <stdint.h>

// F=1024, H=512, S=512, B=32, T=128
// Round-13 with ONE fix: encoder post-loop staging loop bound 8192 -> 2048
// (each i writes a float4; 8192 caused OOB shared writes that corrupted wenc
// and poisoned enc_proj rows s=511/s=0 -> flipped argmax, absmax 1.32).
// Encoder: 256-wide chunks (12 syncs/step), x-phase first, h-loads pre-issued.
// Decoder: 3 barriers/step, 2-deep register prefetch in phase A/B staging.

#define NWG 256

__device__ __forceinline__ float sigm(float x) { return 1.0f / (1.0f + __expf(-x)); }
__device__ __forceinline__ float tanhx(float x) {
  float e = __expf(2.0f * x);
  return 1.0f - 2.0f / (e + 1.0f);
}

__device__ __forceinline__ float ldc(const float* p) {
  return __hip_atomic_load(p, __ATOMIC_RELAXED, __HIP_MEMORY_SCOPE_AGENT);
}
__device__ __forceinline__ float2 ldc2(const float* p) {
  double d = __hip_atomic_load((const double*)p, __ATOMIC_RELAXED, __HIP_MEMORY_SCOPE_AGENT);
  return __builtin_bit_cast(float2, d);
}
__device__ __forceinline__ void stc(float* p, float v) {
  __hip_atomic_store(p, v, __ATOMIC_RELAXED, __HIP_MEMORY_SCOPE_AGENT);
}
__device__ __forceinline__ int ldci(const int* p) {
  return __hip_atomic_load(p, __ATOMIC_RELAXED, __HIP_MEMORY_SCOPE_AGENT);
}
__device__ __forceinline__ void stci(int* p, int v) {
  __hip_atomic_store(p, v, __ATOMIC_RELAXED, __HIP_MEMORY_SCOPE_AGENT);
}

__device__ __forceinline__ void tree_barrier(int* bar, int w, int epoch) {
  __syncthreads();
  if (threadIdx.x == 0) {
    const int g = w >> 3;
    int* gc = bar + g * 64;
    int* rc = bar + 2048;
    int* gf = bar + 2112 + g * 64;
    int old = __hip_atomic_fetch_add(gc, 1, __ATOMIC_RELAXED, __HIP_MEMORY_SCOPE_AGENT);
    if (old == epoch * 8 - 1) {
      __hip_atomic_fetch_add(rc, 1, __ATOMIC_RELAXED, __HIP_MEMORY_SCOPE_AGENT);
      while (__hip_atomic_load(rc, __ATOMIC_RELAXED, __HIP_MEMORY_SCOPE_AGENT) < epoch * 32)
        __builtin_amdgcn_s_sleep(2);
      __hip_atomic_store(gf, epoch, __ATOMIC_RELAXED, __HIP_MEMORY_SCOPE_AGENT);
    } else {
      while (__hip_atomic_load(gf, __ATOMIC_RELAXED, __HIP_MEMORY_SCOPE_AGENT) < epoch)
        __builtin_amdgcn_s_sleep(2);
    }
  }
  __syncthreads();
}

// ---------------------------------------------------------------------------
// Encoder: 256 WGs x 512 thr. Weights LDS-resident. Per step: x-phase
// (4 x 256-wide chunks from feats) then h-phase (2 x 256-wide chunks from
// henc, coherent, all loads pre-issued at loop top).
// ---------------------------------------------------------------------------
__global__ __launch_bounds__(512) void encoder_kernel(
    const float* __restrict__ feats,
    const float* __restrict__ Wih_f, const float* __restrict__ Whh_f,
    const float* __restrict__ bih_f, const float* __restrict__ bhh_f,
    const float* __restrict__ Wih_b, const float* __restrict__ Whh_b,
    const float* __restrict__ bih_b, const float* __restrict__ bhh_b,
    const float* __restrict__ W_enc, const float* __restrict__ b_enc,
    float* __restrict__ enc_proj, float* __restrict__ henc,
    float* __restrict__ cfin, int* __restrict__ bar)
{
  extern __shared__ __align__(16) float dyn[];
  float* wih_l = dyn;            // 16 x 1028
  float* whh_l = dyn + 16448;    // 16 x 516
  __shared__ float hch[32 * 260];   // 256-wide staging chunk (+pad)
  __shared__ float wenc[4 * 516];
  __shared__ float gpart[32][17];
  __shared__ float projp[2][128];
  __shared__ float bias_s[16];
  __shared__ float benc_s[4];

  const int w = blockIdx.x;
  const int dir = (w >= 128) ? 1 : 0;
  const int wl = w & 127;
  const int col0 = wl * 4;
  const int t = threadIdx.x;
  const int g = t >> 7;
  const int tt = t & 127;
  const int b = tt >> 2;
  const int ci = tt & 3;
  const int col = col0 + ci;
  // 4 float4 positions per thread in a [32][256] chunk
  const int p0i = t,        p0b = p0i >> 6, p0q = p0i & 63;
  const int p1i = t + 512,  p1b = p1i >> 6, p1q = p1i & 63;
  const int p2i = t + 1024, p2b = p2i >> 6, p2q = p2i & 63;
  const int p3i = t + 1536, p3b = p3i >> 6, p3q = p3i & 63;

  const float* Wih = dir ? Wih_b : Wih_f;
  const float* Whh = dir ? Whh_b : Whh_f;
  const float* bih = dir ? bih_b : bih_f;
  const float* bhh = dir ? bhh_b : bhh_f;

  for (int i = t; i < 16 * 256; i += 512) {
    int r = i >> 8, q = i & 255;
    int gg = r >> 2, cj = r & 3;
    *(float4*)(wih_l + r * 1028 + q * 4) =
        *(const float4*)(Wih + (size_t)(gg * 512 + col0 + cj) * 1024 + q * 4);
  }
  for (int i = t; i < 16 * 128; i += 512) {
    int r = i >> 7, q = i & 127;
    int gg = r >> 2, cj = r & 3;
    *(float4*)(whh_l + r * 516 + q * 4) =
        *(const float4*)(Whh + (size_t)(gg * 512 + col0 + cj) * 512 + q * 4);
  }
  for (int i = t; i < 4 * 128; i += 512) {
    int jl = i >> 7, q = i & 127;
    *(float4*)(wenc + jl * 516 + q * 4) =
        *(const float4*)(W_enc + (size_t)(col0 + jl) * 1024 + dir * 512 + q * 4);
  }
  if (t < 16) {
    int gg = t >> 2, cj = t & 3;
    bias_s[t] = bih[gg * 512 + col0 + cj] + bhh[gg * 512 + col0 + cj];
  }
  if (t < 4) benc_s[t] = b_enc[col0 + t];
  float c_reg = 0.0f;
  __syncthreads();

  const float* wx = wih_l + (g * 4 + ci) * 1028;
  const float* wh = whh_l + (g * 4 + ci) * 516;
  const float* wpe = wenc + ci * 516;

  for (int it = 0; it < 512; ++it) {
    const int s = dir ? (511 - it) : it;
    float acc = 0.0f, projacc = 0.0f;
    const float* fsrc = feats + ((size_t)s * 32) * 1024;
    const float* hsrc = henc + dir * 32768 + ((it - 1) & 1) * 16384;

    // ---- issue ALL h-chunk coherent loads up front (hidden under x) ----
    float2 h00a, h00b, h01a, h01b, h02a, h02b, h03a, h03b;
    float2 h10a, h10b, h11a, h11b, h12a, h12b, h13a, h13b;
    if (it > 0) {
      const float* sp;
      sp = hsrc + p0b * 512 + p0q * 4;       h00a = ldc2(sp); h00b = ldc2(sp + 2);
      sp = hsrc + p1b * 512 + p1q * 4;       h01a = ldc2(sp); h01b = ldc2(sp + 2);
      sp = hsrc + p2b * 512 + p2q * 4;       h02a = ldc2(sp); h02b = ldc2(sp + 2);
      sp = hsrc + p3b * 512 + p3q * 4;       h03a = ldc2(sp); h03b = ldc2(sp + 2);
      sp = hsrc + p0b * 512 + 256 + p0q * 4; h10a = ldc2(sp); h10b = ldc2(sp + 2);
      sp = hsrc + p1b * 512 + 256 + p1q * 4; h11a = ldc2(sp); h11b = ldc2(sp + 2);
      sp = hsrc + p2b * 512 + 256 + p2q * 4; h12a = ldc2(sp); h12b = ldc2(sp + 2);
      sp = hsrc + p3b * 512 + 256 + p3q * 4; h13a = ldc2(sp); h13b = ldc2(sp + 2);
    }

    // ---- x phase: 4 chunks of [32][256] from feats (plain loads) ----
    {
      float4 xv0 = *(const float4*)(fsrc + p0b * 1024 + p0q * 4);
      float4 xv1 = *(const float4*)(fsrc + p1b * 1024 + p1q * 4);
      float4 xv2 = *(const float4*)(fsrc + p2b * 1024 + p2q * 4);
      float4 xv3 = *(const float4*)(fsrc + p3b * 1024 + p3q * 4);
      for (int ch = 0; ch < 4; ++ch) {
        *(float4*)(hch + p0b * 260 + p0q * 4) = xv0;
        *(float4*)(hch + p1b * 260 + p1q * 4) = xv1;
        *(float4*)(hch + p2b * 260 + p2q * 4) = xv2;
        *(float4*)(hch + p3b * 260 + p3q * 4) = xv3;
        __syncthreads();
        if (ch < 3) {
          xv0 = *(const float4*)(fsrc + p0b * 1024 + (ch + 1) * 256 + p0q * 4);
          xv1 = *(const float4*)(fsrc + p1b * 1024 + (ch + 1) * 256 + p1q * 4);
          xv2 = *(const float4*)(fsrc + p2b * 1024 + (ch + 1) * 256 + p2q * 4);
          xv3 = *(const float4*)(fsrc + p3b * 1024 + (ch + 1) * 256 + p3q * 4);
        }
        const float* hrow = hch + b * 260;
        const float* pw = wx + ch * 256;
#pragma unroll 8
        for (int q = 0; q < 64; ++q) {
          float4 f4 = *(const float4*)(hrow + q * 4);
          float4 a4 = *(const float4*)(pw + q * 4);
          acc += f4.x * a4.x + f4.y * a4.y + f4.z * a4.z + f4.w * a4.w;
        }
        __syncthreads();
      }
    }

    // ---- h phase: 2 chunks of [32][256] from registers ----
    if (it > 0) {
      // chunk 0
      *(float4*)(hch + p0b * 260 + p0q * 4) = make_float4(h00a.x, h00a.y, h00b.x, h00b.y);
      *(float4*)(hch + p1b * 260 + p1q * 4) = make_float4(h01a.x, h01a.y, h01b.x, h01b.y);
      *(float4*)(hch + p2b * 260 + p2q * 4) = make_float4(h02a.x, h02a.y, h02b.x, h02b.y);
      *(float4*)(hch + p3b * 260 + p3q * 4) = make_float4(h03a.x, h03a.y, h03b.x, h03b.y);
      __syncthreads();
      {
        const float* hrow = hch + b * 260;
        const float* pw = wh;
#pragma unroll 8
        for (int q = 0; q < 64; ++q) {
          float4 h4 = *(const float4*)(hrow + q * 4);
          float4 a4 = *(const float4*)(pw + q * 4);
          acc += h4.x * a4.x + h4.y * a4.y + h4.z * a4.z + h4.w * a4.w;
        }
        if (g < 2) {
          const float* hp = hch + b * 260 + g * 128;
          const float* wp = wpe + g * 128;
#pragma unroll 4
          for (int kk = 0; kk < 32; ++kk) {
            float4 h4 = *(const float4*)(hp + kk * 4);
            float4 w4 = *(const float4*)(wp + kk * 4);
            projacc += h4.x * w4.x + h4.y * w4.y + h4.z * w4.z + h4.w * w4.w;
          }
        }
      }
      __syncthreads();
      // chunk 1
      *(float4*)(hch + p0b * 260 + p0q * 4) = make_float4(h10a.x, h10a.y, h10b.x, h10b.y);
      *(float4*)(hch + p1b * 260 + p1q * 4) = make_float4(h11a.x, h11a.y, h11b.x, h11b.y);
      *(float4*)(hch + p2b * 260 + p2q * 4) = make_float4(h12a.x, h12a.y, h12b.x, h12b.y);
      *(float4*)(hch + p3b * 260 + p3q * 4) = make_float4(h13a.x, h13a.y, h13b.x, h13b.y);
      __syncthreads();
      {
        const float* hrow = hch + b * 260;
        const float* pw = wh + 256;
#pragma unroll 8
        for (int q = 0; q < 64; ++q) {
          float4 h4 = *(const float4*)(hrow + q * 4);
          float4 a4 = *(const float4*)(pw + q * 4);
          acc += h4.x * a4.x + h4.y * a4.y + h4.z * a4.z + h4.w * a4.w;
        }
        if (g < 2) {
          const float* hp = hch + b * 260 + g * 128;
          const float* wp = wpe + 256 + g * 128;
#pragma unroll 4
          for (int kk = 0; kk < 32; ++kk) {
            float4 h4 = *(const float4*)(hp + kk * 4);
            float4 w4 = *(const float4*)(wp + kk * 4);
            projacc += h4.x * w4.x + h4.y * w4.y + h4.z * w4.z + h4.w * w4.w;
          }
        }
      }
      __syncthreads();
    }

    gpart[b][g * 4 + ci] = acc;
    if (g < 2) projp[g][tt] = projacc;
    __syncthreads();
    if (t < 128) {
      float gi = gpart[b][ci + 0] + bias_s[ci + 0];
      float gf = gpart[b][ci + 4] + bias_s[ci + 4];
      float gg = gpart[b][ci + 8] + bias_s[ci + 8];
      float go = gpart[b][ci + 12] + bias_s[ci + 12];
      float cn = sigm(gf) * c_reg + sigm(gi) * tanhx(gg);
      c_reg = cn;
      stc(henc + dir * 32768 + (it & 1) * 16384 + b * 512 + col,
          sigm(go) * tanhx(cn));
    } else if (g == 1 && it > 0) {
      const int sp = dir ? (512 - it) : (it - 1);
      const float p = projp[0][tt] + projp[1][tt];
      float* addr = enc_proj + ((size_t)sp * 32 + b) * 512 + col;
      if (it - 1 <= 255) {
        stc(addr, p + benc_s[ci]);
      } else {
        stc(addr, ldc(addr) + p);
      }
    }
    tree_barrier(bar, w, it + 1);
  }

  // post-loop: proj for e=511 (second arriver), and cfin
  {
    const float* hsrc = henc + dir * 32768 + 16384;  // h[511] at pp=1
    float projacc = 0.0f;
    for (int ch = 0; ch < 2; ++ch) {
      for (int i = t; i < 2048; i += 512) {   // 2048 float4s = [32][256] chunk
        int bb = i >> 6, qf = i & 63;
        const float* sp = hsrc + bb * 512 + ch * 256 + qf * 4;
        float2 f0 = ldc2(sp);
        float2 f1 = ldc2(sp + 2);
        *(float4*)(hch + bb * 260 + qf * 4) = make_float4(f0.x, f0.y, f1.x, f1.y);
      }
      __syncthreads();
      if (g < 2) {
        const float* hp = hch + b * 260 + g * 128;
        const float* wp = wpe + ch * 256 + g * 128;
#pragma unroll 4
        for (int kk = 0; kk < 32; ++kk) {
          float4 h4 = *(const float4*)(hp + kk * 4);
          float4 w4 = *(const float4*)(wp + kk * 4);
          projacc += h4.x * w4.x + h4.y * w4.y + h4.z * w4.z + h4.w * w4.w;
        }
      }
      __syncthreads();
    }
    if (g < 2) projp[g][tt] = projacc;
    __syncthreads();
    if (g == 1) {
      const int sp = dir ? 0 : 511;
      float* addr = enc_proj + ((size_t)sp * 32 + b) * 512 + col;
      stc(addr, ldc(addr) + (projp[0][tt] + projp[1][tt]));
    }
    if (t < 128) cfin[dir * 16384 + b * 512 + col] = c_reg;
  }
}

// ---------------------------------------------------------------------------
// Decoder: 3 barriers/step (phase D folded into A). Phase A/B staging with
// 2-deep register prefetch. Phase C batch-major as round 12.
// ---------------------------------------------------------------------------
__global__ __launch_bounds__(512) void decoder_kernel(
    const float* __restrict__ feats,
    const float* __restrict__ Wih_d, const float* __restrict__ Whh_d,
    const float* __restrict__ bih_d, const float* __restrict__ bhh_d,
    const float* __restrict__ W_dec, const float* __restrict__ b_dec,
    const float* __restrict__ W_v, const float* __restrict__ b_v,
    const float* __restrict__ enc_proj, const float* __restrict__ henc,
    const float* __restrict__ cfin,
    float* __restrict__ hbuf, float* __restrict__ dproj,
    float* __restrict__ pval, int* __restrict__ pidx,
    int* __restrict__ bar, float* __restrict__ out)
{
  extern __shared__ __align__(16) float dyn[];
  float* whh_l = dyn;            // 16 x 1028
  float* wih_l = dyn + 16448;    // 16 x 1028
  __shared__ float hch[32 * 132];   // staging; aliased by dpl (barrier-safe)
  __shared__ float gpart[2][32][17];
  __shared__ float c_lds[32][4];
  __shared__ float bias_s[16];
  __shared__ float svals[64];
  __shared__ int ib_lds[32];
  float* dpl = hch + 1088;   // [8][68] dproj slice for phase C (alias)

  const int w = blockIdx.x;
  const int t = threadIdx.x;
  const int q4 = t >> 7;
  const int tt = t & 127;
  const int b = tt >> 2;
  const int ci = tt & 3;
  const int col0 = w * 4;
  const int col = col0 + ci;
  const int i0 = t, i1 = t + 512;
  const int bb0 = i0 >> 5, q0 = i0 & 31;
  const int bb1 = i1 >> 5, q1 = i1 & 31;
  const int bb_c = w >> 3;   // phase C batch
  const int qq_ = w & 7;     // phase C s-block
  const int ccB = t >> 8;            // phase B: col 2w+ccB
  const int bB = (t >> 3) & 31;      // phase B batch
  const int k8 = t & 7;              // phase B k-slice

  for (int i = t; i < 16 * 256; i += 512) {
    int r = i >> 8, q = i & 255;
    int gg = r >> 2, cj = r & 3;
    *(float4*)(whh_l + r * 1028 + q * 4) =
        *(const float4*)(Whh_d + (size_t)(gg * 1024 + col0 + cj) * 1024 + q * 4);
    *(float4*)(wih_l + r * 1028 + q * 4) =
        *(const float4*)(Wih_d + (size_t)(gg * 1024 + col0 + cj) * 1024 + q * 4);
  }
  if (t < 16) {
    int gg = t >> 2, cj = t & 3;
    bias_s[t] = bih_d[gg * 1024 + col0 + cj] + bhh_d[gg * 1024 + col0 + cj];
  }
  if (t < 128) {
    int flat = b * 1024 + col;
    int d = flat >> 14, sb = (flat >> 9) & 31, sh = flat & 511;
    float h0, c0;
    if (d == 0) {
      h0 = henc[16384 + sb * 512 + sh];
      c0 = cfin[sb * 512 + sh];
    } else {
      h0 = henc[32768 + 16384 + sb * 512 + sh];
      c0 = cfin[16384 + sb * 512 + sh];
    }
    stc(hbuf + b * 1024 + col, h0);
    c_lds[b][ci] = c0;
  }
  int bars = 1;
  tree_barrier(bar, w, bars);

  const float* wbase = (q4 < 2) ? whh_l : wih_l;
  const int g0 = (q4 & 1) * 2;
  const float* wr0 = wbase + (size_t)((g0 + 0) * 4 + ci) * 1028;
  const float* wr1 = wbase + (size_t)((g0 + 1) * 4 + ci) * 1028;

  for (int ts = 0; ts < 128; ++ts) {
    const float* hprev = hbuf + (ts & 1) * 32768;
    float* hnext = hbuf + ((ts + 1) & 1) * 32768;

    // ---- phase A: gates GEMM (2-deep staged hprev) + cell; ib folded ----
    float a0 = 0.f, a1 = 0.f;
    const float* xrow = nullptr;
    {
      // set0 <- ch0, set1 <- ch1
      float2 s0a0 = ldc2(hprev + bb0 * 1024 + q0 * 4);
      float2 s0a1 = ldc2(hprev + bb0 * 1024 + q0 * 4 + 2);
      float2 s0b0 = ldc2(hprev + bb1 * 1024 + q1 * 4);
      float2 s0b1 = ldc2(hprev + bb1 * 1024 + q1 * 4 + 2);
      float2 s1a0 = ldc2(hprev + bb0 * 1024 + 128 + q0 * 4);
      float2 s1a1 = ldc2(hprev + bb0 * 1024 + 128 + q0 * 4 + 2);
      float2 s1b0 = ldc2(hprev + bb1 * 1024 + 128 + q1 * 4);
      float2 s1b1 = ldc2(hprev + bb1 * 1024 + 128 + q1 * 4 + 2);
      // folded phase D: per-batch argmax from 8 partials (prev step phase C)
      if (t < 32) {
        int ib = 0;
        if (ts > 0) {
          float v = ldc(pval + t * 8 + 0);
          int si = ldci(pidx + t * 8 + 0);
#pragma unroll
          for (int j = 1; j < 8; ++j) {
            float ov = ldc(pval + t * 8 + j);
            int os = ldci(pidx + t * 8 + j);
            if (ov > v || (ov == v && os < si)) { v = ov; si = os; }
          }
          ib = si;
        }
        ib_lds[t] = ib;
      }
      for (int ch = 0; ch < 8; ++ch) {
        if (ch & 1) {
          *(float4*)(hch + bb0 * 132 + q0 * 4) = make_float4(s1a0.x, s1a0.y, s1a1.x, s1a1.y);
          *(float4*)(hch + bb1 * 132 + q1 * 4) = make_float4(s1b0.x, s1b0.y, s1b1.x, s1b1.y);
        } else {
          *(float4*)(hch + bb0 * 132 + q0 * 4) = make_float4(s0a0.x, s0a0.y, s0a1.x, s0a1.y);
          *(float4*)(hch + bb1 * 132 + q1 * 4) = make_float4(s0b0.x, s0b0.y, s0b1.x, s0b1.y);
        }
        __syncthreads();
        if (ch == 0 && q4 >= 2) {
          int ib = ib_lds[b];
          xrow = feats + ((size_t)ib * 32 + b) * 1024;
        }
        if (ch < 6) {
          const int cn = (ch + 2) * 128;
          if (ch & 1) {
            s1a0 = ldc2(hprev + bb0 * 1024 + cn + q0 * 4);
            s1a1 = ldc2(hprev + bb0 * 1024 + cn + q0 * 4 + 2);
            s1b0 = ldc2(hprev + bb1 * 1024 + cn + q1 * 4);
            s1b1 = ldc2(hprev + bb1 * 1024 + cn + q1 * 4 + 2);
          } else {
            s0a0 = ldc2(hprev + bb0 * 1024 + cn + q0 * 4);
            s0a1 = ldc2(hprev + bb0 * 1024 + cn + q0 * 4 + 2);
            s0b0 = ldc2(hprev + bb1 * 1024 + cn + q1 * 4);
            s0b1 = ldc2(hprev + bb1 * 1024 + cn + q1 * 4 + 2);
          }
        }
        const float* src = (q4 < 2) ? (hch + b * 132) : (xrow + ch * 128);
        const float* p0 = wr0 + ch * 128;
        const float* p1 = wr1 + ch * 128;
#pragma unroll 8
        for (int qq = 0; qq < 32; ++qq) {
          float4 h4 = *(const float4*)(src + qq * 4);
          float4 u0 = *(const float4*)(p0 + qq * 4);
          float4 u1 = *(const float4*)(p1 + qq * 4);
          a0 += h4.x * u0.x + h4.y * u0.y + h4.z * u0.z + h4.w * u0.w;
          a1 += h4.x * u1.x + h4.y * u1.y + h4.z * u1.z + h4.w * u1.w;
        }
        __syncthreads();
      }
    }
    gpart[q4 >> 1][b][ci + (g0 + 0) * 4] = a0;
    gpart[q4 >> 1][b][ci + (g0 + 1) * 4] = a1;
    __syncthreads();
    if (t < 128) {
      float gi = gpart[0][b][ci + 0] + gpart[1][b][ci + 0] + bias_s[ci + 0];
      float gf = gpart[0][b][ci + 4] + gpart[1][b][ci + 4] + bias_s[ci + 4];
      float gg = gpart[0][b][ci + 8] + gpart[1][b][ci + 8] + bias_s[ci + 8];
      float go = gpart[0][b][ci + 12] + gpart[1][b][ci + 12] + bias_s[ci + 12];
      float cn = sigm(gf) * c_lds[b][ci] + sigm(gi) * tanhx(gg);
      c_lds[b][ci] = cn;
      stc(hnext + b * 1024 + col, sigm(go) * tanhx(cn));
    }
    ++bars; tree_barrier(bar, w, bars);

    // ---- phase B: dproj cols {2w,2w+1}; hnext 2-deep staged, 8-way k-split --
    {
      float dacc = 0.f;
      const float* wdrow = W_dec + (size_t)(2 * w + ccB) * 1024;
      float2 s0a0 = ldc2(hnext + bb0 * 1024 + q0 * 4);
      float2 s0a1 = ldc2(hnext + bb0 * 1024 + q0 * 4 + 2);
      float2 s0b0 = ldc2(hnext + bb1 * 1024 + q1 * 4);
      float2 s0b1 = ldc2(hnext + bb1 * 1024 + q1 * 4 + 2);
      float2 s1a0 = ldc2(hnext + bb0 * 1024 + 128 + q0 * 4);
      float2 s1a1 = ldc2(hnext + bb0 * 1024 + 128 + q0 * 4 + 2);
      float2 s1b0 = ldc2(hnext + bb1 * 1024 + 128 + q1 * 4);
      float2 s1b1 = ldc2(hnext + bb1 * 1024 + 128 + q1 * 4 + 2);
      for (int ch = 0; ch < 8; ++ch) {
        if (ch & 1) {
          *(float4*)(hch + bb0 * 132 + q0 * 4) = make_float4(s1a0.x, s1a0.y, s1a1.x, s1a1.y);
          *(float4*)(hch + bb1 * 132 + q1 * 4) = make_float4(s1b0.x, s1b0.y, s1b1.x, s1b1.y);
        } else {
          *(float4*)(hch + bb0 * 132 + q0 * 4) = make_float4(s0a0.x, s0a0.y, s0a1.x, s0a1.y);
          *(float4*)(hch + bb1 * 132 + q1 * 4) = make_float4(s0b0.x, s0b0.y, s0b1.x, s0b1.y);
        }
        __syncthreads();
        if (ch < 6) {
          const int cn = (ch + 2) * 128;
          if (ch & 1) {
            s1a0 = ldc2(hnext + bb0 * 1024 + cn + q0 * 4);
            s1a1 = ldc2(hnext + bb0 * 1024 + cn + q0 * 4 + 2);
            s1b0 = ldc2(hnext + bb1 * 1024 + cn + q1 * 4);
            s1b1 = ldc2(hnext + bb1 * 1024 + cn + q1 * 4 + 2);
          } else {
            s0a0 = ldc2(hnext + bb0 * 1024 + cn + q0 * 4);
            s0a1 = ldc2(hnext + bb0 * 1024 + cn + q0 * 4 + 2);
            s0b0 = ldc2(hnext + bb1 * 1024 + cn + q1 * 4);
            s0b1 = ldc2(hnext + bb1 * 1024 + cn + q1 * 4 + 2);
          }
        }
        const float* hl = hch + bB * 132 + k8 * 16;
        const float* wl = wdrow + ch * 128 + k8 * 16;
#pragma unroll
        for (int j = 0; j < 4; ++j) {
          float4 h4 = *(const float4*)(hl + j * 4);
          float4 w4 = *(const float4*)(wl + j * 4);
          dacc += h4.x * w4.x + h4.y * w4.y + h4.z * w4.z + h4.w * w4.w;
        }
        __syncthreads();
      }
      dacc += __shfl_xor(dacc, 1);
      dacc += __shfl_xor(dacc, 2);
      dacc += __shfl_xor(dacc, 4);
      if (k8 == 0) stc(dproj + bB * 512 + 2 * w + ccB, dacc + b_dec[2 * w + ccB]);
    }
    ++bars; tree_barrier(bar, w, bars);

    // ---- phase C: scores, batch-major (WG: bb_c, s-block qq_) ----
    if (t < 256) {
      float2 v = ldc2(dproj + bb_c * 512 + 2 * t);
      int k = 2 * t;
      dpl[(k >> 6) * 68 + (k & 63) + 0] = v.x;
      dpl[(k >> 6) * 68 + (k & 63) + 1] = v.y;
    }
    __syncthreads();
    {
      const int sl = t >> 3, ks = t & 7;
      const int s = qq_ * 64 + sl;
      const float* ep = enc_proj + ((size_t)s * 32 + bb_c) * 512 + ks * 64;
      const float* dpp = dpl + ks * 68;
      const float* wvp = W_v + ks * 64;
      float sum = 0.f;
#pragma unroll 4
      for (int j = 0; j < 16; ++j) {
        float4 e4 = *(const float4*)(ep + j * 4);
        float4 d4 = *(const float4*)(dpp + j * 4);
        float4 v4 = *(const float4*)(wvp + j * 4);
        sum += tanhx(e4.x + d4.x) * v4.x;
        sum += tanhx(e4.y + d4.y) * v4.y;
        sum += tanhx(e4.z + d4.z) * v4.z;
        sum += tanhx(e4.w + d4.w) * v4.w;
      }
      sum += __shfl_xor(sum, 1);
      sum += __shfl_xor(sum, 2);
      sum += __shfl_xor(sum, 4);
      if (ks == 0) {
        float sv = sum + b_v[0];
        out[((size_t)ts * 32 + bb_c) * 512 + s] = sv;
        svals[sl] = sv;
      }
    }
    __syncthreads();
    if (t < 64) {  // per-WG argmax over its 64 s values (tie -> smaller s)
      float v = svals[t];
      int si = qq_ * 64 + t;
#pragma unroll
      for (int m = 1; m < 64; m <<= 1) {
        float ov = __shfl_xor(v, m);
        int os = __shfl_xor(si, m);
        if (ov > v || (ov == v && os < si)) { v = ov; si = os; }
      }
      if (t == 0) {
        stc(pval + bb_c * 8 + qq_, v);
        stci(pidx + bb_c * 8 + qq_, si);
      }
    }
    ++bars; tree_barrier(bar, w, bars);
  }
}

// ---------------------------------------------------------------------------
extern "C" void kernel_launch(void* const* d_in, const int* in_sizes, int n_in,
                              void* d_out, int out_size, void* d_ws, size_t ws_size,
                              hipStream_t stream) {
  (void)in_sizes; (void)n_in; (void)out_size; (void)ws_size;
  const float* feats = (const float*)d_in[0];
  const float* Wih_f = (const float*)d_in[1];
  const float* Whh_f = (const float*)d_in[2];
  const float* bih_f = (const float*)d_in[3];
  const float* bhh_f = (const float*)d_in[4];
  const float* Wih_b = (const float*)d_in[5];
  const float* Whh_b = (const float*)d_in[6];
  const float* bih_b = (const float*)d_in[7];
  const float* bhh_b = (const float*)d_in[8];
  const float* Wih_d = (const float*)d_in[9];
  const float* Whh_d = (const float*)d_in[10];
  const float* bih_d = (const float*)d_in[11];
  const float* bhh_d = (const float*)d_in[12];
  const float* W_enc = (const float*)d_in[13];
  const float* b_enc = (const float*)d_in[14];
  const float* W_dec = (const float*)d_in[15];
  const float* b_dec = (const float*)d_in[16];
  const float* W_v   = (const float*)d_in[17];
  const float* b_v   = (const float*)d_in[18];
  float* out = (float*)d_out;

  int* ctrl = (int*)d_ws;
  int* bar_enc = ctrl;
  int* bar_dec = ctrl + 8192;
  float* base = (float*)d_ws + 16384;        // after 64 KiB ctrl block
  float* enc_proj = base;                    // 8,388,608
  float* henc     = enc_proj + 8388608;      //    65,536
  float* cfin     = henc + 65536;            //    32,768
  float* hbuf     = cfin + 32768;            //    65,536
  float* dproj    = hbuf + 65536;            //    16,384
  float* pval     = dproj + 16384;           //     8,192 (256 used)
  int*   pidx     = (int*)(pval + 8192);     //     8,192 (256 used)
  // total ~34.4 MB

  const int ENC_LDS = (16 * 1028 + 16 * 516) * 4;   //  98,816 B
  const int DEC_LDS = (2 * 16 * 1028) * 4;          // 131,584 B
  hipFuncSetAttribute((const void*)encoder_kernel,
                      hipFuncAttributeMaxDynamicSharedMemorySize, ENC_LDS);
  hipFuncSetAttribute((const void*)decoder_kernel,
                      hipFuncAttributeMaxDynamicSharedMemorySize, DEC_LDS);

  hipMemsetAsync(d_ws, 0, 65536, stream);

  {
    void* args[] = {(void*)&feats,
                    (void*)&Wih_f, (void*)&Whh_f, (void*)&bih_f, (void*)&bhh_f,
                    (void*)&Wih_b, (void*)&Whh_b, (void*)&bih_b, (void*)&bhh_b,
                    (void*)&W_enc, (void*)&b_enc,
                    (void*)&enc_proj, (void*)&henc, (void*)&cfin, (void*)&bar_enc};
    hipLaunchCooperativeKernel((const void*)encoder_kernel, dim3(NWG), dim3(512),
                               args, ENC_LDS, stream);
  }
  {
    void* args[] = {(void*)&feats,
                    (void*)&Wih_d, (void*)&Whh_d, (void*)&bih_d, (void*)&bhh_d,
                    (void*)&W_dec, (void*)&b_dec, (void*)&W_v, (void*)&b_v,
                    (void*)&enc_proj, (void*)&henc, (void*)&cfin,
                    (void*)&hbuf, (void*)&dproj, (void*)&pval, (void*)&pidx,
                    (void*)&bar_dec, (void*)&out};
    hipLaunchCooperativeKernel((const void*)decoder_kernel, dim3(NWG), dim3(512),
                               args, DEC_LDS, stream);
  }
}

// Round 15
// 16747.501 us; speedup vs baseline: 5.4703x; 1.0545x over previous
//
#include <hip/hip_runtime.h>
#include <stdint.h>

// F=1024, H=512, S=512, B=32, T=128
// Round-14 base. ONE change: encoder 512 -> 1024 threads/WG via 2-way k-split
// (kk2 = t>>9 picks the k-half of each staged chunk; partials combined in
// fixed order through gpartK[2]/projp[2][2]). 4 waves/SIMD for latency hiding.
// Decoder byte-identical to round 14.

#define NWG 256

__device__ __forceinline__ float sigm(float x) { return 1.0f / (1.0f + __expf(-x)); }
__device__ __forceinline__ float tanhx(float x) {
  float e = __expf(2.0f * x);
  return 1.0f - 2.0f / (e + 1.0f);
}

__device__ __forceinline__ float ldc(const float* p) {
  return __hip_atomic_load(p, __ATOMIC_RELAXED, __HIP_MEMORY_SCOPE_AGENT);
}
__device__ __forceinline__ float2 ldc2(const float* p) {
  double d = __hip_atomic_load((const double*)p, __ATOMIC_RELAXED, __HIP_MEMORY_SCOPE_AGENT);
  return __builtin_bit_cast(float2, d);
}
__device__ __forceinline__ void stc(float* p, float v) {
  __hip_atomic_store(p, v, __ATOMIC_RELAXED, __HIP_MEMORY_SCOPE_AGENT);
}
__device__ __forceinline__ int ldci(const int* p) {
  return __hip_atomic_load(p, __ATOMIC_RELAXED, __HIP_MEMORY_SCOPE_AGENT);
}
__device__ __forceinline__ void stci(int* p, int v) {
  __hip_atomic_store(p, v, __ATOMIC_RELAXED, __HIP_MEMORY_SCOPE_AGENT);
}

__device__ __forceinline__ void tree_barrier(int* bar, int w, int epoch) {
  __syncthreads();
  if (threadIdx.x == 0) {
    const int g = w >> 3;
    int* gc = bar + g * 64;
    int* rc = bar + 2048;
    int* gf = bar + 2112 + g * 64;
    int old = __hip_atomic_fetch_add(gc, 1, __ATOMIC_RELAXED, __HIP_MEMORY_SCOPE_AGENT);
    if (old == epoch * 8 - 1) {
      __hip_atomic_fetch_add(rc, 1, __ATOMIC_RELAXED, __HIP_MEMORY_SCOPE_AGENT);
      while (__hip_atomic_load(rc, __ATOMIC_RELAXED, __HIP_MEMORY_SCOPE_AGENT) < epoch * 32)
        __builtin_amdgcn_s_sleep(2);
      __hip_atomic_store(gf, epoch, __ATOMIC_RELAXED, __HIP_MEMORY_SCOPE_AGENT);
    } else {
      while (__hip_atomic_load(gf, __ATOMIC_RELAXED, __HIP_MEMORY_SCOPE_AGENT) < epoch)
        __builtin_amdgcn_s_sleep(2);
    }
  }
  __syncthreads();
}

// ---------------------------------------------------------------------------
// Encoder: 256 WGs x 1024 thr. Thread (kk2,g,b,ci): gate row g*512+col,
// k-half kk2 of each staged 256-chunk. Weights LDS-resident; x-phase first
// (4 chunks from feats), h-phase (2 chunks, coherent loads pre-issued).
// ---------------------------------------------------------------------------
__global__ __launch_bounds__(1024) void encoder_kernel(
    const float* __restrict__ feats,
    const float* __restrict__ Wih_f, const float* __restrict__ Whh_f,
    const float* __restrict__ bih_f, const float* __restrict__ bhh_f,
    const float* __restrict__ Wih_b, const float* __restrict__ Whh_b,
    const float* __restrict__ bih_b, const float* __restrict__ bhh_b,
    const float* __restrict__ W_enc, const float* __restrict__ b_enc,
    float* __restrict__ enc_proj, float* __restrict__ henc,
    float* __restrict__ cfin, int* __restrict__ bar)
{
  extern __shared__ __align__(16) float dyn[];
  float* wih_l = dyn;            // 16 x 1028
  float* whh_l = dyn + 16448;    // 16 x 516
  __shared__ float hch[32 * 260];     // [32][256] staging (+pad)
  __shared__ float wenc[4 * 516];
  __shared__ float gpartK[2][32][17];
  __shared__ float projp[2][2][128];
  __shared__ float bias_s[16];
  __shared__ float benc_s[4];

  const int w = blockIdx.x;
  const int dir = (w >= 128) ? 1 : 0;
  const int wl = w & 127;
  const int col0 = wl * 4;
  const int t = threadIdx.x;
  const int kk2 = t >> 9;            // k-half selector
  const int u = t & 511;
  const int g = u >> 7;              // gate 0..3
  const int tt = u & 127;
  const int b = tt >> 2;
  const int ci = tt & 3;
  const int col = col0 + ci;
  // 2 float4 positions per thread in a [32][256] chunk (2048 float4s)
  const int p0b = t >> 6,          p0q = t & 63;           // rows 0..15
  const int p1b = (t + 1024) >> 6, p1q = (t + 1024) & 63;  // rows 16..31

  const float* Wih = dir ? Wih_b : Wih_f;
  const float* Whh = dir ? Whh_b : Whh_f;
  const float* bih = dir ? bih_b : bih_f;
  const float* bhh = dir ? bhh_b : bhh_f;

  for (int i = t; i < 16 * 256; i += 1024) {
    int r = i >> 8, q = i & 255;
    int gg = r >> 2, cj = r & 3;
    *(float4*)(wih_l + r * 1028 + q * 4) =
        *(const float4*)(Wih + (size_t)(gg * 512 + col0 + cj) * 1024 + q * 4);
  }
  for (int i = t; i < 16 * 128; i += 1024) {
    int r = i >> 7, q = i & 127;
    int gg = r >> 2, cj = r & 3;
    *(float4*)(whh_l + r * 516 + q * 4) =
        *(const float4*)(Whh + (size_t)(gg * 512 + col0 + cj) * 512 + q * 4);
  }
  for (int i = t; i < 4 * 128; i += 1024) {
    int jl = i >> 7, q = i & 127;
    *(float4*)(wenc + jl * 516 + q * 4) =
        *(const float4*)(W_enc + (size_t)(col0 + jl) * 1024 + dir * 512 + q * 4);
  }
  if (t < 16) {
    int gg = t >> 2, cj = t & 3;
    bias_s[t] = bih[gg * 512 + col0 + cj] + bhh[gg * 512 + col0 + cj];
  }
  if (t < 4) benc_s[t] = b_enc[col0 + t];
  float c_reg = 0.0f;
  __syncthreads();

  const float* wx = wih_l + (g * 4 + ci) * 1028;   // this thread's Wih row
  const float* wh = whh_l + (g * 4 + ci) * 516;    // this thread's Whh row
  const float* wpe = wenc + ci * 516;
  const int kq = kk2 * 2 + g;                      // proj quarter (g<2 only)

  for (int it = 0; it < 512; ++it) {
    const int s = dir ? (511 - it) : it;
    float acc = 0.0f, projacc = 0.0f;
    const float* fsrc = feats + ((size_t)s * 32) * 1024;
    const float* hsrc = henc + dir * 32768 + ((it - 1) & 1) * 16384;

    // ---- issue ALL h-chunk coherent loads up front (hidden under x) ----
    float2 h00a, h00b, h01a, h01b;   // chunk 0, positions p0/p1
    float2 h10a, h10b, h11a, h11b;   // chunk 1
    if (it > 0) {
      const float* sp;
      sp = hsrc + p0b * 512 + p0q * 4;       h00a = ldc2(sp); h00b = ldc2(sp + 2);
      sp = hsrc + p1b * 512 + p1q * 4;       h01a = ldc2(sp); h01b = ldc2(sp + 2);
      sp = hsrc + p0b * 512 + 256 + p0q * 4; h10a = ldc2(sp); h10b = ldc2(sp + 2);
      sp = hsrc + p1b * 512 + 256 + p1q * 4; h11a = ldc2(sp); h11b = ldc2(sp + 2);
    }

    // ---- x phase: 4 chunks of [32][256] from feats (plain loads) ----
    {
      float4 xv0 = *(const float4*)(fsrc + p0b * 1024 + p0q * 4);
      float4 xv1 = *(const float4*)(fsrc + p1b * 1024 + p1q * 4);
      for (int ch = 0; ch < 4; ++ch) {
        *(float4*)(hch + p0b * 260 + p0q * 4) = xv0;
        *(float4*)(hch + p1b * 260 + p1q * 4) = xv1;
        __syncthreads();
        if (ch < 3) {
          xv0 = *(const float4*)(fsrc + p0b * 1024 + (ch + 1) * 256 + p0q * 4);
          xv1 = *(const float4*)(fsrc + p1b * 1024 + (ch + 1) * 256 + p1q * 4);
        }
        const float* hrow = hch + b * 260 + kk2 * 128;
        const float* pw = wx + ch * 256 + kk2 * 128;
#pragma unroll 8
        for (int q = 0; q < 32; ++q) {
          float4 f4 = *(const float4*)(hrow + q * 4);
          float4 a4 = *(const float4*)(pw + q * 4);
          acc += f4.x * a4.x + f4.y * a4.y + f4.z * a4.z + f4.w * a4.w;
        }
        __syncthreads();
      }
    }

    // ---- h phase: 2 chunks of [32][256] from registers ----
    if (it > 0) {
      // chunk 0 (k 0..255)
      *(float4*)(hch + p0b * 260 + p0q * 4) = make_float4(h00a.x, h00a.y, h00b.x, h00b.y);
      *(float4*)(hch + p1b * 260 + p1q * 4) = make_float4(h01a.x, h01a.y, h01b.x, h01b.y);
      __syncthreads();
      {
        const float* hrow = hch + b * 260 + kk2 * 128;
        const float* pw = wh + kk2 * 128;
#pragma unroll 8
        for (int q = 0; q < 32; ++q) {
          float4 h4 = *(const float4*)(hrow + q * 4);
          float4 a4 = *(const float4*)(pw + q * 4);
          acc += h4.x * a4.x + h4.y * a4.y + h4.z * a4.z + h4.w * a4.w;
        }
        if (g < 2) {
          const float* hp = hch + b * 260 + kq * 64;
          const float* wp = wpe + kq * 64;
#pragma unroll 4
          for (int kk = 0; kk < 16; ++kk) {
            float4 h4 = *(const float4*)(hp + kk * 4);
            float4 w4 = *(const float4*)(wp + kk * 4);
            projacc += h4.x * w4.x + h4.y * w4.y + h4.z * w4.z + h4.w * w4.w;
          }
        }
      }
      __syncthreads();
      // chunk 1 (k 256..511)
      *(float4*)(hch + p0b * 260 + p0q * 4) = make_float4(h10a.x, h10a.y, h10b.x, h10b.y);
      *(float4*)(hch + p1b * 260 + p1q * 4) = make_float4(h11a.x, h11a.y, h11b.x, h11b.y);
      __syncthreads();
      {
        const float* hrow = hch + b * 260 + kk2 * 128;
        const float* pw = wh + 256 + kk2 * 128;
#pragma unroll 8
        for (int q = 0; q < 32; ++q) {
          float4 h4 = *(const float4*)(hrow + q * 4);
          float4 a4 = *(const float4*)(pw + q * 4);
          acc += h4.x * a4.x + h4.y * a4.y + h4.z * a4.z + h4.w * a4.w;
        }
        if (g < 2) {
          const float* hp = hch + b * 260 + kq * 64;
          const float* wp = wpe + 256 + kq * 64;
#pragma unroll 4
          for (int kk = 0; kk < 16; ++kk) {
            float4 h4 = *(const float4*)(hp + kk * 4);
            float4 w4 = *(const float4*)(wp + kk * 4);
            projacc += h4.x * w4.x + h4.y * w4.y + h4.z * w4.z + h4.w * w4.w;
          }
        }
      }
      __syncthreads();
    }

    gpartK[kk2][b][g * 4 + ci] = acc;
    if (g < 2) projp[kk2][g][tt] = projacc;
    __syncthreads();
    if (t < 128) {   // kk2=0, g=0: owns (b,ci)
      float gi = gpartK[0][b][ci + 0] + gpartK[1][b][ci + 0] + bias_s[ci + 0];
      float gf = gpartK[0][b][ci + 4] + gpartK[1][b][ci + 4] + bias_s[ci + 4];
      float gg = gpartK[0][b][ci + 8] + gpartK[1][b][ci + 8] + bias_s[ci + 8];
      float go = gpartK[0][b][ci + 12] + gpartK[1][b][ci + 12] + bias_s[ci + 12];
      float cn = sigm(gf) * c_reg + sigm(gi) * tanhx(gg);
      c_reg = cn;
      stc(henc + dir * 32768 + (it & 1) * 16384 + b * 512 + col,
          sigm(go) * tanhx(cn));
    } else if (kk2 == 0 && g == 1 && it > 0) {
      const int sp = dir ? (512 - it) : (it - 1);
      const float p = projp[0][0][tt] + projp[0][1][tt] +
                      projp[1][0][tt] + projp[1][1][tt];
      float* addr = enc_proj + ((size_t)sp * 32 + b) * 512 + col;
      if (it - 1 <= 255) {
        stc(addr, p + benc_s[ci]);
      } else {
        stc(addr, ldc(addr) + p);
      }
    }
    tree_barrier(bar, w, it + 1);
  }

  // post-loop: proj for e=511 (second arriver), and cfin
  {
    const float* hsrc = henc + dir * 32768 + 16384;  // h[511] at pp=1
    float projacc = 0.0f;
    for (int ch = 0; ch < 2; ++ch) {
      for (int i = t; i < 2048; i += 1024) {   // 2048 float4s = [32][256]
        int bb = i >> 6, qf = i & 63;
        const float* sp = hsrc + bb * 512 + ch * 256 + qf * 4;
        float2 f0 = ldc2(sp);
        float2 f1 = ldc2(sp + 2);
        *(float4*)(hch + bb * 260 + qf * 4) = make_float4(f0.x, f0.y, f1.x, f1.y);
      }
      __syncthreads();
      if (g < 2) {
        const float* hp = hch + b * 260 + kq * 64;
        const float* wp = wpe + ch * 256 + kq * 64;
#pragma unroll 4
        for (int kk = 0; kk < 16; ++kk) {
          float4 h4 = *(const float4*)(hp + kk * 4);
          float4 w4 = *(const float4*)(wp + kk * 4);
          projacc += h4.x * w4.x + h4.y * w4.y + h4.z * w4.z + h4.w * w4.w;
        }
      }
      __syncthreads();
    }
    if (g < 2) projp[kk2][g][tt] = projacc;
    __syncthreads();
    if (kk2 == 0 && g == 1) {
      const int sp = dir ? 0 : 511;
      float* addr = enc_proj + ((size_t)sp * 32 + b) * 512 + col;
      stc(addr, ldc(addr) + (projp[0][0][tt] + projp[0][1][tt] +
                             projp[1][0][tt] + projp[1][1][tt]));
    }
    if (t < 128) cfin[dir * 16384 + b * 512 + col] = c_reg;
  }
}

// ---------------------------------------------------------------------------
// Decoder: byte-identical to round 14. 3 barriers/step; 2-deep prefetch.
// ---------------------------------------------------------------------------
__global__ __launch_bounds__(512) void decoder_kernel(
    const float* __restrict__ feats,
    const float* __restrict__ Wih_d, const float* __restrict__ Whh_d,
    const float* __restrict__ bih_d, const float* __restrict__ bhh_d,
    const float* __restrict__ W_dec, const float* __restrict__ b_dec,
    const float* __restrict__ W_v, const float* __restrict__ b_v,
    const float* __restrict__ enc_proj, const float* __restrict__ henc,
    const float* __restrict__ cfin,
    float* __restrict__ hbuf, float* __restrict__ dproj,
    float* __restrict__ pval, int* __restrict__ pidx,
    int* __restrict__ bar, float* __restrict__ out)
{
  extern __shared__ __align__(16) float dyn[];
  float* whh_l = dyn;            // 16 x 1028
  float* wih_l = dyn + 16448;    // 16 x 1028
  __shared__ float hch[32 * 132];   // staging; aliased by dpl (barrier-safe)
  __shared__ float gpart[2][32][17];
  __shared__ float c_lds[32][4];
  __shared__ float bias_s[16];
  __shared__ float svals[64];
  __shared__ int ib_lds[32];
  float* dpl = hch + 1088;   // [8][68] dproj slice for phase C (alias)

  const int w = blockIdx.x;
  const int t = threadIdx.x;
  const int q4 = t >> 7;
  const int tt = t & 127;
  const int b = tt >> 2;
  const int ci = tt & 3;
  const int col0 = w * 4;
  const int col = col0 + ci;
  const int i0 = t, i1 = t + 512;
  const int bb0 = i0 >> 5, q0 = i0 & 31;
  const int bb1 = i1 >> 5, q1 = i1 & 31;
  const int bb_c = w >> 3;   // phase C batch
  const int qq_ = w & 7;     // phase C s-block
  const int ccB = t >> 8;            // phase B: col 2w+ccB
  const int bB = (t >> 3) & 31;      // phase B batch
  const int k8 = t & 7;              // phase B k-slice

  for (int i = t; i < 16 * 256; i += 512) {
    int r = i >> 8, q = i & 255;
    int gg = r >> 2, cj = r & 3;
    *(float4*)(whh_l + r * 1028 + q * 4) =
        *(const float4*)(Whh_d + (size_t)(gg * 1024 + col0 + cj) * 1024 + q * 4);
    *(float4*)(wih_l + r * 1028 + q * 4) =
        *(const float4*)(Wih_d + (size_t)(gg * 1024 + col0 + cj) * 1024 + q * 4);
  }
  if (t < 16) {
    int gg = t >> 2, cj = t & 3;
    bias_s[t] = bih_d[gg * 1024 + col0 + cj] + bhh_d[gg * 1024 + col0 + cj];
  }
  if (t < 128) {
    int flat = b * 1024 + col;
    int d = flat >> 14, sb = (flat >> 9) & 31, sh = flat & 511;
    float h0, c0;
    if (d == 0) {
      h0 = henc[16384 + sb * 512 + sh];
      c0 = cfin[sb * 512 + sh];
    } else {
      h0 = henc[32768 + 16384 + sb * 512 + sh];
      c0 = cfin[16384 + sb * 512 + sh];
    }
    stc(hbuf + b * 1024 + col, h0);
    c_lds[b][ci] = c0;
  }
  int bars = 1;
  tree_barrier(bar, w, bars);

  const float* wbase = (q4 < 2) ? whh_l : wih_l;
  const int g0 = (q4 & 1) * 2;
  const float* wr0 = wbase + (size_t)((g0 + 0) * 4 + ci) * 1028;
  const float* wr1 = wbase + (size_t)((g0 + 1) * 4 + ci) * 1028;

  for (int ts = 0; ts < 128; ++ts) {
    const float* hprev = hbuf + (ts & 1) * 32768;
    float* hnext = hbuf + ((ts + 1) & 1) * 32768;

    // ---- phase A: gates GEMM (2-deep staged hprev) + cell; ib folded ----
    float a0 = 0.f, a1 = 0.f;
    const float* xrow = nullptr;
    {
      float2 s0a0 = ldc2(hprev + bb0 * 1024 + q0 * 4);
      float2 s0a1 = ldc2(hprev + bb0 * 1024 + q0 * 4 + 2);
      float2 s0b0 = ldc2(hprev + bb1 * 1024 + q1 * 4);
      float2 s0b1 = ldc2(hprev + bb1 * 1024 + q1 * 4 + 2);
      float2 s1a0 = ldc2(hprev + bb0 * 1024 + 128 + q0 * 4);
      float2 s1a1 = ldc2(hprev + bb0 * 1024 + 128 + q0 * 4 + 2);
      float2 s1b0 = ldc2(hprev + bb1 * 1024 + 128 + q1 * 4);
      float2 s1b1 = ldc2(hprev + bb1 * 1024 + 128 + q1 * 4 + 2);
      if (t < 32) {
        int ib = 0;
        if (ts > 0) {
          float v = ldc(pval + t * 8 + 0);
          int si = ldci(pidx + t * 8 + 0);
#pragma unroll
          for (int j = 1; j < 8; ++j) {
            float ov = ldc(pval + t * 8 + j);
            int os = ldci(pidx + t * 8 + j);
            if (ov > v || (ov == v && os < si)) { v = ov; si = os; }
          }
          ib = si;
        }
        ib_lds[t] = ib;
      }
      for (int ch = 0; ch < 8; ++ch) {
        if (ch & 1) {
          *(float4*)(hch + bb0 * 132 + q0 * 4) = make_float4(s1a0.x, s1a0.y, s1a1.x, s1a1.y);
          *(float4*)(hch + bb1 * 132 + q1 * 4) = make_float4(s1b0.x, s1b0.y, s1b1.x, s1b1.y);
        } else {
          *(float4*)(hch + bb0 * 132 + q0 * 4) = make_float4(s0a0.x, s0a0.y, s0a1.x, s0a1.y);
          *(float4*)(hch + bb1 * 132 + q1 * 4) = make_float4(s0b0.x, s0b0.y, s0b1.x, s0b1.y);
        }
        __syncthreads();
        if (ch == 0 && q4 >= 2) {
          int ib = ib_lds[b];
          xrow = feats + ((size_t)ib * 32 + b) * 1024;
        }
        if (ch < 6) {
          const int cn = (ch + 2) * 128;
          if (ch & 1) {
            s1a0 = ldc2(hprev + bb0 * 1024 + cn + q0 * 4);
            s1a1 = ldc2(hprev + bb0 * 1024 + cn + q0 * 4 + 2);
            s1b0 = ldc2(hprev + bb1 * 1024 + cn + q1 * 4);
            s1b1 = ldc2(hprev + bb1 * 1024 + cn + q1 * 4 + 2);
          } else {
            s0a0 = ldc2(hprev + bb0 * 1024 + cn + q0 * 4);
            s0a1 = ldc2(hprev + bb0 * 1024 + cn + q0 * 4 + 2);
            s0b0 = ldc2(hprev + bb1 * 1024 + cn + q1 * 4);
            s0b1 = ldc2(hprev + bb1 * 1024 + cn + q1 * 4 + 2);
          }
        }
        const float* src = (q4 < 2) ? (hch + b * 132) : (xrow + ch * 128);
        const float* p0 = wr0 + ch * 128;
        const float* p1 = wr1 + ch * 128;
#pragma unroll 8
        for (int qq = 0; qq < 32; ++qq) {
          float4 h4 = *(const float4*)(src + qq * 4);
          float4 u0 = *(const float4*)(p0 + qq * 4);
          float4 u1 = *(const float4*)(p1 + qq * 4);
          a0 += h4.x * u0.x + h4.y * u0.y + h4.z * u0.z + h4.w * u0.w;
          a1 += h4.x * u1.x + h4.y * u1.y + h4.z * u1.z + h4.w * u1.w;
        }
        __syncthreads();
      }
    }
    gpart[q4 >> 1][b][ci + (g0 + 0) * 4] = a0;
    gpart[q4 >> 1][b][ci + (g0 + 1) * 4] = a1;
    __syncthreads();
    if (t < 128) {
      float gi = gpart[0][b][ci + 0] + gpart[1][b][ci + 0] + bias_s[ci + 0];
      float gf = gpart[0][b][ci + 4] + gpart[1][b][ci + 4] + bias_s[ci + 4];
      float gg = gpart[0][b][ci + 8] + gpart[1][b][ci + 8] + bias_s[ci + 8];
      float go = gpart[0][b][ci + 12] + gpart[1][b][ci + 12] + bias_s[ci + 12];
      float cn = sigm(gf) * c_lds[b][ci] + sigm(gi) * tanhx(gg);
      c_lds[b][ci] = cn;
      stc(hnext + b * 1024 + col, sigm(go) * tanhx(cn));
    }
    ++bars; tree_barrier(bar, w, bars);

    // ---- phase B: dproj cols {2w,2w+1}; hnext 2-deep staged, 8-way k-split --
    {
      float dacc = 0.f;
      const float* wdrow = W_dec + (size_t)(2 * w + ccB) * 1024;
      float2 s0a0 = ldc2(hnext + bb0 * 1024 + q0 * 4);
      float2 s0a1 = ldc2(hnext + bb0 * 1024 + q0 * 4 + 2);
      float2 s0b0 = ldc2(hnext + bb1 * 1024 + q1 * 4);
      float2 s0b1 = ldc2(hnext + bb1 * 1024 + q1 * 4 + 2);
      float2 s1a0 = ldc2(hnext + bb0 * 1024 + 128 + q0 * 4);
      float2 s1a1 = ldc2(hnext + bb0 * 1024 + 128 + q0 * 4 + 2);
      float2 s1b0 = ldc2(hnext + bb1 * 1024 + 128 + q1 * 4);
      float2 s1b1 = ldc2(hnext + bb1 * 1024 + 128 + q1 * 4 + 2);
      for (int ch = 0; ch < 8; ++ch) {
        if (ch & 1) {
          *(float4*)(hch + bb0 * 132 + q0 * 4) = make_float4(s1a0.x, s1a0.y, s1a1.x, s1a1.y);
          *(float4*)(hch + bb1 * 132 + q1 * 4) = make_float4(s1b0.x, s1b0.y, s1b1.x, s1b1.y);
        } else {
          *(float4*)(hch + bb0 * 132 + q0 * 4) = make_float4(s0a0.x, s0a0.y, s0a1.x, s0a1.y);
          *(float4*)(hch + bb1 * 132 + q1 * 4) = make_float4(s0b0.x, s0b0.y, s0b1.x, s0b1.y);
        }
        __syncthreads();
        if (ch < 6) {
          const int cn = (ch + 2) * 128;
          if (ch & 1) {
            s1a0 = ldc2(hnext + bb0 * 1024 + cn + q0 * 4);
            s1a1 = ldc2(hnext + bb0 * 1024 + cn + q0 * 4 + 2);
            s1b0 = ldc2(hnext + bb1 * 1024 + cn + q1 * 4);
            s1b1 = ldc2(hnext + bb1 * 1024 + cn + q1 * 4 + 2);
          } else {
            s0a0 = ldc2(hnext + bb0 * 1024 + cn + q0 * 4);
            s0a1 = ldc2(hnext + bb0 * 1024 + cn + q0 * 4 + 2);
            s0b0 = ldc2(hnext + bb1 * 1024 + cn + q1 * 4);
            s0b1 = ldc2(hnext + bb1 * 1024 + cn + q1 * 4 + 2);
          }
        }
        const float* hl = hch + bB * 132 + k8 * 16;
        const float* wl = wdrow + ch * 128 + k8 * 16;
#pragma unroll
        for (int j = 0; j < 4; ++j) {
          float4 h4 = *(const float4*)(hl + j * 4);
          float4 w4 = *(const float4*)(wl + j * 4);
          dacc += h4.x * w4.x + h4.y * w4.y + h4.z * w4.z + h4.w * w4.w;
        }
        __syncthreads();
      }
      dacc += __shfl_xor(dacc, 1);
      dacc += __shfl_xor(dacc, 2);
      dacc += __shfl_xor(dacc, 4);
      if (k8 == 0) stc(dproj + bB * 512 + 2 * w + ccB, dacc + b_dec[2 * w + ccB]);
    }
    ++bars; tree_barrier(bar, w, bars);

    // ---- phase C: scores, batch-major (WG: bb_c, s-block qq_) ----
    if (t < 256) {
      float2 v = ldc2(dproj + bb_c * 512 + 2 * t);
      int k = 2 * t;
      dpl[(k >> 6) * 68 + (k & 63) + 0] = v.x;
      dpl[(k >> 6) * 68 + (k & 63) + 1] = v.y;
    }
    __syncthreads();
    {
      const int sl = t >> 3, ks = t & 7;
      const int s = qq_ * 64 + sl;
      const float* ep = enc_proj + ((size_t)s * 32 + bb_c) * 512 + ks * 64;
      const float* dpp = dpl + ks * 68;
      const float* wvp = W_v + ks * 64;
      float sum = 0.f;
#pragma unroll 4
      for (int j = 0; j < 16; ++j) {
        float4 e4 = *(const float4*)(ep + j * 4);
        float4 d4 = *(const float4*)(dpp + j * 4);
        float4 v4 = *(const float4*)(wvp + j * 4);
        sum += tanhx(e4.x + d4.x) * v4.x;
        sum += tanhx(e4.y + d4.y) * v4.y;
        sum += tanhx(e4.z + d4.z) * v4.z;
        sum += tanhx(e4.w + d4.w) * v4.w;
      }
      sum += __shfl_xor(sum, 1);
      sum += __shfl_xor(sum, 2);
      sum += __shfl_xor(sum, 4);
      if (ks == 0) {
        float sv = sum + b_v[0];
        out[((size_t)ts * 32 + bb_c) * 512 + s] = sv;
        svals[sl] = sv;
      }
    }
    __syncthreads();
    if (t < 64) {
      float v = svals[t];
      int si = qq_ * 64 + t;
#pragma unroll
      for (int m = 1; m < 64; m <<= 1) {
        float ov = __shfl_xor(v, m);
        int os = __shfl_xor(si, m);
        if (ov > v || (ov == v && os < si)) { v = ov; si = os; }
      }
      if (t == 0) {
        stc(pval + bb_c * 8 + qq_, v);
        stci(pidx + bb_c * 8 + qq_, si);
      }
    }
    ++bars; tree_barrier(bar, w, bars);
  }
}

// ---------------------------------------------------------------------------
extern "C" void kernel_launch(void* const* d_in, const int* in_sizes, int n_in,
                              void* d_out, int out_size, void* d_ws, size_t ws_size,
                              hipStream_t stream) {
  (void)in_sizes; (void)n_in; (void)out_size; (void)ws_size;
  const float* feats = (const float*)d_in[0];
  const float* Wih_f = (const float*)d_in[1];
  const float* Whh_f = (const float*)d_in[2];
  const float* bih_f = (const float*)d_in[3];
  const float* bhh_f = (const float*)d_in[4];
  const float* Wih_b = (const float*)d_in[5];
  const float* Whh_b = (const float*)d_in[6];
  const float* bih_b = (const float*)d_in[7];
  const float* bhh_b = (const float*)d_in[8];
  const float* Wih_d = (const float*)d_in[9];
  const float* Whh_d = (const float*)d_in[10];
  const float* bih_d = (const float*)d_in[11];
  const float* bhh_d = (const float*)d_in[12];
  const float* W_enc = (const float*)d_in[13];
  const float* b_enc = (const float*)d_in[14];
  const float* W_dec = (const float*)d_in[15];
  const float* b_dec = (const float*)d_in[16];
  const float* W_v   = (const float*)d_in[17];
  const float* b_v   = (const float*)d_in[18];
  float* out = (float*)d_out;

  int* ctrl = (int*)d_ws;
  int* bar_enc = ctrl;
  int* bar_dec = ctrl + 8192;
  float* base = (float*)d_ws + 16384;        // after 64 KiB ctrl block
  float* enc_proj = base;                    // 8,388,608
  float* henc     = enc_proj + 8388608;      //    65,536
  float* cfin     = henc + 65536;            //    32,768
  float* hbuf     = cfin + 32768;            //    65,536
  float* dproj    = hbuf + 65536;            //    16,384
  float* pval     = dproj + 16384;           //     8,192 (256 used)
  int*   pidx     = (int*)(pval + 8192);     //     8,192 (256 used)
  // total ~34.4 MB

  const int ENC_LDS = (16 * 1028 + 16 * 516) * 4;   //  98,816 B
  const int DEC_LDS = (2 * 16 * 1028) * 4;          // 131,584 B
  hipFuncSetAttribute((const void*)encoder_kernel,
                      hipFuncAttributeMaxDynamicSharedMemorySize, ENC_LDS);
  hipFuncSetAttribute((const void*)decoder_kernel,
                      hipFuncAttributeMaxDynamicSharedMemorySize, DEC_LDS);

  hipMemsetAsync(d_ws, 0, 65536, stream);

  {
    void* args[] = {(void*)&feats,
                    (void*)&Wih_f, (void*)&Whh_f, (void*)&bih_f, (void*)&bhh_f,
                    (void*)&Wih_b, (void*)&Whh_b, (void*)&bih_b, (void*)&bhh_b,
                    (void*)&W_enc, (void*)&b_enc,
                    (void*)&enc_proj, (void*)&henc, (void*)&cfin, (void*)&bar_enc};
    hipLaunchCooperativeKernel((const void*)encoder_kernel, dim3(NWG), dim3(1024),
                               args, ENC_LDS, stream);
  }
  {
    void* args[] = {(void*)&feats,
                    (void*)&Wih_d, (void*)&Whh_d, (void*)&bih_d, (void*)&bhh_d,
                    (void*)&W_dec, (void*)&b_dec, (void*)&W_v, (void*)&b_v,
                    (void*)&enc_proj, (void*)&henc, (void*)&cfin,
                    (void*)&hbuf, (void*)&dproj, (void*)&pval, (void*)&pidx,
                    (void*)&bar_dec, (void*)&out};
    hipLaunchCooperativeKernel((const void*)decoder_kernel, dim3(NWG), dim3(512),
                               args, DEC_LDS, stream);
  }
}